// Round 2
// baseline (1516.429 us; speedup 1.0000x reference)
//
#include <hip/hip_runtime.h>

typedef __bf16 bf16x8 __attribute__((ext_vector_type(8)));
typedef float f32x4 __attribute__((ext_vector_type(4)));

#define MFMA_BF16 __builtin_amdgcn_mfma_f32_16x16x32_bf16

// Swizzled element index for a [rows][C] bf16 LDS tile, 16B-chunk XOR by row&7
// (G4 pattern: byte ^= ((row&7)<<4)). col must address within an 8-elem chunk.
__device__ __forceinline__ int swz64(int row, int col) {   // C = 64
  return row * 64 + (((col >> 3) ^ (row & 7)) << 3) + (col & 7);
}
__device__ __forceinline__ int swz512(int row, int col) {  // C = 512
  return row * 512 + (((col >> 3) ^ (row & 7)) << 3) + (col & 7);
}

// ---------------------------------------------------------------------------
// prep: zero stat accumulators, cast W2/W3 to bf16 in scratch
// ---------------------------------------------------------------------------
__global__ __launch_bounds__(256) void prep_kernel(
    const float* __restrict__ W2, const float* __restrict__ W3,
    __bf16* __restrict__ W2bf, __bf16* __restrict__ W3bf,
    float* __restrict__ stats, int nstats) {
  int i = blockIdx.x * 256 + threadIdx.x;
  if (i < 32768) W2bf[i] = (__bf16)W2[i];
  if (i < 262144) W3bf[i] = (__bf16)W3[i];
  if (i < nstats) stats[i] = 0.f;
}

// ---------------------------------------------------------------------------
// stats1: column stats of y1 = x2 @ W1^T + b1 (no store)
// block = 256 = 64 cols x 4 rows, 128 rows/block
// ---------------------------------------------------------------------------
__global__ __launch_bounds__(256) void stats1_kernel(
    const float* __restrict__ x, const float* __restrict__ W1,
    const float* __restrict__ b1, float* __restrict__ gsum,
    float* __restrict__ gsq) {
  int t = threadIdx.x;
  int c = t & 63;
  int rw = t >> 6;
  float w0 = W1[c * 3 + 0], w1 = W1[c * 3 + 1], w2 = W1[c * 3 + 2];
  float b = b1[c];
  int base = blockIdx.x * 128;
  float sum = 0.f, sq = 0.f;
#pragma unroll 4
  for (int i = 0; i < 32; ++i) {
    int row = base + i * 4 + rw;
    const float* xp = x + (size_t)row * 3;
    float y = fmaf(xp[0], w0, fmaf(xp[1], w1, fmaf(xp[2], w2, b)));
    sum += y;
    sq += y * y;
  }
  __shared__ float ssum[256], ssq[256];
  ssum[t] = sum;
  ssq[t] = sq;
  __syncthreads();
  if (t < 64) {
    float s = ssum[t] + ssum[t + 64] + ssum[t + 128] + ssum[t + 192];
    float q = ssq[t] + ssq[t + 64] + ssq[t + 128] + ssq[t + 192];
    atomicAdd(&gsum[t], s);
    atomicAdd(&gsq[t], q);
  }
}

// ---------------------------------------------------------------------------
// finalize1: BN1 scale/shift folded with W1,b1 ->
//   h1[r][c] = relu(fold1[c]*x0 + fold1[64+c]*x1 + fold1[128+c]*x2 + fold1[192+c])
// ---------------------------------------------------------------------------
__global__ void finalize1_kernel(const float* __restrict__ gsum,
                                 const float* __restrict__ gsq,
                                 const float* __restrict__ gamma,
                                 const float* __restrict__ beta,
                                 const float* __restrict__ W1,
                                 const float* __restrict__ b1,
                                 float* __restrict__ fold1, float invN) {
  int c = threadIdx.x;  // 64
  float mu = gsum[c] * invN;
  float var = gsq[c] * invN - mu * mu;
  float sc = gamma[c] * rsqrtf(var + 1e-5f);
  float sh = beta[c] - mu * sc;
  fold1[c] = sc * W1[c * 3 + 0];
  fold1[64 + c] = sc * W1[c * 3 + 1];
  fold1[128 + c] = sc * W1[c * 3 + 2];
  fold1[192 + c] = sc * b1[c] + sh;
}

// finalize for BN2/BN3: scale[c], shiftf[c] = scale*b + shift (bias folded)
__global__ void finalize23_kernel(const float* __restrict__ gsum,
                                  const float* __restrict__ gsq,
                                  const float* __restrict__ gamma,
                                  const float* __restrict__ beta,
                                  const float* __restrict__ b,
                                  float* __restrict__ scale,
                                  float* __restrict__ shiftf, float invN) {
  int c = blockIdx.x * blockDim.x + threadIdx.x;
  if (c >= 512) return;
  float mu = gsum[c] * invN;
  float var = gsq[c] * invN - mu * mu;
  float sc = gamma[c] * rsqrtf(var + 1e-5f);
  float sh = beta[c] - mu * sc;
  scale[c] = sc;
  shiftf[c] = sc * b[c] + sh;
}

// ---------------------------------------------------------------------------
// Fused recompute kernel. Per block: 64 rows.
//   stage A: h1[64][64] in LDS (from x2, folded BN1)
//   GEMM2:   y2 = h1 @ W2bf^T   (K=64), 4 chunks of 128 cols
//            MODE 0: accumulate stats2, discard
//            MODE>=1: h2 = relu(scale2*y2 + shift2f) -> LDS [64][512]
//   GEMM3:   y3 = h2 @ W3bf^T   (K=512), 4 chunks of 128 cols
//            MODE 1: accumulate stats3, discard
//            MODE 2: h3 = relu(scale3*y3+shift3f); out += h3 @ W4^T (2 cols)
// waves 2x2 over each 64x128 chunk -> wave tile 32x64, frags 2x4, K-step 32
// ---------------------------------------------------------------------------
template <int MODE>
__global__ __launch_bounds__(256) void fused_kernel(
    const float* __restrict__ x2, const float* __restrict__ fold1,
    const __bf16* __restrict__ W2bf, const float* __restrict__ b2,
    const float* __restrict__ scale2, const float* __restrict__ shift2f,
    const __bf16* __restrict__ W3bf, const float* __restrict__ b3,
    const float* __restrict__ scale3, const float* __restrict__ shift3f,
    const float* __restrict__ W4, const float* __restrict__ b4,
    float* __restrict__ gsum2, float* __restrict__ gsq2,
    float* __restrict__ gsum3, float* __restrict__ gsq3,
    float* __restrict__ out) {
  __shared__ float xs[64][4];
  __shared__ __bf16 h1[64 * 64];    // swizzled, 8 KB
  __shared__ __bf16 h2[64 * 512];   // swizzled, 64 KB
  __shared__ float outacc[64][2];

  const int t = threadIdx.x;
  const int rBase = blockIdx.x * 64;
  const int lane = t & 63, wave = t >> 6;
  const int wm = wave >> 1, wn = wave & 1;
  const int lrow = lane & 15, lgrp = lane >> 4;

  if (t < 192) {
    float v = x2[(size_t)rBase * 3 + t];
    xs[t / 3][t % 3] = v;
  }
  if (MODE == 2 && t < 128) outacc[t >> 1][t & 1] = 0.f;
  __syncthreads();

  // ---- stage A: h1 ----
  {
    int r = t >> 2, c0 = (t & 3) * 16;
    float X0 = xs[r][0], X1 = xs[r][1], X2 = xs[r][2];
    bf16x8 o8[2];
#pragma unroll
    for (int j = 0; j < 16; ++j) {
      int c = c0 + j;
      float h = fmaf(fold1[c], X0,
                     fmaf(fold1[64 + c], X1,
                          fmaf(fold1[128 + c], X2, fold1[192 + c])));
      o8[j >> 3][j & 7] = (__bf16)fmaxf(h, 0.f);
    }
#pragma unroll
    for (int q = 0; q < 2; ++q) {
      int chunk = (c0 >> 3) + q;
      *(bf16x8*)&h1[r * 64 + ((chunk ^ (r & 7)) << 3)] = o8[q];
    }
  }
  __syncthreads();

  // ---- GEMM2: 4 chunks of 128 cols ----
#pragma unroll 1
  for (int ch = 0; ch < 4; ++ch) {
    f32x4 acc[2][4] = {};
#pragma unroll
    for (int kk = 0; kk < 64; kk += 32) {
      bf16x8 af[2], bfr[4];
#pragma unroll
      for (int m = 0; m < 2; ++m) {
        int row = wm * 32 + m * 16 + lrow;
        af[m] = *(const bf16x8*)&h1[swz64(row, kk + lgrp * 8)];
      }
#pragma unroll
      for (int n = 0; n < 4; ++n) {
        int col = ch * 128 + wn * 64 + n * 16 + lrow;
        bfr[n] = *(const bf16x8*)&W2bf[(size_t)col * 64 + kk + lgrp * 8];
      }
#pragma unroll
      for (int m = 0; m < 2; ++m)
#pragma unroll
        for (int n = 0; n < 4; ++n)
          acc[m][n] = MFMA_BF16(af[m], bfr[n], acc[m][n], 0, 0, 0);
    }
    // epilogue
#pragma unroll
    for (int n = 0; n < 4; ++n) {
      int col = ch * 128 + wn * 64 + n * 16 + lrow;
      if (MODE == 0) {
        float bcol = b2[col];
        float cs = 0.f, cq = 0.f;
#pragma unroll
        for (int m = 0; m < 2; ++m)
#pragma unroll
          for (int r = 0; r < 4; ++r) {
            float y = acc[m][n][r] + bcol;
            cs += y;
            cq += y * y;
          }
        cs += __shfl_xor(cs, 16);
        cq += __shfl_xor(cq, 16);
        cs += __shfl_xor(cs, 32);
        cq += __shfl_xor(cq, 32);
        if (lgrp == 0) {
          atomicAdd(&gsum2[col], cs);
          atomicAdd(&gsq2[col], cq);
        }
      } else {
        float sc = scale2[col], sh = shift2f[col];
#pragma unroll
        for (int m = 0; m < 2; ++m) {
          int row0 = wm * 32 + m * 16 + lgrp * 4;
#pragma unroll
          for (int r = 0; r < 4; ++r) {
            float h = fmaxf(fmaf(sc, acc[m][n][r], sh), 0.f);
            h2[swz512(row0 + r, col)] = (__bf16)h;
          }
        }
      }
    }
  }
  if (MODE == 0) return;
  __syncthreads();

  // ---- GEMM3: 4 chunks of 128 cols ----
  float d0[2][4], d1[2][4];
  if (MODE == 2) {
#pragma unroll
    for (int m = 0; m < 2; ++m)
#pragma unroll
      for (int r = 0; r < 4; ++r) d0[m][r] = d1[m][r] = 0.f;
  }
#pragma unroll 1
  for (int ch = 0; ch < 4; ++ch) {
    f32x4 acc[2][4] = {};
#pragma unroll 1
    for (int kk = 0; kk < 512; kk += 32) {
      bf16x8 af[2], bfr[4];
#pragma unroll
      for (int m = 0; m < 2; ++m) {
        int row = wm * 32 + m * 16 + lrow;
        af[m] = *(const bf16x8*)&h2[swz512(row, kk + lgrp * 8)];
      }
#pragma unroll
      for (int n = 0; n < 4; ++n) {
        int col = ch * 128 + wn * 64 + n * 16 + lrow;
        bfr[n] = *(const bf16x8*)&W3bf[(size_t)col * 512 + kk + lgrp * 8];
      }
#pragma unroll
      for (int m = 0; m < 2; ++m)
#pragma unroll
        for (int n = 0; n < 4; ++n)
          acc[m][n] = MFMA_BF16(af[m], bfr[n], acc[m][n], 0, 0, 0);
    }
    // epilogue
#pragma unroll
    for (int n = 0; n < 4; ++n) {
      int col = ch * 128 + wn * 64 + n * 16 + lrow;
      if (MODE == 1) {
        float bcol = b3[col];
        float cs = 0.f, cq = 0.f;
#pragma unroll
        for (int m = 0; m < 2; ++m)
#pragma unroll
          for (int r = 0; r < 4; ++r) {
            float y = acc[m][n][r] + bcol;
            cs += y;
            cq += y * y;
          }
        cs += __shfl_xor(cs, 16);
        cq += __shfl_xor(cq, 16);
        cs += __shfl_xor(cs, 32);
        cq += __shfl_xor(cq, 32);
        if (lgrp == 0) {
          atomicAdd(&gsum3[col], cs);
          atomicAdd(&gsq3[col], cq);
        }
      } else {
        float sc = scale3[col], sh = shift3f[col];
        float w40 = W4[col], w41 = W4[512 + col];
#pragma unroll
        for (int m = 0; m < 2; ++m)
#pragma unroll
          for (int r = 0; r < 4; ++r) {
            float h = fmaxf(fmaf(sc, acc[m][n][r], sh), 0.f);
            d0[m][r] = fmaf(h, w40, d0[m][r]);
            d1[m][r] = fmaf(h, w41, d1[m][r]);
          }
      }
    }
  }

  if (MODE == 2) {
    // reduce over the 16 lanes holding the same rows (different cols)
#pragma unroll
    for (int m = 0; m < 2; ++m)
#pragma unroll
      for (int r = 0; r < 4; ++r) {
#pragma unroll
        for (int off = 1; off < 16; off <<= 1) {
          d0[m][r] += __shfl_xor(d0[m][r], off);
          d1[m][r] += __shfl_xor(d1[m][r], off);
        }
        if (lrow == 0) {
          int row = wm * 32 + m * 16 + lgrp * 4 + r;
          atomicAdd(&outacc[row][0], d0[m][r]);
          atomicAdd(&outacc[row][1], d1[m][r]);
        }
      }
    __syncthreads();
    if (t < 128) {
      int row = t >> 1, o = t & 1;
      out[(size_t)(rBase + row) * 2 + o] = outacc[row][o] + b4[o];
    }
  }
}

// ---------------------------------------------------------------------------
extern "C" void kernel_launch(void* const* d_in, const int* in_sizes, int n_in,
                              void* d_out, int out_size, void* d_ws,
                              size_t ws_size, hipStream_t stream) {
  const float* x2 = (const float*)d_in[1];
  const float* W1 = (const float*)d_in[2];
  const float* b1 = (const float*)d_in[3];
  const float* W2 = (const float*)d_in[4];
  const float* b2 = (const float*)d_in[5];
  const float* W3 = (const float*)d_in[6];
  const float* b3 = (const float*)d_in[7];
  const float* W4 = (const float*)d_in[8];
  const float* b4 = (const float*)d_in[9];
  const float* gamma1 = (const float*)d_in[10];
  const float* beta1 = (const float*)d_in[11];
  const float* gamma2 = (const float*)d_in[12];
  const float* beta2 = (const float*)d_in[13];
  const float* gamma3 = (const float*)d_in[14];
  const float* beta3 = (const float*)d_in[15];
  float* out = (float*)d_out;

  const int N = in_sizes[1] / 3;  // 262144
  const float invN = 1.0f / (float)N;

  // --- tiny scratch layout (~607 KB total) ---
  float* stats = (float*)d_ws;
  float* gsum1 = stats;          // 64
  float* gsq1 = gsum1 + 64;      // 64
  float* gsum2 = gsq1 + 64;      // 512
  float* gsq2 = gsum2 + 512;     // 512
  float* gsum3 = gsq2 + 512;     // 512
  float* gsq3 = gsum3 + 512;     // 512
  const int nstats = 64 * 2 + 512 * 4;  // 2176
  float* fold1 = stats + 2176;   // 256
  float* scale2 = fold1 + 256;   // 512
  float* shift2f = scale2 + 512; // 512
  float* scale3 = shift2f + 512; // 512
  float* shift3f = scale3 + 512; // 512
  __bf16* W2bf = (__bf16*)(shift3f + 512);  // 32768 elems (64 KB)
  __bf16* W3bf = W2bf + 32768;              // 262144 elems (512 KB)

  prep_kernel<<<1024, 256, 0, stream>>>(W2, W3, W2bf, W3bf, stats, nstats);
  stats1_kernel<<<N / 128, 256, 0, stream>>>(x2, W1, b1, gsum1, gsq1);
  finalize1_kernel<<<1, 64, 0, stream>>>(gsum1, gsq1, gamma1, beta1, W1, b1,
                                         fold1, invN);
  fused_kernel<0><<<N / 64, 256, 0, stream>>>(
      x2, fold1, W2bf, b2, scale2, shift2f, W3bf, b3, scale3, shift3f, W4, b4,
      gsum2, gsq2, gsum3, gsq3, out);
  finalize23_kernel<<<1, 512, 0, stream>>>(gsum2, gsq2, gamma2, beta2, b2,
                                           scale2, shift2f, invN);
  fused_kernel<1><<<N / 64, 256, 0, stream>>>(
      x2, fold1, W2bf, b2, scale2, shift2f, W3bf, b3, scale3, shift3f, W4, b4,
      gsum2, gsq2, gsum3, gsq3, out);
  finalize23_kernel<<<1, 512, 0, stream>>>(gsum3, gsq3, gamma3, beta3, b3,
                                           scale3, shift3f, invN);
  fused_kernel<2><<<N / 64, 256, 0, stream>>>(
      x2, fold1, W2bf, b2, scale2, shift2f, W3bf, b3, scale3, shift3f, W4, b4,
      gsum2, gsq2, gsum3, gsq3, out);
}

// Round 3
// 1433.836 us; speedup vs baseline: 1.0576x; 1.0576x over previous
//
#include <hip/hip_runtime.h>

typedef __bf16 bf16x4 __attribute__((ext_vector_type(4)));
typedef __bf16 bf16x8 __attribute__((ext_vector_type(8)));
typedef float f32x4 __attribute__((ext_vector_type(4)));

#define MFMA_BF16 __builtin_amdgcn_mfma_f32_16x16x32_bf16

// Swizzled element index for [rows][C] bf16 LDS tiles: XOR 16B-chunk id with row&7.
__device__ __forceinline__ int swz64(int row, int col) {
  return row * 64 + (((col >> 3) ^ (row & 7)) << 3) + (col & 7);
}
__device__ __forceinline__ int swz512(int row, int col) {
  return row * 512 + (((col >> 3) ^ (row & 7)) << 3) + (col & 7);
}

// ---------------------------------------------------------------------------
// prep: zero accumulators (5312 f32), cast W2/W3 to bf16
// ---------------------------------------------------------------------------
__global__ __launch_bounds__(256) void prep_kernel(
    const float* __restrict__ W2, const float* __restrict__ W3,
    __bf16* __restrict__ W2bf, __bf16* __restrict__ W3bf,
    float* __restrict__ stats) {
  int i = blockIdx.x * 256 + threadIdx.x;
  if (i < 32768) W2bf[i] = (__bf16)W2[i];
  if (i < 262144) W3bf[i] = (__bf16)W3[i];
  if (i < 5312) stats[i] = 0.f;
}

// ---------------------------------------------------------------------------
// stats1: column stats of y1 = x2 @ W1^T + b1 (no store)
// ---------------------------------------------------------------------------
__global__ __launch_bounds__(256) void stats1_kernel(
    const float* __restrict__ x, const float* __restrict__ W1,
    const float* __restrict__ b1, float* __restrict__ gsum,
    float* __restrict__ gsq) {
  int t = threadIdx.x;
  int c = t & 63;
  int rw = t >> 6;
  float w0 = W1[c * 3 + 0], w1 = W1[c * 3 + 1], w2 = W1[c * 3 + 2];
  float b = b1[c];
  int base = blockIdx.x * 128;
  float sum = 0.f, sq = 0.f;
#pragma unroll 4
  for (int i = 0; i < 32; ++i) {
    int row = base + i * 4 + rw;
    const float* xp = x + (size_t)row * 3;
    float y = fmaf(xp[0], w0, fmaf(xp[1], w1, fmaf(xp[2], w2, b)));
    sum += y;
    sq += y * y;
  }
  __shared__ float ssum[256], ssq[256];
  ssum[t] = sum;
  ssq[t] = sq;
  __syncthreads();
  if (t < 64) {
    float s = ssum[t] + ssum[t + 64] + ssum[t + 128] + ssum[t + 192];
    float q = ssq[t] + ssq[t + 64] + ssq[t + 128] + ssq[t + 192];
    atomicAdd(&gsum[t], s);
    atomicAdd(&gsq[t], q);
  }
}

// ---------------------------------------------------------------------------
// finalize1: fold BN1 scale/shift with W1,b1 into 4 coeffs per column
// ---------------------------------------------------------------------------
__global__ void finalize1_kernel(const float* __restrict__ gsum,
                                 const float* __restrict__ gsq,
                                 const float* __restrict__ gamma,
                                 const float* __restrict__ beta,
                                 const float* __restrict__ W1,
                                 const float* __restrict__ b1,
                                 float* __restrict__ fold1, float invN) {
  int c = threadIdx.x;  // 64
  float mu = gsum[c] * invN;
  float var = gsq[c] * invN - mu * mu;
  float sc = gamma[c] * rsqrtf(var + 1e-5f);
  float sh = beta[c] - mu * sc;
  fold1[c] = sc * W1[c * 3 + 0];
  fold1[64 + c] = sc * W1[c * 3 + 1];
  fold1[128 + c] = sc * W1[c * 3 + 2];
  fold1[192 + c] = sc * b1[c] + sh;
}

// finalize BN3: scale[c], shiftf[c] = scale*b + shift
__global__ void finalize3_kernel(const float* __restrict__ gsum,
                                 const float* __restrict__ gsq,
                                 const float* __restrict__ gamma,
                                 const float* __restrict__ beta,
                                 const float* __restrict__ b,
                                 float* __restrict__ scale,
                                 float* __restrict__ shiftf, float invN) {
  int c = blockIdx.x * blockDim.x + threadIdx.x;
  if (c >= 512) return;
  float mu = gsum[c] * invN;
  float var = gsq[c] * invN - mu * mu;
  float sc = gamma[c] * rsqrtf(var + 1e-5f);
  float sh = beta[c] - mu * sc;
  scale[c] = sc;
  shiftf[c] = sc * b[c] + sh;
}

// ---------------------------------------------------------------------------
// m1: M1 = sum_r h1_r h1_r^T (64x64) and s1 = sum_r h1_r, via MFMA SYRK.
// 128 blocks x 2048 rows (32 subtiles of 64). h1T staged [64 cols][72 pad].
// ---------------------------------------------------------------------------
__global__ __launch_bounds__(256) void m1_kernel(const float* __restrict__ x2,
                                                 const float* __restrict__ fold1,
                                                 float* __restrict__ M1,
                                                 float* __restrict__ s1) {
  __shared__ __bf16 h1T[64 * 72];
  const int t = threadIdx.x;
  const int lane = t & 63, wave = t >> 6;
  const int lrow = lane & 15, lgrp = lane >> 4;
  const int r = t >> 2, c0 = (t & 3) * 16;

  float f0[16], f1[16], f2[16], f3[16];
#pragma unroll
  for (int j = 0; j < 16; ++j) {
    f0[j] = fold1[c0 + j];
    f1[j] = fold1[64 + c0 + j];
    f2[j] = fold1[128 + c0 + j];
    f3[j] = fold1[192 + c0 + j];
  }

  f32x4 acc[4] = {};
  float sAcc[16] = {};

  for (int sub = 0; sub < 32; ++sub) {
    int row = blockIdx.x * 2048 + sub * 64 + r;
    const float* xp = x2 + (size_t)row * 3;
    float X0 = xp[0], X1 = xp[1], X2 = xp[2];
    __syncthreads();  // protect h1T from previous subtile's readers
#pragma unroll
    for (int j = 0; j < 16; ++j) {
      float h = fmaxf(fmaf(f0[j], X0, fmaf(f1[j], X1, fmaf(f2[j], X2, f3[j]))),
                      0.f);
      sAcc[j] += h;
      h1T[(c0 + j) * 72 + r] = (__bf16)h;
    }
    __syncthreads();
#pragma unroll
    for (int kk = 0; kk < 64; kk += 32) {
      bf16x8 af =
          *(const bf16x8*)&h1T[(wave * 16 + lrow) * 72 + kk + lgrp * 8];
#pragma unroll
      for (int n = 0; n < 4; ++n) {
        bf16x8 bfr = *(const bf16x8*)&h1T[(n * 16 + lrow) * 72 + kk + lgrp * 8];
        acc[n] = MFMA_BF16(af, bfr, acc[n], 0, 0, 0);
      }
    }
  }
  // M1 accumulate: D[i][j], i = wave*16 + lgrp*4 + rr, j = n*16 + lrow
#pragma unroll
  for (int n = 0; n < 4; ++n)
#pragma unroll
    for (int rr = 0; rr < 4; ++rr)
      atomicAdd(&M1[(wave * 16 + lgrp * 4 + rr) * 64 + n * 16 + lrow],
                acc[n][rr]);
  // s1: reduce over the 16 lanes sharing (lane&3) => 16 distinct rows
#pragma unroll
  for (int j = 0; j < 16; ++j) {
    float v = sAcc[j];
    v += __shfl_xor(v, 4);
    v += __shfl_xor(v, 8);
    v += __shfl_xor(v, 16);
    v += __shfl_xor(v, 32);
    if (lane < 4) atomicAdd(&s1[(lane & 3) * 16 + j], v);
  }
}

// ---------------------------------------------------------------------------
// finalize2v: per col c of layer 2, q = w^T M1 w; derive BN2 scale/shiftf.
// one wave per column; lane i holds w_i. M1 staged padded [64][65].
// ---------------------------------------------------------------------------
__global__ __launch_bounds__(256) void finalize2v_kernel(
    const float* __restrict__ M1, const float* __restrict__ s1,
    const float* __restrict__ W2, const float* __restrict__ b2,
    const float* __restrict__ gamma2, const float* __restrict__ beta2,
    float* __restrict__ scale2, float* __restrict__ shift2f, float fN) {
  __shared__ float sM[64 * 65];
  __shared__ float ss[64];
  int t = threadIdx.x;
  for (int i = t; i < 4096; i += 256) sM[(i >> 6) * 65 + (i & 63)] = M1[i];
  if (t < 64) ss[t] = s1[t];
  __syncthreads();
  int lane = t & 63;
  int col = blockIdx.x * 4 + (t >> 6);
  float wi = W2[(size_t)col * 64 + lane];
  float p = 0.f;
#pragma unroll
  for (int j = 0; j < 64; ++j) p = fmaf(sM[lane * 65 + j], __shfl(wi, j), p);
  float qi = wi * p;
  float swi = ss[lane] * wi;
#pragma unroll
  for (int off = 1; off < 64; off <<= 1) {
    qi += __shfl_xor(qi, off);
    swi += __shfl_xor(swi, off);
  }
  if (lane == 0) {
    float b = b2[col];
    float sy = swi + fN * b;
    float sqs = qi + 2.f * b * swi + fN * b * b;
    float mu = sy / fN;
    float var = sqs / fN - mu * mu;
    float sc = gamma2[col] * rsqrtf(var + 1e-5f);
    scale2[col] = sc;
    shift2f[col] = (beta2[col] - mu * sc) + sc * b;
  }
}

// ---------------------------------------------------------------------------
// Fused recompute kernel, 64 rows/block, 4 waves (2m x 2n).
//   h1 staged (swizzled); GEMM2 swapped-operand -> h2 b64 writes;
//   GEMM3 4-deep software-pipelined B prefetch from L2.
// MODE 1: GEMM3 -> stats3.  MODE 2: GEMM3 -> BN3+ReLU+@W4 -> out.
// ---------------------------------------------------------------------------
#define G3_PHASE(BUF, KOFF)                                                    \
  {                                                                            \
    bf16x8 af0 =                                                               \
        *(const bf16x8*)&h2[swz512(wm * 32 + lrow, k0 + (KOFF) + lgrp * 8)];   \
    bf16x8 af1 = *(const bf16x8*)&h2[swz512(wm * 32 + 16 + lrow,               \
                                            k0 + (KOFF) + lgrp * 8)];          \
    _Pragma("unroll") for (int n = 0; n < 4; ++n) {                            \
      acc[0][n] = MFMA_BF16(af0, BUF[n], acc[0][n], 0, 0, 0);                  \
      acc[1][n] = MFMA_BF16(af1, BUF[n], acc[1][n], 0, 0, 0);                  \
    }                                                                          \
    if (kq < 3) {                                                              \
      _Pragma("unroll") for (int n = 0; n < 4; ++n) BUF[n] =                   \
          *(const bf16x8*)(bp[n] + k0 + (KOFF) + 128);                         \
    }                                                                          \
  }

template <int MODE>
__global__ __launch_bounds__(256, 2) void fused_kernel(
    const float* __restrict__ x2, const float* __restrict__ fold1,
    const __bf16* __restrict__ W2bf, const float* __restrict__ scale2,
    const float* __restrict__ shift2f, const __bf16* __restrict__ W3bf,
    const float* __restrict__ b3, const float* __restrict__ scale3,
    const float* __restrict__ shift3f, const float* __restrict__ W4,
    const float* __restrict__ b4, float* __restrict__ gsum3,
    float* __restrict__ gsq3, float* __restrict__ out) {
  __shared__ float xs[64][4];
  __shared__ __bf16 h1[64 * 64];
  __shared__ __bf16 h2[64 * 512];
  __shared__ float sSc2[512], sSh2[512];
  __shared__ float outacc[64][2];

  const int t = threadIdx.x;
  const int rBase = blockIdx.x * 64;
  const int lane = t & 63, wave = t >> 6;
  const int wm = wave >> 1, wn = wave & 1;
  const int lrow = lane & 15, lgrp = lane >> 4;

  for (int i = t; i < 512; i += 256) {
    sSc2[i] = scale2[i];
    sSh2[i] = shift2f[i];
  }
  if (t < 192) xs[t / 3][t % 3] = x2[(size_t)rBase * 3 + t];
  if (MODE == 2 && t < 128) outacc[t >> 1][t & 1] = 0.f;
  __syncthreads();

  // ---- stage h1 (folded BN1, swizzled) ----
  {
    int r = t >> 2, c0 = (t & 3) * 16;
    float X0 = xs[r][0], X1 = xs[r][1], X2 = xs[r][2];
    bf16x8 o8[2];
#pragma unroll
    for (int j = 0; j < 16; ++j) {
      int c = c0 + j;
      float h = fmaf(fold1[c], X0,
                     fmaf(fold1[64 + c], X1,
                          fmaf(fold1[128 + c], X2, fold1[192 + c])));
      o8[j >> 3][j & 7] = (__bf16)fmaxf(h, 0.f);
    }
#pragma unroll
    for (int q = 0; q < 2; ++q) {
      int chunk = (c0 >> 3) + q;
      *(bf16x8*)&h1[r * 64 + ((chunk ^ (r & 7)) << 3)] = o8[q];
    }
  }
  __syncthreads();

  // ---- GEMM2 (swapped operands): h2 = relu(scale2*(h1@W2^T)+shift2f) ----
#pragma unroll 1
  for (int ch = 0; ch < 4; ++ch) {
    const int colb = ch * 128 + wn * 64;
    bf16x8 bw0[4], bw1[4];
#pragma unroll
    for (int n = 0; n < 4; ++n) {
      const __bf16* wp = W2bf + (size_t)(colb + n * 16 + lrow) * 64 + lgrp * 8;
      bw0[n] = *(const bf16x8*)(wp);
      bw1[n] = *(const bf16x8*)(wp + 32);
    }
    f32x4 a2[4][2] = {};
    {
      bf16x8 af0 = *(const bf16x8*)&h1[swz64(wm * 32 + lrow, lgrp * 8)];
      bf16x8 af1 = *(const bf16x8*)&h1[swz64(wm * 32 + 16 + lrow, lgrp * 8)];
#pragma unroll
      for (int n = 0; n < 4; ++n) {
        a2[n][0] = MFMA_BF16(bw0[n], af0, a2[n][0], 0, 0, 0);
        a2[n][1] = MFMA_BF16(bw0[n], af1, a2[n][1], 0, 0, 0);
      }
      af0 = *(const bf16x8*)&h1[swz64(wm * 32 + lrow, 32 + lgrp * 8)];
      af1 = *(const bf16x8*)&h1[swz64(wm * 32 + 16 + lrow, 32 + lgrp * 8)];
#pragma unroll
      for (int n = 0; n < 4; ++n) {
        a2[n][0] = MFMA_BF16(bw1[n], af0, a2[n][0], 0, 0, 0);
        a2[n][1] = MFMA_BF16(bw1[n], af1, a2[n][1], 0, 0, 0);
      }
    }
    // epilogue: lane holds 4 consecutive CHANNELS (lgrp*4+rr) at row lrow
#pragma unroll
    for (int n = 0; n < 4; ++n) {
      int c0 = colb + n * 16 + lgrp * 4;
      float sc0 = sSc2[c0], sc1 = sSc2[c0 + 1], sc2v = sSc2[c0 + 2],
            sc3v = sSc2[c0 + 3];
      float sh0 = sSh2[c0], sh1 = sSh2[c0 + 1], sh2v = sSh2[c0 + 2],
            sh3v = sSh2[c0 + 3];
#pragma unroll
      for (int m = 0; m < 2; ++m) {
        int row = wm * 32 + m * 16 + lrow;
        bf16x4 hv;
        hv[0] = (__bf16)fmaxf(fmaf(sc0, a2[n][m][0], sh0), 0.f);
        hv[1] = (__bf16)fmaxf(fmaf(sc1, a2[n][m][1], sh1), 0.f);
        hv[2] = (__bf16)fmaxf(fmaf(sc2v, a2[n][m][2], sh2v), 0.f);
        hv[3] = (__bf16)fmaxf(fmaf(sc3v, a2[n][m][3], sh3v), 0.f);
        *(bf16x4*)&h2[swz512(row, c0)] = hv;
      }
    }
  }
  __syncthreads();

  // ---- GEMM3, 4-deep pipelined B prefetch ----
  float d0[2][4], d1[2][4];
  if (MODE == 2) {
#pragma unroll
    for (int m = 0; m < 2; ++m)
#pragma unroll
      for (int rr = 0; rr < 4; ++rr) d0[m][rr] = d1[m][rr] = 0.f;
  }
#pragma unroll 1
  for (int ch = 0; ch < 4; ++ch) {
    const int colb = ch * 128 + wn * 64;
    const __bf16* bp[4];
    bf16x8 bA[4], bB[4], bC[4], bD[4];
#pragma unroll
    for (int n = 0; n < 4; ++n) {
      bp[n] = W3bf + (size_t)(colb + n * 16 + lrow) * 512 + lgrp * 8;
      bA[n] = *(const bf16x8*)(bp[n]);
      bB[n] = *(const bf16x8*)(bp[n] + 32);
      bC[n] = *(const bf16x8*)(bp[n] + 64);
      bD[n] = *(const bf16x8*)(bp[n] + 96);
    }
    f32x4 acc[2][4] = {};
#pragma unroll
    for (int kq = 0; kq < 4; ++kq) {
      const int k0 = kq * 128;
      G3_PHASE(bA, 0)
      G3_PHASE(bB, 32)
      G3_PHASE(bC, 64)
      G3_PHASE(bD, 96)
    }
    // ---- per-chunk epilogue ----
#pragma unroll
    for (int n = 0; n < 4; ++n) {
      int col = colb + n * 16 + lrow;
      if (MODE == 1) {
        float bcol = b3[col];
        float cs = 0.f, cq = 0.f;
#pragma unroll
        for (int m = 0; m < 2; ++m)
#pragma unroll
          for (int rr = 0; rr < 4; ++rr) {
            float y = acc[m][n][rr] + bcol;
            cs += y;
            cq += y * y;
          }
        cs += __shfl_xor(cs, 16);
        cq += __shfl_xor(cq, 16);
        cs += __shfl_xor(cs, 32);
        cq += __shfl_xor(cq, 32);
        if (lgrp == 0) {
          atomicAdd(&gsum3[col], cs);
          atomicAdd(&gsq3[col], cq);
        }
      } else {
        float sc = scale3[col], sh = shift3f[col];
        float w40 = W4[col], w41 = W4[512 + col];
#pragma unroll
        for (int m = 0; m < 2; ++m)
#pragma unroll
          for (int rr = 0; rr < 4; ++rr) {
            float h = fmaxf(fmaf(sc, acc[m][n][rr], sh), 0.f);
            d0[m][rr] = fmaf(h, w40, d0[m][rr]);
            d1[m][rr] = fmaf(h, w41, d1[m][rr]);
          }
      }
    }
  }

  if (MODE == 2) {
#pragma unroll
    for (int m = 0; m < 2; ++m)
#pragma unroll
      for (int rr = 0; rr < 4; ++rr) {
#pragma unroll
        for (int off = 1; off < 16; off <<= 1) {
          d0[m][rr] += __shfl_xor(d0[m][rr], off);
          d1[m][rr] += __shfl_xor(d1[m][rr], off);
        }
        if (lrow == 0) {
          int row = wm * 32 + m * 16 + lgrp * 4 + rr;
          atomicAdd(&outacc[row][0], d0[m][rr]);
          atomicAdd(&outacc[row][1], d1[m][rr]);
        }
      }
    __syncthreads();
    if (t < 128) {
      int row = t >> 1, o = t & 1;
      out[(size_t)(rBase + row) * 2 + o] = outacc[row][o] + b4[o];
    }
  }
}

// ---------------------------------------------------------------------------
extern "C" void kernel_launch(void* const* d_in, const int* in_sizes, int n_in,
                              void* d_out, int out_size, void* d_ws,
                              size_t ws_size, hipStream_t stream) {
  const float* x2 = (const float*)d_in[1];
  const float* W1 = (const float*)d_in[2];
  const float* b1 = (const float*)d_in[3];
  const float* W2 = (const float*)d_in[4];
  const float* b2 = (const float*)d_in[5];
  const float* W3 = (const float*)d_in[6];
  const float* b3 = (const float*)d_in[7];
  const float* W4 = (const float*)d_in[8];
  const float* b4 = (const float*)d_in[9];
  const float* gamma1 = (const float*)d_in[10];
  const float* beta1 = (const float*)d_in[11];
  const float* gamma2 = (const float*)d_in[12];
  const float* beta2 = (const float*)d_in[13];
  const float* gamma3 = (const float*)d_in[14];
  const float* beta3 = (const float*)d_in[15];
  float* out = (float*)d_out;

  const int N = in_sizes[1] / 3;  // 262144
  const float invN = 1.0f / (float)N;

  // --- scratch layout (~606 KB) ---
  float* f0 = (float*)d_ws;
  float* gsum1 = f0;             // 64
  float* gsq1 = f0 + 64;         // 64
  float* M1 = f0 + 128;          // 4096
  float* s1 = f0 + 4224;         // 64
  float* gsum3 = f0 + 4288;      // 512
  float* gsq3 = f0 + 4800;       // 512  (zeroed region ends at 5312)
  float* fold1 = f0 + 5312;      // 256
  float* scale2 = f0 + 5568;     // 512
  float* shift2f = f0 + 6080;    // 512
  float* scale3 = f0 + 6592;     // 512
  float* shift3f = f0 + 7104;    // 512
  __bf16* W2bf = (__bf16*)(f0 + 7616);  // 32768
  __bf16* W3bf = W2bf + 32768;          // 262144

  prep_kernel<<<1024, 256, 0, stream>>>(W2, W3, W2bf, W3bf, f0);
  stats1_kernel<<<N / 128, 256, 0, stream>>>(x2, W1, b1, gsum1, gsq1);
  finalize1_kernel<<<1, 64, 0, stream>>>(gsum1, gsq1, gamma1, beta1, W1, b1,
                                         fold1, invN);
  m1_kernel<<<128, 256, 0, stream>>>(x2, fold1, M1, s1);
  finalize2v_kernel<<<128, 256, 0, stream>>>(M1, s1, W2, b2, gamma2, beta2,
                                             scale2, shift2f, (float)N);
  fused_kernel<1><<<N / 64, 256, 0, stream>>>(
      x2, fold1, W2bf, scale2, shift2f, W3bf, b3, scale3, shift3f, W4, b4,
      gsum3, gsq3, out);
  finalize3_kernel<<<1, 512, 0, stream>>>(gsum3, gsq3, gamma3, beta3, b3,
                                          scale3, shift3f, invN);
  fused_kernel<2><<<N / 64, 256, 0, stream>>>(
      x2, fold1, W2bf, scale2, shift2f, W3bf, b3, scale3, shift3f, W4, b4,
      gsum3, gsq3, out);
}

// Round 4
// 922.854 us; speedup vs baseline: 1.6432x; 1.5537x over previous
//
#include <hip/hip_runtime.h>

typedef __bf16 bf16x4 __attribute__((ext_vector_type(4)));
typedef __bf16 bf16x8 __attribute__((ext_vector_type(8)));
typedef float f32x4 __attribute__((ext_vector_type(4)));

#define MFMA_BF16 __builtin_amdgcn_mfma_f32_16x16x32_bf16

// Swizzled element index for [rows][C] bf16 LDS tiles: XOR 16B-chunk id with row&7.
__device__ __forceinline__ int swz64(int row, int col) {
  return row * 64 + (((col >> 3) ^ (row & 7)) << 3) + (col & 7);
}
__device__ __forceinline__ int swz512(int row, int col) {
  return row * 512 + (((col >> 3) ^ (row & 7)) << 3) + (col & 7);
}

// ---------------------------------------------------------------------------
// prep: zero accumulators (5312 f32), cast W2/W3 to bf16
// ---------------------------------------------------------------------------
__global__ __launch_bounds__(256) void prep_kernel(
    const float* __restrict__ W2, const float* __restrict__ W3,
    __bf16* __restrict__ W2bf, __bf16* __restrict__ W3bf,
    float* __restrict__ stats) {
  int i = blockIdx.x * 256 + threadIdx.x;
  if (i < 32768) W2bf[i] = (__bf16)W2[i];
  if (i < 262144) W3bf[i] = (__bf16)W3[i];
  if (i < 5312) stats[i] = 0.f;
}

// ---------------------------------------------------------------------------
// stats1: column stats of y1 = x2 @ W1^T + b1 (no store)
// ---------------------------------------------------------------------------
__global__ __launch_bounds__(256) void stats1_kernel(
    const float* __restrict__ x, const float* __restrict__ W1,
    const float* __restrict__ b1, float* __restrict__ gsum,
    float* __restrict__ gsq) {
  int t = threadIdx.x;
  int c = t & 63;
  int rw = t >> 6;
  float w0 = W1[c * 3 + 0], w1 = W1[c * 3 + 1], w2 = W1[c * 3 + 2];
  float b = b1[c];
  int base = blockIdx.x * 128;
  float sum = 0.f, sq = 0.f;
#pragma unroll 4
  for (int i = 0; i < 32; ++i) {
    int row = base + i * 4 + rw;
    const float* xp = x + (size_t)row * 3;
    float y = fmaf(xp[0], w0, fmaf(xp[1], w1, fmaf(xp[2], w2, b)));
    sum += y;
    sq += y * y;
  }
  __shared__ float ssum[256], ssq[256];
  ssum[t] = sum;
  ssq[t] = sq;
  __syncthreads();
  if (t < 64) {
    float s = ssum[t] + ssum[t + 64] + ssum[t + 128] + ssum[t + 192];
    float q = ssq[t] + ssq[t + 64] + ssq[t + 128] + ssq[t + 192];
    atomicAdd(&gsum[t], s);
    atomicAdd(&gsq[t], q);
  }
}

// ---------------------------------------------------------------------------
// finalize1: fold BN1 scale/shift with W1,b1 into 4 coeffs per column
// ---------------------------------------------------------------------------
__global__ void finalize1_kernel(const float* __restrict__ gsum,
                                 const float* __restrict__ gsq,
                                 const float* __restrict__ gamma,
                                 const float* __restrict__ beta,
                                 const float* __restrict__ W1,
                                 const float* __restrict__ b1,
                                 float* __restrict__ fold1, float invN) {
  int c = threadIdx.x;  // 64
  float mu = gsum[c] * invN;
  float var = gsq[c] * invN - mu * mu;
  float sc = gamma[c] * rsqrtf(var + 1e-5f);
  float sh = beta[c] - mu * sc;
  fold1[c] = sc * W1[c * 3 + 0];
  fold1[64 + c] = sc * W1[c * 3 + 1];
  fold1[128 + c] = sc * W1[c * 3 + 2];
  fold1[192 + c] = sc * b1[c] + sh;
}

// finalize BN3: scale[c], shiftf[c] = scale*b + shift
__global__ void finalize3_kernel(const float* __restrict__ gsum,
                                 const float* __restrict__ gsq,
                                 const float* __restrict__ gamma,
                                 const float* __restrict__ beta,
                                 const float* __restrict__ b,
                                 float* __restrict__ scale,
                                 float* __restrict__ shiftf, float invN) {
  int c = blockIdx.x * blockDim.x + threadIdx.x;
  if (c >= 512) return;
  float mu = gsum[c] * invN;
  float var = gsq[c] * invN - mu * mu;
  float sc = gamma[c] * rsqrtf(var + 1e-5f);
  float sh = beta[c] - mu * sc;
  scale[c] = sc;
  shiftf[c] = sc * b[c] + sh;
}

// ---------------------------------------------------------------------------
// m1: M1 = sum_r h1_r h1_r^T (64x64) and s1 = sum_r h1_r, via MFMA SYRK.
// 256 blocks x 1024 rows (16 subtiles of 64). h1T staged [64 cols][72 pad].
// ---------------------------------------------------------------------------
__global__ __launch_bounds__(256) void m1_kernel(const float* __restrict__ x2,
                                                 const float* __restrict__ fold1,
                                                 float* __restrict__ M1,
                                                 float* __restrict__ s1) {
  __shared__ __bf16 h1T[64 * 72];
  const int t = threadIdx.x;
  const int lane = t & 63, wave = t >> 6;
  const int lrow = lane & 15, lgrp = lane >> 4;
  const int r = t >> 2, c0 = (t & 3) * 16;

  float f0[16], f1[16], f2[16], f3[16];
#pragma unroll
  for (int j = 0; j < 16; ++j) {
    f0[j] = fold1[c0 + j];
    f1[j] = fold1[64 + c0 + j];
    f2[j] = fold1[128 + c0 + j];
    f3[j] = fold1[192 + c0 + j];
  }

  f32x4 acc[4] = {};
  float sAcc[16] = {};

  for (int sub = 0; sub < 16; ++sub) {
    int row = blockIdx.x * 1024 + sub * 64 + r;
    const float* xp = x2 + (size_t)row * 3;
    float X0 = xp[0], X1 = xp[1], X2 = xp[2];
    __syncthreads();  // protect h1T from previous subtile's readers
#pragma unroll
    for (int j = 0; j < 16; ++j) {
      float h = fmaxf(fmaf(f0[j], X0, fmaf(f1[j], X1, fmaf(f2[j], X2, f3[j]))),
                      0.f);
      sAcc[j] += h;
      h1T[(c0 + j) * 72 + r] = (__bf16)h;
    }
    __syncthreads();
#pragma unroll
    for (int kk = 0; kk < 64; kk += 32) {
      bf16x8 af =
          *(const bf16x8*)&h1T[(wave * 16 + lrow) * 72 + kk + lgrp * 8];
#pragma unroll
      for (int n = 0; n < 4; ++n) {
        bf16x8 bfr = *(const bf16x8*)&h1T[(n * 16 + lrow) * 72 + kk + lgrp * 8];
        acc[n] = MFMA_BF16(af, bfr, acc[n], 0, 0, 0);
      }
    }
  }
#pragma unroll
  for (int n = 0; n < 4; ++n)
#pragma unroll
    for (int rr = 0; rr < 4; ++rr)
      atomicAdd(&M1[(wave * 16 + lgrp * 4 + rr) * 64 + n * 16 + lrow],
                acc[n][rr]);
#pragma unroll
  for (int j = 0; j < 16; ++j) {
    float v = sAcc[j];
    v += __shfl_xor(v, 4);
    v += __shfl_xor(v, 8);
    v += __shfl_xor(v, 16);
    v += __shfl_xor(v, 32);
    if (lane < 4) atomicAdd(&s1[(lane & 3) * 16 + j], v);
  }
}

// ---------------------------------------------------------------------------
// finalize2v: per col c of layer 2, q = w^T M1 w; derive BN2 scale/shiftf.
// ---------------------------------------------------------------------------
__global__ __launch_bounds__(256) void finalize2v_kernel(
    const float* __restrict__ M1, const float* __restrict__ s1,
    const float* __restrict__ W2, const float* __restrict__ b2,
    const float* __restrict__ gamma2, const float* __restrict__ beta2,
    float* __restrict__ scale2, float* __restrict__ shift2f, float fN) {
  __shared__ float sM[64 * 65];
  __shared__ float ss[64];
  int t = threadIdx.x;
  for (int i = t; i < 4096; i += 256) sM[(i >> 6) * 65 + (i & 63)] = M1[i];
  if (t < 64) ss[t] = s1[t];
  __syncthreads();
  int lane = t & 63;
  int col = blockIdx.x * 4 + (t >> 6);
  float wi = W2[(size_t)col * 64 + lane];
  float p = 0.f;
#pragma unroll
  for (int j = 0; j < 64; ++j) p = fmaf(sM[lane * 65 + j], __shfl(wi, j), p);
  float qi = wi * p;
  float swi = ss[lane] * wi;
#pragma unroll
  for (int off = 1; off < 64; off <<= 1) {
    qi += __shfl_xor(qi, off);
    swi += __shfl_xor(swi, off);
  }
  if (lane == 0) {
    float b = b2[col];
    float sy = swi + fN * b;
    float sqs = qi + 2.f * b * swi + fN * b * b;
    float mu = sy / fN;
    float var = sqs / fN - mu * mu;
    float sc = gamma2[col] * rsqrtf(var + 1e-5f);
    scale2[col] = sc;
    shift2f[col] = (beta2[col] - mu * sc) + sc * b;
  }
}

// ---------------------------------------------------------------------------
// Fused kernel, register-resident W3.
// 512 threads (8 waves). grid = 256 rowBlocks x 2 colHalves.
// Wave w owns W3 cols [colHalf*256 + w*32, +32) as 32 bf16x8 register frags.
// Per row-group (64 rows, 16 per block): stage h1 -> GEMM2 (h2 to LDS,
// wave w computes channels [w*64,+64)) -> GEMM3 inner loop = pure
// {4 ds_read_b128 + 8 MFMA} per k-step.
// MODE 1: accumulate col stats of y3 in regs across rgs, atomics at end.
// MODE 2: BN3+ReLU+ @W4 -> out (pre-zeroed, cross-half atomicAdd).
// ---------------------------------------------------------------------------
template <int MODE>
__global__ __launch_bounds__(512, 2) void fused_kernel(
    const float* __restrict__ x2, const float* __restrict__ fold1,
    const __bf16* __restrict__ W2bf, const float* __restrict__ scale2,
    const float* __restrict__ shift2f, const __bf16* __restrict__ W3bf,
    const float* __restrict__ b3, const float* __restrict__ scale3,
    const float* __restrict__ shift3f, const float* __restrict__ W4,
    const float* __restrict__ b4, float* __restrict__ gsum3,
    float* __restrict__ gsq3, float* __restrict__ out) {
  __shared__ __bf16 h1[64 * 64];     // 8 KB  (swizzled)
  __shared__ __bf16 h2[64 * 512];    // 64 KB (swizzled)
  __shared__ __bf16 sW2[512 * 64];   // 64 KB (swizzled, [channel][k])
  __shared__ float sF[256];
  __shared__ float sSc2[512], sSh2[512];
  __shared__ float outaccW[8][64][2];  // 4 KB (MODE 2)

  const int t = threadIdx.x;
  const int lane = t & 63, wave = t >> 6;
  const int lrow = lane & 15, lgrp = lane >> 4;
  const int colHalf = blockIdx.x & 1;
  const int rowBlk = blockIdx.x >> 1;
  const int wCol3 = colHalf * 256 + wave * 32;  // GEMM3 col base (this wave)
  const int wCol2 = wave * 64;                  // GEMM2 channel base

  // ---- one-time LDS staging ----
  if (t < 256) sF[t] = fold1[t];
  {
    int i = t;
    if (i < 512) {
      sSc2[i] = scale2[i];
      sSh2[i] = shift2f[i];
    }
  }
#pragma unroll
  for (int i = 0; i < 8; ++i) {
    int seg = i * 512 + t;  // 4096 chunks of 8 bf16
    int ch = seg >> 3;
    int c0 = (seg & 7) * 8;
    bf16x8 v = *(const bf16x8*)&W2bf[ch * 64 + c0];
    *(bf16x8*)&sW2[ch * 64 + (((c0 >> 3) ^ (ch & 7)) << 3)] = v;
  }

  // ---- one-time: W3 fragments -> registers (128 VGPR, static indexing) ----
  bf16x8 b3r[16][2];
#pragma unroll
  for (int k = 0; k < 16; ++k)
#pragma unroll
    for (int n = 0; n < 2; ++n)
      b3r[k][n] = *(const bf16x8*)&W3bf[(size_t)(wCol3 + n * 16 + lrow) * 512 +
                                        k * 32 + lgrp * 8];

  // hoisted per-lane column params
  const int c3a = wCol3 + lrow, c3b = wCol3 + 16 + lrow;
  float b3a = 0.f, b3b = 0.f;
  float sc3a = 0.f, sc3b = 0.f, sh3a = 0.f, sh3b = 0.f;
  float w40a = 0.f, w40b = 0.f, w41a = 0.f, w41b = 0.f, B40 = 0.f, B41 = 0.f;
  if (MODE == 1) {
    b3a = b3[c3a];
    b3b = b3[c3b];
  } else {
    sc3a = scale3[c3a];
    sc3b = scale3[c3b];
    sh3a = shift3f[c3a];
    sh3b = shift3f[c3b];
    w40a = W4[c3a];
    w40b = W4[c3b];
    w41a = W4[512 + c3a];
    w41b = W4[512 + c3b];
    B40 = b4[0];
    B41 = b4[1];
  }
  float csA = 0.f, cqA = 0.f, csB = 0.f, cqB = 0.f;

  for (int g = 0; g < 16; ++g) {
    const int rBase = (rowBlk * 16 + g) * 64;

    // ---- stage h1 (+ zero outaccW) ----
    if (MODE == 2) {
      for (int i = t; i < 1024; i += 512) ((float*)outaccW)[i] = 0.f;
    }
    {
      int r = t >> 3, c0 = (t & 7) * 8;
      const float* xp = x2 + (size_t)(rBase + r) * 3;
      float X0 = xp[0], X1 = xp[1], X2v = xp[2];
      bf16x8 hv;
#pragma unroll
      for (int j = 0; j < 8; ++j) {
        int c = c0 + j;
        float h = fmaf(sF[c], X0,
                       fmaf(sF[64 + c], X1, fmaf(sF[128 + c], X2v, sF[192 + c])));
        hv[j] = (__bf16)fmaxf(h, 0.f);
      }
      *(bf16x8*)&h1[r * 64 + (((c0 >> 3) ^ (r & 7)) << 3)] = hv;
    }
    __syncthreads();

    // ---- GEMM2 (swapped operands): h2[:, wCol2..+64] ----
    {
      f32x4 a2[4][4] = {};  // [n][m]
#pragma unroll
      for (int kk = 0; kk < 2; ++kk) {
        bf16x8 af[4];
#pragma unroll
        for (int m = 0; m < 4; ++m)
          af[m] = *(const bf16x8*)&h1[swz64(m * 16 + lrow, kk * 32 + lgrp * 8)];
#pragma unroll
        for (int n = 0; n < 4; ++n) {
          int ch = wCol2 + n * 16 + lrow;
          bf16x8 bw = *(const bf16x8*)&sW2[ch * 64 +
              ((((kk * 32 + lgrp * 8) >> 3) ^ (ch & 7)) << 3)];
#pragma unroll
          for (int m = 0; m < 4; ++m)
            a2[n][m] = MFMA_BF16(bw, af[m], a2[n][m], 0, 0, 0);
        }
      }
      // write h2: channel = wCol2 + n*16 + lgrp*4 + rr, row = m*16 + lrow
#pragma unroll
      for (int n = 0; n < 4; ++n) {
        int ch0 = wCol2 + n * 16 + lgrp * 4;
        float s0 = sSc2[ch0], s1v = sSc2[ch0 + 1], s2v = sSc2[ch0 + 2],
              s3v = sSc2[ch0 + 3];
        float z0 = sSh2[ch0], z1 = sSh2[ch0 + 1], z2 = sSh2[ch0 + 2],
              z3 = sSh2[ch0 + 3];
#pragma unroll
        for (int m = 0; m < 4; ++m) {
          int row = m * 16 + lrow;
          bf16x4 hv;
          hv[0] = (__bf16)fmaxf(fmaf(s0, a2[n][m][0], z0), 0.f);
          hv[1] = (__bf16)fmaxf(fmaf(s1v, a2[n][m][1], z1), 0.f);
          hv[2] = (__bf16)fmaxf(fmaf(s2v, a2[n][m][2], z2), 0.f);
          hv[3] = (__bf16)fmaxf(fmaf(s3v, a2[n][m][3], z3), 0.f);
          *(bf16x4*)&h2[swz512(row, ch0)] = hv;
        }
      }
    }
    __syncthreads();

    // ---- GEMM3: pure LDS-read + register-B MFMA ----
    f32x4 acc[4][2] = {};  // [m][n]
#pragma unroll
    for (int k = 0; k < 16; ++k) {
      bf16x8 af[4];
#pragma unroll
      for (int m = 0; m < 4; ++m)
        af[m] = *(const bf16x8*)&h2[swz512(m * 16 + lrow, k * 32 + lgrp * 8)];
#pragma unroll
      for (int m = 0; m < 4; ++m) {
        acc[m][0] = MFMA_BF16(af[m], b3r[k][0], acc[m][0], 0, 0, 0);
        acc[m][1] = MFMA_BF16(af[m], b3r[k][1], acc[m][1], 0, 0, 0);
      }
    }

    if (MODE == 1) {
      // accumulate col stats in registers across row-groups
#pragma unroll
      for (int m = 0; m < 4; ++m)
#pragma unroll
        for (int rr = 0; rr < 4; ++rr) {
          float ya = acc[m][0][rr] + b3a;
          float yb = acc[m][1][rr] + b3b;
          csA += ya;
          cqA = fmaf(ya, ya, cqA);
          csB += yb;
          cqB = fmaf(yb, yb, cqB);
        }
    } else {
      // BN3 + ReLU + dot with W4 -> per-row partials
#pragma unroll
      for (int m = 0; m < 4; ++m)
#pragma unroll
        for (int rr = 0; rr < 4; ++rr) {
          float ha = fmaxf(fmaf(sc3a, acc[m][0][rr], sh3a), 0.f);
          float hb = fmaxf(fmaf(sc3b, acc[m][1][rr], sh3b), 0.f);
          float dd0 = fmaf(ha, w40a, hb * w40b);
          float dd1 = fmaf(ha, w41a, hb * w41b);
          dd0 += __shfl_xor(dd0, 1);
          dd1 += __shfl_xor(dd1, 1);
          dd0 += __shfl_xor(dd0, 2);
          dd1 += __shfl_xor(dd1, 2);
          dd0 += __shfl_xor(dd0, 4);
          dd1 += __shfl_xor(dd1, 4);
          dd0 += __shfl_xor(dd0, 8);
          dd1 += __shfl_xor(dd1, 8);
          if (lrow == 0) {
            int row = m * 16 + lgrp * 4 + rr;
            outaccW[wave][row][0] = dd0;
            outaccW[wave][row][1] = dd1;
          }
        }
      __syncthreads();
      if (t < 128) {
        int row = t >> 1, o = t & 1;
        float s = 0.f;
#pragma unroll
        for (int w = 0; w < 8; ++w) s += outaccW[w][row][o];
        if (colHalf == 0) s += (o == 0) ? B40 : B41;
        atomicAdd(&out[(size_t)(rBase + row) * 2 + o], s);
      }
      __syncthreads();
    }
  }

  if (MODE == 1) {
    csA += __shfl_xor(csA, 16);
    cqA += __shfl_xor(cqA, 16);
    csB += __shfl_xor(csB, 16);
    cqB += __shfl_xor(cqB, 16);
    csA += __shfl_xor(csA, 32);
    cqA += __shfl_xor(cqA, 32);
    csB += __shfl_xor(csB, 32);
    cqB += __shfl_xor(cqB, 32);
    if (lgrp == 0) {
      atomicAdd(&gsum3[c3a], csA);
      atomicAdd(&gsq3[c3a], cqA);
      atomicAdd(&gsum3[c3b], csB);
      atomicAdd(&gsq3[c3b], cqB);
    }
  }
}

// ---------------------------------------------------------------------------
extern "C" void kernel_launch(void* const* d_in, const int* in_sizes, int n_in,
                              void* d_out, int out_size, void* d_ws,
                              size_t ws_size, hipStream_t stream) {
  const float* x2 = (const float*)d_in[1];
  const float* W1 = (const float*)d_in[2];
  const float* b1 = (const float*)d_in[3];
  const float* W2 = (const float*)d_in[4];
  const float* b2 = (const float*)d_in[5];
  const float* W3 = (const float*)d_in[6];
  const float* b3 = (const float*)d_in[7];
  const float* W4 = (const float*)d_in[8];
  const float* b4 = (const float*)d_in[9];
  const float* gamma1 = (const float*)d_in[10];
  const float* beta1 = (const float*)d_in[11];
  const float* gamma2 = (const float*)d_in[12];
  const float* beta2 = (const float*)d_in[13];
  const float* gamma3 = (const float*)d_in[14];
  const float* beta3 = (const float*)d_in[15];
  float* out = (float*)d_out;

  const int N = in_sizes[1] / 3;  // 262144
  const float invN = 1.0f / (float)N;

  // --- scratch layout (~606 KB) ---
  float* f0 = (float*)d_ws;
  float* gsum1 = f0;           // 64
  float* gsq1 = f0 + 64;       // 64
  float* M1 = f0 + 128;        // 4096
  float* s1 = f0 + 4224;       // 64
  float* gsum3 = f0 + 4288;    // 512
  float* gsq3 = f0 + 4800;     // 512  (zeroed region ends at 5312)
  float* fold1 = f0 + 5312;    // 256
  float* scale2 = f0 + 5568;   // 512
  float* shift2f = f0 + 6080;  // 512
  float* scale3 = f0 + 6592;   // 512
  float* shift3f = f0 + 7104;  // 512
  __bf16* W2bf = (__bf16*)(f0 + 7616);  // 32768
  __bf16* W3bf = W2bf + 32768;          // 262144

  prep_kernel<<<1024, 256, 0, stream>>>(W2, W3, W2bf, W3bf, f0);
  stats1_kernel<<<N / 128, 256, 0, stream>>>(x2, W1, b1, gsum1, gsq1);
  finalize1_kernel<<<1, 64, 0, stream>>>(gsum1, gsq1, gamma1, beta1, W1, b1,
                                         fold1, invN);
  m1_kernel<<<256, 256, 0, stream>>>(x2, fold1, M1, s1);
  finalize2v_kernel<<<128, 256, 0, stream>>>(M1, s1, W2, b2, gamma2, beta2,
                                             scale2, shift2f, (float)N);
  fused_kernel<1><<<512, 512, 0, stream>>>(
      x2, fold1, W2bf, scale2, shift2f, W3bf, b3, scale3, shift3f, W4, b4,
      gsum3, gsq3, out);
  finalize3_kernel<<<1, 512, 0, stream>>>(gsum3, gsq3, gamma3, beta3, b3,
                                          scale3, shift3f, invN);
  hipMemsetAsync(out, 0, (size_t)N * 2 * sizeof(float), stream);
  fused_kernel<2><<<512, 512, 0, stream>>>(
      x2, fold1, W2bf, scale2, shift2f, W3bf, b3, scale3, shift3f, W4, b4,
      gsum3, gsq3, out);
}

// Round 5
// 570.672 us; speedup vs baseline: 2.6573x; 1.6171x over previous
//
#include <hip/hip_runtime.h>

typedef __bf16 bf16x4 __attribute__((ext_vector_type(4)));
typedef __bf16 bf16x8 __attribute__((ext_vector_type(8)));
typedef float f32x4 __attribute__((ext_vector_type(4)));

#define MFMA_BF16 __builtin_amdgcn_mfma_f32_16x16x32_bf16

// Swizzled element index for [rows][C] bf16 LDS tiles: XOR 16B-chunk id with row&7.
__device__ __forceinline__ int swz64(int row, int col) {
  return row * 64 + (((col >> 3) ^ (row & 7)) << 3) + (col & 7);
}
__device__ __forceinline__ int swz512(int row, int col) {
  return row * 512 + (((col >> 3) ^ (row & 7)) << 3) + (col & 7);
}

// ---------------------------------------------------------------------------
// prep: zero accumulators (5312 f32), cast W2/W3 to bf16
// ---------------------------------------------------------------------------
__global__ __launch_bounds__(256) void prep_kernel(
    const float* __restrict__ W2, const float* __restrict__ W3,
    __bf16* __restrict__ W2bf, __bf16* __restrict__ W3bf,
    float* __restrict__ stats) {
  int i = blockIdx.x * 256 + threadIdx.x;
  if (i < 32768) W2bf[i] = (__bf16)W2[i];
  if (i < 262144) W3bf[i] = (__bf16)W3[i];
  if (i < 5312) stats[i] = 0.f;
}

// ---------------------------------------------------------------------------
// stats1: column stats of y1 = x2 @ W1^T + b1 (no store)
// ---------------------------------------------------------------------------
__global__ __launch_bounds__(256) void stats1_kernel(
    const float* __restrict__ x, const float* __restrict__ W1,
    const float* __restrict__ b1, float* __restrict__ gsum,
    float* __restrict__ gsq) {
  int t = threadIdx.x;
  int c = t & 63;
  int rw = t >> 6;
  float w0 = W1[c * 3 + 0], w1 = W1[c * 3 + 1], w2 = W1[c * 3 + 2];
  float b = b1[c];
  int base = blockIdx.x * 128;
  float sum = 0.f, sq = 0.f;
#pragma unroll 4
  for (int i = 0; i < 32; ++i) {
    int row = base + i * 4 + rw;
    const float* xp = x + (size_t)row * 3;
    float y = fmaf(xp[0], w0, fmaf(xp[1], w1, fmaf(xp[2], w2, b)));
    sum += y;
    sq += y * y;
  }
  __shared__ float ssum[256], ssq[256];
  ssum[t] = sum;
  ssq[t] = sq;
  __syncthreads();
  if (t < 64) {
    float s = ssum[t] + ssum[t + 64] + ssum[t + 128] + ssum[t + 192];
    float q = ssq[t] + ssq[t + 64] + ssq[t + 128] + ssq[t + 192];
    atomicAdd(&gsum[t], s);
    atomicAdd(&gsq[t], q);
  }
}

// ---------------------------------------------------------------------------
// finalize1: fold BN1 scale/shift with W1,b1 into 4 coeffs per column
// ---------------------------------------------------------------------------
__global__ void finalize1_kernel(const float* __restrict__ gsum,
                                 const float* __restrict__ gsq,
                                 const float* __restrict__ gamma,
                                 const float* __restrict__ beta,
                                 const float* __restrict__ W1,
                                 const float* __restrict__ b1,
                                 float* __restrict__ fold1, float invN) {
  int c = threadIdx.x;  // 64
  float mu = gsum[c] * invN;
  float var = gsq[c] * invN - mu * mu;
  float sc = gamma[c] * rsqrtf(var + 1e-5f);
  float sh = beta[c] - mu * sc;
  fold1[c] = sc * W1[c * 3 + 0];
  fold1[64 + c] = sc * W1[c * 3 + 1];
  fold1[128 + c] = sc * W1[c * 3 + 2];
  fold1[192 + c] = sc * b1[c] + sh;
}

// finalize BN3: scale[c], shiftf[c] = scale*b + shift
__global__ void finalize3_kernel(const float* __restrict__ gsum,
                                 const float* __restrict__ gsq,
                                 const float* __restrict__ gamma,
                                 const float* __restrict__ beta,
                                 const float* __restrict__ b,
                                 float* __restrict__ scale,
                                 float* __restrict__ shiftf, float invN) {
  int c = blockIdx.x * blockDim.x + threadIdx.x;
  if (c >= 512) return;
  float mu = gsum[c] * invN;
  float var = gsq[c] * invN - mu * mu;
  float sc = gamma[c] * rsqrtf(var + 1e-5f);
  float sh = beta[c] - mu * sc;
  scale[c] = sc;
  shiftf[c] = sc * b[c] + sh;
}

// ---------------------------------------------------------------------------
// m1: M1 = sum_r h1_r h1_r^T (64x64), s1 = sum_r h1_r.
// 1024 blocks x 256 rows. ONE barrier: stage h1T[64 cols][256 rows +8 pad]
// for all 256 rows (coeffs in LDS, x2 via float4->LDS), then 8 MFMA k-steps
// over the full 256-row contraction. Atomics once at end.
// ---------------------------------------------------------------------------
__global__ __launch_bounds__(256, 4) void m1_kernel(
    const float* __restrict__ x2, const float* __restrict__ fold1,
    float* __restrict__ M1, float* __restrict__ s1) {
  __shared__ float sF[256];
  __shared__ float xs[768];
  __shared__ __bf16 h1T[64 * 264];  // [col][row], row-pad 264
  __shared__ float s1s[4][64];

  const int t = threadIdx.x;
  const int lane = t & 63, wave = t >> 6;
  const int lrow = lane & 15, lgrp = lane >> 4;

  sF[t] = fold1[t];
  if (t < 192)
    ((float4*)xs)[t] = ((const float4*)(x2 + (size_t)blockIdx.x * 768))[t];
  __syncthreads();

  // h-compute: thread owns cols c0..c0+15, rows r0, r0+64, r0+128, r0+192
  const int c0 = (t & 3) * 16;
  const int r0 = t >> 2;
  float sAcc[16] = {};
#pragma unroll
  for (int s = 0; s < 4; ++s) {
    int r = r0 + s * 64;
    float X0 = xs[r * 3], X1 = xs[r * 3 + 1], X2 = xs[r * 3 + 2];
#pragma unroll
    for (int j = 0; j < 16; ++j) {
      int c = c0 + j;
      float h = fmaxf(
          fmaf(sF[c], X0, fmaf(sF[64 + c], X1, fmaf(sF[128 + c], X2, sF[192 + c]))),
          0.f);
      sAcc[j] += h;
      h1T[c * 264 + r] = (__bf16)h;
    }
  }
  __syncthreads();

  // SYRK: D[i][j] = sum_k h1T[i][k] * h1T[j][k], k = 256 rows
  f32x4 acc[4] = {};
#pragma unroll
  for (int kk = 0; kk < 256; kk += 32) {
    bf16x8 af = *(const bf16x8*)&h1T[(wave * 16 + lrow) * 264 + kk + lgrp * 8];
#pragma unroll
    for (int n = 0; n < 4; ++n) {
      bf16x8 bfr = *(const bf16x8*)&h1T[(n * 16 + lrow) * 264 + kk + lgrp * 8];
      acc[n] = MFMA_BF16(af, bfr, acc[n], 0, 0, 0);
    }
  }
#pragma unroll
  for (int n = 0; n < 4; ++n)
#pragma unroll
    for (int rr = 0; rr < 4; ++rr)
      atomicAdd(&M1[(wave * 16 + lgrp * 4 + rr) * 64 + n * 16 + lrow],
                acc[n][rr]);

  // s1: wave-reduce lanes sharing (t&3), then block-reduce via LDS
#pragma unroll
  for (int j = 0; j < 16; ++j) {
    float v = sAcc[j];
    v += __shfl_xor(v, 4);
    v += __shfl_xor(v, 8);
    v += __shfl_xor(v, 16);
    v += __shfl_xor(v, 32);
    if (lane < 4) s1s[wave][(lane & 3) * 16 + j] = v;
  }
  __syncthreads();
  if (t < 64)
    atomicAdd(&s1[t], s1s[0][t] + s1s[1][t] + s1s[2][t] + s1s[3][t]);
}

// ---------------------------------------------------------------------------
// finalize2v: per col c of layer 2, q = w^T M1 w; derive BN2 scale/shiftf.
// ---------------------------------------------------------------------------
__global__ __launch_bounds__(256) void finalize2v_kernel(
    const float* __restrict__ M1, const float* __restrict__ s1,
    const float* __restrict__ W2, const float* __restrict__ b2,
    const float* __restrict__ gamma2, const float* __restrict__ beta2,
    float* __restrict__ scale2, float* __restrict__ shift2f, float fN) {
  __shared__ float sM[64 * 65];
  __shared__ float ss[64];
  int t = threadIdx.x;
  for (int i = t; i < 4096; i += 256) sM[(i >> 6) * 65 + (i & 63)] = M1[i];
  if (t < 64) ss[t] = s1[t];
  __syncthreads();
  int lane = t & 63;
  int col = blockIdx.x * 4 + (t >> 6);
  float wi = W2[(size_t)col * 64 + lane];
  float p = 0.f;
#pragma unroll
  for (int j = 0; j < 64; ++j) p = fmaf(sM[lane * 65 + j], __shfl(wi, j), p);
  float qi = wi * p;
  float swi = ss[lane] * wi;
#pragma unroll
  for (int off = 1; off < 64; off <<= 1) {
    qi += __shfl_xor(qi, off);
    swi += __shfl_xor(swi, off);
  }
  if (lane == 0) {
    float b = b2[col];
    float sy = swi + fN * b;
    float sqs = qi + 2.f * b * swi + fN * b * b;
    float mu = sy / fN;
    float var = sqs / fN - mu * mu;
    float sc = gamma2[col] * rsqrtf(var + 1e-5f);
    scale2[col] = sc;
    shift2f[col] = (beta2[col] - mu * sc) + sc * b;
  }
}

// ---------------------------------------------------------------------------
// Fused kernel, register-resident W3.
// 512 threads (8 waves). grid = 256 rowBlocks x 2 colHalves.
// Wave w owns W3 cols [colHalf*256 + w*32, +32) as 32 bf16x8 register frags.
// MODE 1: accumulate col stats of y3 in regs across rgs, atomics at end.
// MODE 2: BN3+ReLU+ @W4 -> out (pre-zeroed, cross-half atomicAdd).
// ---------------------------------------------------------------------------
template <int MODE>
__global__ __launch_bounds__(512, 2) void fused_kernel(
    const float* __restrict__ x2, const float* __restrict__ fold1,
    const __bf16* __restrict__ W2bf, const float* __restrict__ scale2,
    const float* __restrict__ shift2f, const __bf16* __restrict__ W3bf,
    const float* __restrict__ b3, const float* __restrict__ scale3,
    const float* __restrict__ shift3f, const float* __restrict__ W4,
    const float* __restrict__ b4, float* __restrict__ gsum3,
    float* __restrict__ gsq3, float* __restrict__ out) {
  __shared__ __bf16 h1[64 * 64];     // 8 KB  (swizzled)
  __shared__ __bf16 h2[64 * 512];    // 64 KB (swizzled)
  __shared__ __bf16 sW2[512 * 64];   // 64 KB (swizzled, [channel][k])
  __shared__ float sF[256];
  __shared__ float sSc2[512], sSh2[512];
  __shared__ float outaccW[8][64][2];  // 4 KB (MODE 2)

  const int t = threadIdx.x;
  const int lane = t & 63, wave = t >> 6;
  const int lrow = lane & 15, lgrp = lane >> 4;
  const int colHalf = blockIdx.x & 1;
  const int rowBlk = blockIdx.x >> 1;
  const int wCol3 = colHalf * 256 + wave * 32;  // GEMM3 col base (this wave)
  const int wCol2 = wave * 64;                  // GEMM2 channel base

  // ---- one-time LDS staging ----
  if (t < 256) sF[t] = fold1[t];
  {
    int i = t;
    if (i < 512) {
      sSc2[i] = scale2[i];
      sSh2[i] = shift2f[i];
    }
  }
#pragma unroll
  for (int i = 0; i < 8; ++i) {
    int seg = i * 512 + t;  // 4096 chunks of 8 bf16
    int ch = seg >> 3;
    int c0 = (seg & 7) * 8;
    bf16x8 v = *(const bf16x8*)&W2bf[ch * 64 + c0];
    *(bf16x8*)&sW2[ch * 64 + (((c0 >> 3) ^ (ch & 7)) << 3)] = v;
  }

  // ---- one-time: W3 fragments -> registers (128 VGPR, static indexing) ----
  bf16x8 b3r[16][2];
#pragma unroll
  for (int k = 0; k < 16; ++k)
#pragma unroll
    for (int n = 0; n < 2; ++n)
      b3r[k][n] = *(const bf16x8*)&W3bf[(size_t)(wCol3 + n * 16 + lrow) * 512 +
                                        k * 32 + lgrp * 8];

  // hoisted per-lane column params
  const int c3a = wCol3 + lrow, c3b = wCol3 + 16 + lrow;
  float b3a = 0.f, b3b = 0.f;
  float sc3a = 0.f, sc3b = 0.f, sh3a = 0.f, sh3b = 0.f;
  float w40a = 0.f, w40b = 0.f, w41a = 0.f, w41b = 0.f, B40 = 0.f, B41 = 0.f;
  if (MODE == 1) {
    b3a = b3[c3a];
    b3b = b3[c3b];
  } else {
    sc3a = scale3[c3a];
    sc3b = scale3[c3b];
    sh3a = shift3f[c3a];
    sh3b = shift3f[c3b];
    w40a = W4[c3a];
    w40b = W4[c3b];
    w41a = W4[512 + c3a];
    w41b = W4[512 + c3b];
    B40 = b4[0];
    B41 = b4[1];
  }
  float csA = 0.f, cqA = 0.f, csB = 0.f, cqB = 0.f;

  for (int g = 0; g < 16; ++g) {
    const int rBase = (rowBlk * 16 + g) * 64;

    // ---- stage h1 (+ zero outaccW) ----
    if (MODE == 2) {
      for (int i = t; i < 1024; i += 512) ((float*)outaccW)[i] = 0.f;
    }
    {
      int r = t >> 3, c0 = (t & 7) * 8;
      const float* xp = x2 + (size_t)(rBase + r) * 3;
      float X0 = xp[0], X1 = xp[1], X2v = xp[2];
      bf16x8 hv;
#pragma unroll
      for (int j = 0; j < 8; ++j) {
        int c = c0 + j;
        float h = fmaf(sF[c], X0,
                       fmaf(sF[64 + c], X1, fmaf(sF[128 + c], X2v, sF[192 + c])));
        hv[j] = (__bf16)fmaxf(h, 0.f);
      }
      *(bf16x8*)&h1[r * 64 + (((c0 >> 3) ^ (r & 7)) << 3)] = hv;
    }
    __syncthreads();

    // ---- GEMM2 (swapped operands): h2[:, wCol2..+64] ----
    {
      f32x4 a2[4][4] = {};  // [n][m]
#pragma unroll
      for (int kk = 0; kk < 2; ++kk) {
        bf16x8 af[4];
#pragma unroll
        for (int m = 0; m < 4; ++m)
          af[m] = *(const bf16x8*)&h1[swz64(m * 16 + lrow, kk * 32 + lgrp * 8)];
#pragma unroll
        for (int n = 0; n < 4; ++n) {
          int ch = wCol2 + n * 16 + lrow;
          bf16x8 bw = *(const bf16x8*)&sW2[ch * 64 +
              ((((kk * 32 + lgrp * 8) >> 3) ^ (ch & 7)) << 3)];
#pragma unroll
          for (int m = 0; m < 4; ++m)
            a2[n][m] = MFMA_BF16(bw, af[m], a2[n][m], 0, 0, 0);
        }
      }
      // write h2: channel = wCol2 + n*16 + lgrp*4 + rr, row = m*16 + lrow
#pragma unroll
      for (int n = 0; n < 4; ++n) {
        int ch0 = wCol2 + n * 16 + lgrp * 4;
        float s0 = sSc2[ch0], s1v = sSc2[ch0 + 1], s2v = sSc2[ch0 + 2],
              s3v = sSc2[ch0 + 3];
        float z0 = sSh2[ch0], z1 = sSh2[ch0 + 1], z2 = sSh2[ch0 + 2],
              z3 = sSh2[ch0 + 3];
#pragma unroll
        for (int m = 0; m < 4; ++m) {
          int row = m * 16 + lrow;
          bf16x4 hv;
          hv[0] = (__bf16)fmaxf(fmaf(s0, a2[n][m][0], z0), 0.f);
          hv[1] = (__bf16)fmaxf(fmaf(s1v, a2[n][m][1], z1), 0.f);
          hv[2] = (__bf16)fmaxf(fmaf(s2v, a2[n][m][2], z2), 0.f);
          hv[3] = (__bf16)fmaxf(fmaf(s3v, a2[n][m][3], z3), 0.f);
          *(bf16x4*)&h2[swz512(row, ch0)] = hv;
        }
      }
    }
    __syncthreads();

    // ---- GEMM3: pure LDS-read + register-B MFMA ----
    f32x4 acc[4][2] = {};  // [m][n]
#pragma unroll
    for (int k = 0; k < 16; ++k) {
      bf16x8 af[4];
#pragma unroll
      for (int m = 0; m < 4; ++m)
        af[m] = *(const bf16x8*)&h2[swz512(m * 16 + lrow, k * 32 + lgrp * 8)];
#pragma unroll
      for (int m = 0; m < 4; ++m) {
        acc[m][0] = MFMA_BF16(af[m], b3r[k][0], acc[m][0], 0, 0, 0);
        acc[m][1] = MFMA_BF16(af[m], b3r[k][1], acc[m][1], 0, 0, 0);
      }
    }

    if (MODE == 1) {
      // accumulate col stats in registers across row-groups
#pragma unroll
      for (int m = 0; m < 4; ++m)
#pragma unroll
        for (int rr = 0; rr < 4; ++rr) {
          float ya = acc[m][0][rr] + b3a;
          float yb = acc[m][1][rr] + b3b;
          csA += ya;
          cqA = fmaf(ya, ya, cqA);
          csB += yb;
          cqB = fmaf(yb, yb, cqB);
        }
    } else {
      // BN3 + ReLU + dot with W4 -> per-row partials
#pragma unroll
      for (int m = 0; m < 4; ++m)
#pragma unroll
        for (int rr = 0; rr < 4; ++rr) {
          float ha = fmaxf(fmaf(sc3a, acc[m][0][rr], sh3a), 0.f);
          float hb = fmaxf(fmaf(sc3b, acc[m][1][rr], sh3b), 0.f);
          float dd0 = fmaf(ha, w40a, hb * w40b);
          float dd1 = fmaf(ha, w41a, hb * w41b);
          dd0 += __shfl_xor(dd0, 1);
          dd1 += __shfl_xor(dd1, 1);
          dd0 += __shfl_xor(dd0, 2);
          dd1 += __shfl_xor(dd1, 2);
          dd0 += __shfl_xor(dd0, 4);
          dd1 += __shfl_xor(dd1, 4);
          dd0 += __shfl_xor(dd0, 8);
          dd1 += __shfl_xor(dd1, 8);
          if (lrow == 0) {
            int row = m * 16 + lgrp * 4 + rr;
            outaccW[wave][row][0] = dd0;
            outaccW[wave][row][1] = dd1;
          }
        }
      __syncthreads();
      if (t < 128) {
        int row = t >> 1, o = t & 1;
        float s = 0.f;
#pragma unroll
        for (int w = 0; w < 8; ++w) s += outaccW[w][row][o];
        if (colHalf == 0) s += (o == 0) ? B40 : B41;
        atomicAdd(&out[(size_t)(rBase + row) * 2 + o], s);
      }
      __syncthreads();
    }
  }

  if (MODE == 1) {
    csA += __shfl_xor(csA, 16);
    cqA += __shfl_xor(cqA, 16);
    csB += __shfl_xor(csB, 16);
    cqB += __shfl_xor(cqB, 16);
    csA += __shfl_xor(csA, 32);
    cqA += __shfl_xor(cqA, 32);
    csB += __shfl_xor(csB, 32);
    cqB += __shfl_xor(cqB, 32);
    if (lgrp == 0) {
      atomicAdd(&gsum3[c3a], csA);
      atomicAdd(&gsq3[c3a], cqA);
      atomicAdd(&gsum3[c3b], csB);
      atomicAdd(&gsq3[c3b], cqB);
    }
  }
}

// ---------------------------------------------------------------------------
extern "C" void kernel_launch(void* const* d_in, const int* in_sizes, int n_in,
                              void* d_out, int out_size, void* d_ws,
                              size_t ws_size, hipStream_t stream) {
  const float* x2 = (const float*)d_in[1];
  const float* W1 = (const float*)d_in[2];
  const float* b1 = (const float*)d_in[3];
  const float* W2 = (const float*)d_in[4];
  const float* b2 = (const float*)d_in[5];
  const float* W3 = (const float*)d_in[6];
  const float* b3 = (const float*)d_in[7];
  const float* W4 = (const float*)d_in[8];
  const float* b4 = (const float*)d_in[9];
  const float* gamma1 = (const float*)d_in[10];
  const float* beta1 = (const float*)d_in[11];
  const float* gamma2 = (const float*)d_in[12];
  const float* beta2 = (const float*)d_in[13];
  const float* gamma3 = (const float*)d_in[14];
  const float* beta3 = (const float*)d_in[15];
  float* out = (float*)d_out;

  const int N = in_sizes[1] / 3;  // 262144
  const float invN = 1.0f / (float)N;

  // --- scratch layout (~606 KB) ---
  float* f0 = (float*)d_ws;
  float* gsum1 = f0;           // 64
  float* gsq1 = f0 + 64;       // 64
  float* M1 = f0 + 128;        // 4096
  float* s1 = f0 + 4224;       // 64
  float* gsum3 = f0 + 4288;    // 512
  float* gsq3 = f0 + 4800;     // 512  (zeroed region ends at 5312)
  float* fold1 = f0 + 5312;    // 256
  float* scale2 = f0 + 5568;   // 512
  float* shift2f = f0 + 6080;  // 512
  float* scale3 = f0 + 6592;   // 512
  float* shift3f = f0 + 7104;  // 512
  __bf16* W2bf = (__bf16*)(f0 + 7616);  // 32768
  __bf16* W3bf = W2bf + 32768;          // 262144

  prep_kernel<<<1024, 256, 0, stream>>>(W2, W3, W2bf, W3bf, f0);
  stats1_kernel<<<N / 128, 256, 0, stream>>>(x2, W1, b1, gsum1, gsq1);
  finalize1_kernel<<<1, 64, 0, stream>>>(gsum1, gsq1, gamma1, beta1, W1, b1,
                                         fold1, invN);
  m1_kernel<<<N / 256, 256, 0, stream>>>(x2, fold1, M1, s1);
  finalize2v_kernel<<<128, 256, 0, stream>>>(M1, s1, W2, b2, gamma2, beta2,
                                             scale2, shift2f, (float)N);
  fused_kernel<1><<<512, 512, 0, stream>>>(
      x2, fold1, W2bf, scale2, shift2f, W3bf, b3, scale3, shift3f, W4, b4,
      gsum3, gsq3, out);
  finalize3_kernel<<<1, 512, 0, stream>>>(gsum3, gsq3, gamma3, beta3, b3,
                                          scale3, shift3f, invN);
  hipMemsetAsync(out, 0, (size_t)N * 2 * sizeof(float), stream);
  fused_kernel<2><<<512, 512, 0, stream>>>(
      x2, fold1, W2bf, scale2, shift2f, W3bf, b3, scale3, shift3f, W4, b4,
      gsum3, gsq3, out);
}

// Round 6
// 569.717 us; speedup vs baseline: 2.6617x; 1.0017x over previous
//
#include <hip/hip_runtime.h>

typedef __bf16 bf16x4 __attribute__((ext_vector_type(4)));
typedef __bf16 bf16x8 __attribute__((ext_vector_type(8)));
typedef float f32x4 __attribute__((ext_vector_type(4)));

#define MFMA_BF16 __builtin_amdgcn_mfma_f32_16x16x32_bf16

// Swizzled element index for [rows][C] bf16 LDS tiles: XOR 16B-chunk id with row&7.
__device__ __forceinline__ int swz64(int row, int col) {
  return row * 64 + (((col >> 3) ^ (row & 7)) << 3) + (col & 7);
}
__device__ __forceinline__ int swz512(int row, int col) {
  return row * 512 + (((col >> 3) ^ (row & 7)) << 3) + (col & 7);
}

// ---------------------------------------------------------------------------
// prep: zero accumulators (5312 f32), cast W2/W3 to bf16
// ---------------------------------------------------------------------------
__global__ __launch_bounds__(256) void prep_kernel(
    const float* __restrict__ W2, const float* __restrict__ W3,
    __bf16* __restrict__ W2bf, __bf16* __restrict__ W3bf,
    float* __restrict__ stats) {
  int i = blockIdx.x * 256 + threadIdx.x;
  if (i < 32768) W2bf[i] = (__bf16)W2[i];
  if (i < 262144) W3bf[i] = (__bf16)W3[i];
  if (i < 5312) stats[i] = 0.f;
}

// ---------------------------------------------------------------------------
// stats1: column stats of y1 = x2 @ W1^T + b1 (no store)
// ---------------------------------------------------------------------------
__global__ __launch_bounds__(256) void stats1_kernel(
    const float* __restrict__ x, const float* __restrict__ W1,
    const float* __restrict__ b1, float* __restrict__ gsum,
    float* __restrict__ gsq) {
  int t = threadIdx.x;
  int c = t & 63;
  int rw = t >> 6;
  float w0 = W1[c * 3 + 0], w1 = W1[c * 3 + 1], w2 = W1[c * 3 + 2];
  float b = b1[c];
  int base = blockIdx.x * 128;
  float sum = 0.f, sq = 0.f;
#pragma unroll 4
  for (int i = 0; i < 32; ++i) {
    int row = base + i * 4 + rw;
    const float* xp = x + (size_t)row * 3;
    float y = fmaf(xp[0], w0, fmaf(xp[1], w1, fmaf(xp[2], w2, b)));
    sum += y;
    sq += y * y;
  }
  __shared__ float ssum[256], ssq[256];
  ssum[t] = sum;
  ssq[t] = sq;
  __syncthreads();
  if (t < 64) {
    float s = ssum[t] + ssum[t + 64] + ssum[t + 128] + ssum[t + 192];
    float q = ssq[t] + ssq[t + 64] + ssq[t + 128] + ssq[t + 192];
    atomicAdd(&gsum[t], s);
    atomicAdd(&gsq[t], q);
  }
}

// ---------------------------------------------------------------------------
// finalize1: fold BN1 scale/shift with W1,b1 into 4 coeffs per column
// ---------------------------------------------------------------------------
__global__ void finalize1_kernel(const float* __restrict__ gsum,
                                 const float* __restrict__ gsq,
                                 const float* __restrict__ gamma,
                                 const float* __restrict__ beta,
                                 const float* __restrict__ W1,
                                 const float* __restrict__ b1,
                                 float* __restrict__ fold1, float invN) {
  int c = threadIdx.x;  // 64
  float mu = gsum[c] * invN;
  float var = gsq[c] * invN - mu * mu;
  float sc = gamma[c] * rsqrtf(var + 1e-5f);
  float sh = beta[c] - mu * sc;
  fold1[c] = sc * W1[c * 3 + 0];
  fold1[64 + c] = sc * W1[c * 3 + 1];
  fold1[128 + c] = sc * W1[c * 3 + 2];
  fold1[192 + c] = sc * b1[c] + sh;
}

// finalize BN3: scale, shiftf (bias-folded, for acc path), shiftp (plain)
__global__ void finalize3_kernel(const float* __restrict__ gsum,
                                 const float* __restrict__ gsq,
                                 const float* __restrict__ gamma,
                                 const float* __restrict__ beta,
                                 const float* __restrict__ b,
                                 float* __restrict__ scale,
                                 float* __restrict__ shiftf,
                                 float* __restrict__ shiftp, float invN) {
  int c = blockIdx.x * blockDim.x + threadIdx.x;
  if (c >= 512) return;
  float mu = gsum[c] * invN;
  float var = gsq[c] * invN - mu * mu;
  float sc = gamma[c] * rsqrtf(var + 1e-5f);
  float sh = beta[c] - mu * sc;
  scale[c] = sc;
  shiftf[c] = sc * b[c] + sh;
  shiftp[c] = sh;
}

// ---------------------------------------------------------------------------
// m1: M1 = sum_r h1_r h1_r^T (64x64), s1 = sum_r h1_r.
// ---------------------------------------------------------------------------
__global__ __launch_bounds__(256, 4) void m1_kernel(
    const float* __restrict__ x2, const float* __restrict__ fold1,
    float* __restrict__ M1, float* __restrict__ s1) {
  __shared__ float sF[256];
  __shared__ float xs[768];
  __shared__ __bf16 h1T[64 * 264];  // [col][row], row-pad 264
  __shared__ float s1s[4][64];

  const int t = threadIdx.x;
  const int lane = t & 63, wave = t >> 6;
  const int lrow = lane & 15, lgrp = lane >> 4;

  sF[t] = fold1[t];
  if (t < 192)
    ((float4*)xs)[t] = ((const float4*)(x2 + (size_t)blockIdx.x * 768))[t];
  __syncthreads();

  const int c0 = (t & 3) * 16;
  const int r0 = t >> 2;
  float sAcc[16] = {};
#pragma unroll
  for (int s = 0; s < 4; ++s) {
    int r = r0 + s * 64;
    float X0 = xs[r * 3], X1 = xs[r * 3 + 1], X2 = xs[r * 3 + 2];
#pragma unroll
    for (int j = 0; j < 16; ++j) {
      int c = c0 + j;
      float h = fmaxf(
          fmaf(sF[c], X0, fmaf(sF[64 + c], X1, fmaf(sF[128 + c], X2, sF[192 + c]))),
          0.f);
      sAcc[j] += h;
      h1T[c * 264 + r] = (__bf16)h;
    }
  }
  __syncthreads();

  f32x4 acc[4] = {};
#pragma unroll
  for (int kk = 0; kk < 256; kk += 32) {
    bf16x8 af = *(const bf16x8*)&h1T[(wave * 16 + lrow) * 264 + kk + lgrp * 8];
#pragma unroll
    for (int n = 0; n < 4; ++n) {
      bf16x8 bfr = *(const bf16x8*)&h1T[(n * 16 + lrow) * 264 + kk + lgrp * 8];
      acc[n] = MFMA_BF16(af, bfr, acc[n], 0, 0, 0);
    }
  }
#pragma unroll
  for (int n = 0; n < 4; ++n)
#pragma unroll
    for (int rr = 0; rr < 4; ++rr)
      atomicAdd(&M1[(wave * 16 + lgrp * 4 + rr) * 64 + n * 16 + lrow],
                acc[n][rr]);

#pragma unroll
  for (int j = 0; j < 16; ++j) {
    float v = sAcc[j];
    v += __shfl_xor(v, 4);
    v += __shfl_xor(v, 8);
    v += __shfl_xor(v, 16);
    v += __shfl_xor(v, 32);
    if (lane < 4) s1s[wave][(lane & 3) * 16 + j] = v;
  }
  __syncthreads();
  if (t < 64)
    atomicAdd(&s1[t], s1s[0][t] + s1s[1][t] + s1s[2][t] + s1s[3][t]);
}

// ---------------------------------------------------------------------------
// finalize2v: per col c of layer 2, q = w^T M1 w; derive BN2 scale/shiftf.
// ---------------------------------------------------------------------------
__global__ __launch_bounds__(256) void finalize2v_kernel(
    const float* __restrict__ M1, const float* __restrict__ s1,
    const float* __restrict__ W2, const float* __restrict__ b2,
    const float* __restrict__ gamma2, const float* __restrict__ beta2,
    float* __restrict__ scale2, float* __restrict__ shift2f, float fN) {
  __shared__ float sM[64 * 65];
  __shared__ float ss[64];
  int t = threadIdx.x;
  for (int i = t; i < 4096; i += 256) sM[(i >> 6) * 65 + (i & 63)] = M1[i];
  if (t < 64) ss[t] = s1[t];
  __syncthreads();
  int lane = t & 63;
  int col = blockIdx.x * 4 + (t >> 6);
  float wi = W2[(size_t)col * 64 + lane];
  float p = 0.f;
#pragma unroll
  for (int j = 0; j < 64; ++j) p = fmaf(sM[lane * 65 + j], __shfl(wi, j), p);
  float qi = wi * p;
  float swi = ss[lane] * wi;
#pragma unroll
  for (int off = 1; off < 64; off <<= 1) {
    qi += __shfl_xor(qi, off);
    swi += __shfl_xor(swi, off);
  }
  if (lane == 0) {
    float b = b2[col];
    float sy = swi + fN * b;
    float sqs = qi + 2.f * b * swi + fN * b * b;
    float mu = sy / fN;
    float var = sqs / fN - mu * mu;
    float sc = gamma2[col] * rsqrtf(var + 1e-5f);
    scale2[col] = sc;
    shift2f[col] = (beta2[col] - mu * sc) + sc * b;
  }
}

// ---------------------------------------------------------------------------
// Fused kernel, register-resident W3.
// MODE 1: stats only.  MODE 3: stats + store y3 (bf16).  MODE 2: out path.
// ---------------------------------------------------------------------------
template <int MODE>
__global__ __launch_bounds__(512, 2) void fused_kernel(
    const float* __restrict__ x2, const float* __restrict__ fold1,
    const __bf16* __restrict__ W2bf, const float* __restrict__ scale2,
    const float* __restrict__ shift2f, const __bf16* __restrict__ W3bf,
    const float* __restrict__ b3, const float* __restrict__ scale3,
    const float* __restrict__ shift3f, const float* __restrict__ W4,
    const float* __restrict__ b4, float* __restrict__ gsum3,
    float* __restrict__ gsq3, float* __restrict__ out,
    __bf16* __restrict__ y3o) {
  __shared__ __bf16 h1[64 * 64];     // 8 KB  (swizzled)
  __shared__ __bf16 h2[64 * 512];    // 64 KB (swizzled)
  __shared__ __bf16 sW2[512 * 64];   // 64 KB (swizzled, [channel][k])
  __shared__ float sF[256];
  __shared__ float sSc2[512], sSh2[512];
  __shared__ float outaccW[8][64][2];  // 4 KB (MODE 2)

  const int t = threadIdx.x;
  const int lane = t & 63, wave = t >> 6;
  const int lrow = lane & 15, lgrp = lane >> 4;
  const int colHalf = blockIdx.x & 1;
  const int rowBlk = blockIdx.x >> 1;
  const int wCol3 = colHalf * 256 + wave * 32;  // GEMM3 col base (this wave)
  const int wCol2 = wave * 64;                  // GEMM2 channel base

  // ---- one-time LDS staging ----
  if (t < 256) sF[t] = fold1[t];
  if (t < 512) {
    sSc2[t] = scale2[t];
    sSh2[t] = shift2f[t];
  }
#pragma unroll
  for (int i = 0; i < 8; ++i) {
    int seg = i * 512 + t;
    int ch = seg >> 3;
    int c0 = (seg & 7) * 8;
    bf16x8 v = *(const bf16x8*)&W2bf[ch * 64 + c0];
    *(bf16x8*)&sW2[ch * 64 + (((c0 >> 3) ^ (ch & 7)) << 3)] = v;
  }

  // ---- one-time: W3 fragments -> registers ----
  bf16x8 b3r[16][2];
#pragma unroll
  for (int k = 0; k < 16; ++k)
#pragma unroll
    for (int n = 0; n < 2; ++n)
      b3r[k][n] = *(const bf16x8*)&W3bf[(size_t)(wCol3 + n * 16 + lrow) * 512 +
                                        k * 32 + lgrp * 8];

  const int c3a = wCol3 + lrow, c3b = wCol3 + 16 + lrow;
  float b3a = 0.f, b3b = 0.f;
  float sc3a = 0.f, sc3b = 0.f, sh3a = 0.f, sh3b = 0.f;
  float w40a = 0.f, w40b = 0.f, w41a = 0.f, w41b = 0.f, B40 = 0.f, B41 = 0.f;
  if (MODE != 2) {
    b3a = b3[c3a];
    b3b = b3[c3b];
  } else {
    sc3a = scale3[c3a];
    sc3b = scale3[c3b];
    sh3a = shift3f[c3a];
    sh3b = shift3f[c3b];
    w40a = W4[c3a];
    w40b = W4[c3b];
    w41a = W4[512 + c3a];
    w41b = W4[512 + c3b];
    B40 = b4[0];
    B41 = b4[1];
  }
  float csA = 0.f, cqA = 0.f, csB = 0.f, cqB = 0.f;

  for (int g = 0; g < 16; ++g) {
    const int rBase = (rowBlk * 16 + g) * 64;

    if (MODE == 2) {
      for (int i = t; i < 1024; i += 512) ((float*)outaccW)[i] = 0.f;
    }
    {
      int r = t >> 3, c0 = (t & 7) * 8;
      const float* xp = x2 + (size_t)(rBase + r) * 3;
      float X0 = xp[0], X1 = xp[1], X2v = xp[2];
      bf16x8 hv;
#pragma unroll
      for (int j = 0; j < 8; ++j) {
        int c = c0 + j;
        float h = fmaf(sF[c], X0,
                       fmaf(sF[64 + c], X1, fmaf(sF[128 + c], X2v, sF[192 + c])));
        hv[j] = (__bf16)fmaxf(h, 0.f);
      }
      *(bf16x8*)&h1[r * 64 + (((c0 >> 3) ^ (r & 7)) << 3)] = hv;
    }
    __syncthreads();

    // ---- GEMM2 (swapped operands): h2[:, wCol2..+64] ----
    {
      f32x4 a2[4][4] = {};  // [n][m]
#pragma unroll
      for (int kk = 0; kk < 2; ++kk) {
        bf16x8 af[4];
#pragma unroll
        for (int m = 0; m < 4; ++m)
          af[m] = *(const bf16x8*)&h1[swz64(m * 16 + lrow, kk * 32 + lgrp * 8)];
#pragma unroll
        for (int n = 0; n < 4; ++n) {
          int ch = wCol2 + n * 16 + lrow;
          bf16x8 bw = *(const bf16x8*)&sW2[ch * 64 +
              ((((kk * 32 + lgrp * 8) >> 3) ^ (ch & 7)) << 3)];
#pragma unroll
          for (int m = 0; m < 4; ++m)
            a2[n][m] = MFMA_BF16(bw, af[m], a2[n][m], 0, 0, 0);
        }
      }
#pragma unroll
      for (int n = 0; n < 4; ++n) {
        int ch0 = wCol2 + n * 16 + lgrp * 4;
        float s0 = sSc2[ch0], s1v = sSc2[ch0 + 1], s2v = sSc2[ch0 + 2],
              s3v = sSc2[ch0 + 3];
        float z0 = sSh2[ch0], z1 = sSh2[ch0 + 1], z2 = sSh2[ch0 + 2],
              z3 = sSh2[ch0 + 3];
#pragma unroll
        for (int m = 0; m < 4; ++m) {
          int row = m * 16 + lrow;
          bf16x4 hv;
          hv[0] = (__bf16)fmaxf(fmaf(s0, a2[n][m][0], z0), 0.f);
          hv[1] = (__bf16)fmaxf(fmaf(s1v, a2[n][m][1], z1), 0.f);
          hv[2] = (__bf16)fmaxf(fmaf(s2v, a2[n][m][2], z2), 0.f);
          hv[3] = (__bf16)fmaxf(fmaf(s3v, a2[n][m][3], z3), 0.f);
          *(bf16x4*)&h2[swz512(row, ch0)] = hv;
        }
      }
    }
    __syncthreads();

    // ---- GEMM3: pure LDS-read + register-B MFMA ----
    f32x4 acc[4][2] = {};  // [m][n]
#pragma unroll
    for (int k = 0; k < 16; ++k) {
      bf16x8 af[4];
#pragma unroll
      for (int m = 0; m < 4; ++m)
        af[m] = *(const bf16x8*)&h2[swz512(m * 16 + lrow, k * 32 + lgrp * 8)];
#pragma unroll
      for (int m = 0; m < 4; ++m) {
        acc[m][0] = MFMA_BF16(af[m], b3r[k][0], acc[m][0], 0, 0, 0);
        acc[m][1] = MFMA_BF16(af[m], b3r[k][1], acc[m][1], 0, 0, 0);
      }
    }

    if (MODE != 2) {
#pragma unroll
      for (int m = 0; m < 4; ++m)
#pragma unroll
        for (int rr = 0; rr < 4; ++rr) {
          float ya = acc[m][0][rr] + b3a;
          float yb = acc[m][1][rr] + b3b;
          csA += ya;
          cqA = fmaf(ya, ya, cqA);
          csB += yb;
          cqB = fmaf(yb, yb, cqB);
          if (MODE == 3) {
            size_t row = (size_t)(rBase + m * 16 + lgrp * 4 + rr);
            y3o[row * 512 + c3a] = (__bf16)ya;
            y3o[row * 512 + c3b] = (__bf16)yb;
          }
        }
    } else {
#pragma unroll
      for (int m = 0; m < 4; ++m)
#pragma unroll
        for (int rr = 0; rr < 4; ++rr) {
          float ha = fmaxf(fmaf(sc3a, acc[m][0][rr], sh3a), 0.f);
          float hb = fmaxf(fmaf(sc3b, acc[m][1][rr], sh3b), 0.f);
          float dd0 = fmaf(ha, w40a, hb * w40b);
          float dd1 = fmaf(ha, w41a, hb * w41b);
          dd0 += __shfl_xor(dd0, 1);
          dd1 += __shfl_xor(dd1, 1);
          dd0 += __shfl_xor(dd0, 2);
          dd1 += __shfl_xor(dd1, 2);
          dd0 += __shfl_xor(dd0, 4);
          dd1 += __shfl_xor(dd1, 4);
          dd0 += __shfl_xor(dd0, 8);
          dd1 += __shfl_xor(dd1, 8);
          if (lrow == 0) {
            int row = m * 16 + lgrp * 4 + rr;
            outaccW[wave][row][0] = dd0;
            outaccW[wave][row][1] = dd1;
          }
        }
      __syncthreads();
      if (t < 128) {
        int row = t >> 1, o = t & 1;
        float s = 0.f;
#pragma unroll
        for (int w = 0; w < 8; ++w) s += outaccW[w][row][o];
        if (colHalf == 0) s += (o == 0) ? B40 : B41;
        atomicAdd(&out[(size_t)(rBase + row) * 2 + o], s);
      }
      __syncthreads();
    }
  }

  if (MODE != 2) {
    csA += __shfl_xor(csA, 16);
    cqA += __shfl_xor(cqA, 16);
    csB += __shfl_xor(csB, 16);
    cqB += __shfl_xor(cqB, 16);
    csA += __shfl_xor(csA, 32);
    cqA += __shfl_xor(cqA, 32);
    csB += __shfl_xor(csB, 32);
    cqB += __shfl_xor(cqB, 32);
    if (lgrp == 0) {
      atomicAdd(&gsum3[c3a], csA);
      atomicAdd(&gsq3[c3a], cqA);
      atomicAdd(&gsum3[c3b], csB);
      atomicAdd(&gsq3[c3b], cqB);
    }
  }
}

// ---------------------------------------------------------------------------
// stream_out: out = relu(sc3*y3 + sh3p) @ W4^T + b4, y3 bf16 from HBM.
// 256 threads = 4 waves, one row per wave per iter, grid-stride.
// ---------------------------------------------------------------------------
__global__ __launch_bounds__(256) void stream_out_kernel(
    const __bf16* __restrict__ y3, const float* __restrict__ scale3,
    const float* __restrict__ shift3p, const float* __restrict__ W4,
    const float* __restrict__ b4, float* __restrict__ out, int N) {
  __shared__ float sSc[512], sSh[512], sW0[512], sW1[512];
  int t = threadIdx.x;
  for (int i = t; i < 512; i += 256) {
    sSc[i] = scale3[i];
    sSh[i] = shift3p[i];
    sW0[i] = W4[i];
    sW1[i] = W4[512 + i];
  }
  __syncthreads();
  int lane = t & 63, wv = t >> 6;
  int c0 = lane * 8;
  float fsc[8], fsh[8], fw0[8], fw1[8];
#pragma unroll
  for (int j = 0; j < 8; ++j) {
    fsc[j] = sSc[c0 + j];
    fsh[j] = sSh[c0 + j];
    fw0[j] = sW0[c0 + j];
    fw1[j] = sW1[c0 + j];
  }
  float B0 = b4[0], B1 = b4[1];
  for (size_t row = (size_t)blockIdx.x * 4 + wv; row < (size_t)N;
       row += (size_t)gridDim.x * 4) {
    bf16x8 v = *(const bf16x8*)(y3 + row * 512 + c0);
    float d0 = 0.f, d1 = 0.f;
#pragma unroll
    for (int j = 0; j < 8; ++j) {
      float h = fmaxf(fmaf(fsc[j], (float)v[j], fsh[j]), 0.f);
      d0 = fmaf(h, fw0[j], d0);
      d1 = fmaf(h, fw1[j], d1);
    }
#pragma unroll
    for (int off = 1; off < 64; off <<= 1) {
      d0 += __shfl_xor(d0, off);
      d1 += __shfl_xor(d1, off);
    }
    if (lane == 0) {
      out[row * 2 + 0] = d0 + B0;
      out[row * 2 + 1] = d1 + B1;
    }
  }
}

// ---------------------------------------------------------------------------
extern "C" void kernel_launch(void* const* d_in, const int* in_sizes, int n_in,
                              void* d_out, int out_size, void* d_ws,
                              size_t ws_size, hipStream_t stream) {
  const float* x2 = (const float*)d_in[1];
  const float* W1 = (const float*)d_in[2];
  const float* b1 = (const float*)d_in[3];
  const float* W2 = (const float*)d_in[4];
  const float* b2 = (const float*)d_in[5];
  const float* W3 = (const float*)d_in[6];
  const float* b3 = (const float*)d_in[7];
  const float* W4 = (const float*)d_in[8];
  const float* b4 = (const float*)d_in[9];
  const float* gamma1 = (const float*)d_in[10];
  const float* beta1 = (const float*)d_in[11];
  const float* gamma2 = (const float*)d_in[12];
  const float* beta2 = (const float*)d_in[13];
  const float* gamma3 = (const float*)d_in[14];
  const float* beta3 = (const float*)d_in[15];
  float* out = (float*)d_out;

  const int N = in_sizes[1] / 3;  // 262144
  const float invN = 1.0f / (float)N;

  // --- small scratch layout (< 1 MiB) ---
  float* f0 = (float*)d_ws;
  float* gsum1 = f0;           // 64
  float* gsq1 = f0 + 64;       // 64
  float* M1 = f0 + 128;        // 4096
  float* s1 = f0 + 4224;       // 64
  float* gsum3 = f0 + 4288;    // 512
  float* gsq3 = f0 + 4800;     // 512  (zeroed region ends at 5312)
  float* fold1 = f0 + 5312;    // 256
  float* scale2 = f0 + 5568;   // 512
  float* shift2f = f0 + 6080;  // 512
  float* scale3 = f0 + 6592;   // 512
  float* shift3f = f0 + 7104;  // 512
  float* shift3p = f0 + 7616;  // 512
  __bf16* W2bf = (__bf16*)(f0 + 8128);  // 32768 elems
  __bf16* W3bf = W2bf + 32768;          // 262144 elems; ends ~622 KB

  // --- y3 store path gate: y3 bf16 at 1 MiB offset, N*512*2 bytes ---
  const size_t y3off = (size_t)1 << 20;
  const size_t need = y3off + (size_t)N * 512 * 2;
  const bool storePath = (ws_size >= need);
  __bf16* y3bf = (__bf16*)((char*)d_ws + y3off);

  prep_kernel<<<1024, 256, 0, stream>>>(W2, W3, W2bf, W3bf, f0);
  stats1_kernel<<<N / 128, 256, 0, stream>>>(x2, W1, b1, gsum1, gsq1);
  finalize1_kernel<<<1, 64, 0, stream>>>(gsum1, gsq1, gamma1, beta1, W1, b1,
                                         fold1, invN);
  m1_kernel<<<N / 256, 256, 0, stream>>>(x2, fold1, M1, s1);
  finalize2v_kernel<<<128, 256, 0, stream>>>(M1, s1, W2, b2, gamma2, beta2,
                                             scale2, shift2f, (float)N);
  if (storePath) {
    fused_kernel<3><<<512, 512, 0, stream>>>(
        x2, fold1, W2bf, scale2, shift2f, W3bf, b3, scale3, shift3f, W4, b4,
        gsum3, gsq3, out, y3bf);
    finalize3_kernel<<<1, 512, 0, stream>>>(gsum3, gsq3, gamma3, beta3, b3,
                                            scale3, shift3f, shift3p, invN);
    stream_out_kernel<<<2048, 256, 0, stream>>>(y3bf, scale3, shift3p, W4, b4,
                                                out, N);
  } else {
    fused_kernel<1><<<512, 512, 0, stream>>>(
        x2, fold1, W2bf, scale2, shift2f, W3bf, b3, scale3, shift3f, W4, b4,
        gsum3, gsq3, out, nullptr);
    finalize3_kernel<<<1, 512, 0, stream>>>(gsum3, gsq3, gamma3, beta3, b3,
                                            scale3, shift3f, shift3p, invN);
    hipMemsetAsync(out, 0, (size_t)N * 2 * sizeof(float), stream);
    fused_kernel<2><<<512, 512, 0, stream>>>(
        x2, fold1, W2bf, scale2, shift2f, W3bf, b3, scale3, shift3f, W4, b4,
        gsum3, gsq3, out, nullptr);
  }
}

// Round 7
// 547.732 us; speedup vs baseline: 2.7686x; 1.0401x over previous
//
#include <hip/hip_runtime.h>

typedef __bf16 bf16x4 __attribute__((ext_vector_type(4)));
typedef __bf16 bf16x8 __attribute__((ext_vector_type(8)));
typedef float f32x4 __attribute__((ext_vector_type(4)));

#define MFMA_BF16 __builtin_amdgcn_mfma_f32_16x16x32_bf16

// ---------------------------------------------------------------------------
// prep: zero accumulators (5312 f32), cast W2/W3 to bf16
// ---------------------------------------------------------------------------
__global__ __launch_bounds__(256) void prep_kernel(
    const float* __restrict__ W2, const float* __restrict__ W3,
    __bf16* __restrict__ W2bf, __bf16* __restrict__ W3bf,
    float* __restrict__ stats) {
  int i = blockIdx.x * 256 + threadIdx.x;
  if (i < 32768) W2bf[i] = (__bf16)W2[i];
  if (i < 262144) W3bf[i] = (__bf16)W3[i];
  if (i < 5312) stats[i] = 0.f;
}

// ---------------------------------------------------------------------------
// stats1: column stats of y1 = x2 @ W1^T + b1 (no store)
// ---------------------------------------------------------------------------
__global__ __launch_bounds__(256) void stats1_kernel(
    const float* __restrict__ x, const float* __restrict__ W1,
    const float* __restrict__ b1, float* __restrict__ gsum,
    float* __restrict__ gsq) {
  int t = threadIdx.x;
  int c = t & 63;
  int rw = t >> 6;
  float w0 = W1[c * 3 + 0], w1 = W1[c * 3 + 1], w2 = W1[c * 3 + 2];
  float b = b1[c];
  int base = blockIdx.x * 128;
  float sum = 0.f, sq = 0.f;
#pragma unroll 4
  for (int i = 0; i < 32; ++i) {
    int row = base + i * 4 + rw;
    const float* xp = x + (size_t)row * 3;
    float y = fmaf(xp[0], w0, fmaf(xp[1], w1, fmaf(xp[2], w2, b)));
    sum += y;
    sq += y * y;
  }
  __shared__ float ssum[256], ssq[256];
  ssum[t] = sum;
  ssq[t] = sq;
  __syncthreads();
  if (t < 64) {
    float s = ssum[t] + ssum[t + 64] + ssum[t + 128] + ssum[t + 192];
    float q = ssq[t] + ssq[t + 64] + ssq[t + 128] + ssq[t + 192];
    atomicAdd(&gsum[t], s);
    atomicAdd(&gsq[t], q);
  }
}

// ---------------------------------------------------------------------------
// finalize1: fold BN1 scale/shift with W1,b1 into 4 coeffs per column
// ---------------------------------------------------------------------------
__global__ void finalize1_kernel(const float* __restrict__ gsum,
                                 const float* __restrict__ gsq,
                                 const float* __restrict__ gamma,
                                 const float* __restrict__ beta,
                                 const float* __restrict__ W1,
                                 const float* __restrict__ b1,
                                 float* __restrict__ fold1, float invN) {
  int c = threadIdx.x;  // 64
  float mu = gsum[c] * invN;
  float var = gsq[c] * invN - mu * mu;
  float sc = gamma[c] * rsqrtf(var + 1e-5f);
  float sh = beta[c] - mu * sc;
  fold1[c] = sc * W1[c * 3 + 0];
  fold1[64 + c] = sc * W1[c * 3 + 1];
  fold1[128 + c] = sc * W1[c * 3 + 2];
  fold1[192 + c] = sc * b1[c] + sh;
}

// finalize BN3: scale, shiftf (bias-folded, for acc path), shiftp (plain)
__global__ void finalize3_kernel(const float* __restrict__ gsum,
                                 const float* __restrict__ gsq,
                                 const float* __restrict__ gamma,
                                 const float* __restrict__ beta,
                                 const float* __restrict__ b,
                                 float* __restrict__ scale,
                                 float* __restrict__ shiftf,
                                 float* __restrict__ shiftp, float invN) {
  int c = blockIdx.x * blockDim.x + threadIdx.x;
  if (c >= 512) return;
  float mu = gsum[c] * invN;
  float var = gsq[c] * invN - mu * mu;
  float sc = gamma[c] * rsqrtf(var + 1e-5f);
  float sh = beta[c] - mu * sc;
  scale[c] = sc;
  shiftf[c] = sc * b[c] + sh;
  shiftp[c] = sh;
}

// ---------------------------------------------------------------------------
// m1: M1 = sum_r h1_r h1_r^T (64x64), s1 = sum_r h1_r.
// ---------------------------------------------------------------------------
__global__ __launch_bounds__(256, 4) void m1_kernel(
    const float* __restrict__ x2, const float* __restrict__ fold1,
    float* __restrict__ M1, float* __restrict__ s1) {
  __shared__ float sF[256];
  __shared__ float xs[768];
  __shared__ __bf16 h1T[64 * 264];  // [col][row], row-pad 264
  __shared__ float s1s[4][64];

  const int t = threadIdx.x;
  const int lane = t & 63, wave = t >> 6;
  const int lrow = lane & 15, lgrp = lane >> 4;

  sF[t] = fold1[t];
  if (t < 192)
    ((float4*)xs)[t] = ((const float4*)(x2 + (size_t)blockIdx.x * 768))[t];
  __syncthreads();

  const int c0 = (t & 3) * 16;
  const int r0 = t >> 2;
  float sAcc[16] = {};
#pragma unroll
  for (int s = 0; s < 4; ++s) {
    int r = r0 + s * 64;
    float X0 = xs[r * 3], X1 = xs[r * 3 + 1], X2 = xs[r * 3 + 2];
#pragma unroll
    for (int j = 0; j < 16; ++j) {
      int c = c0 + j;
      float h = fmaxf(
          fmaf(sF[c], X0, fmaf(sF[64 + c], X1, fmaf(sF[128 + c], X2, sF[192 + c]))),
          0.f);
      sAcc[j] += h;
      h1T[c * 264 + r] = (__bf16)h;
    }
  }
  __syncthreads();

  f32x4 acc[4] = {};
#pragma unroll
  for (int kk = 0; kk < 256; kk += 32) {
    bf16x8 af = *(const bf16x8*)&h1T[(wave * 16 + lrow) * 264 + kk + lgrp * 8];
#pragma unroll
    for (int n = 0; n < 4; ++n) {
      bf16x8 bfr = *(const bf16x8*)&h1T[(n * 16 + lrow) * 264 + kk + lgrp * 8];
      acc[n] = MFMA_BF16(af, bfr, acc[n], 0, 0, 0);
    }
  }
#pragma unroll
  for (int n = 0; n < 4; ++n)
#pragma unroll
    for (int rr = 0; rr < 4; ++rr)
      atomicAdd(&M1[(wave * 16 + lgrp * 4 + rr) * 64 + n * 16 + lrow],
                acc[n][rr]);

#pragma unroll
  for (int j = 0; j < 16; ++j) {
    float v = sAcc[j];
    v += __shfl_xor(v, 4);
    v += __shfl_xor(v, 8);
    v += __shfl_xor(v, 16);
    v += __shfl_xor(v, 32);
    if (lane < 4) s1s[wave][(lane & 3) * 16 + j] = v;
  }
  __syncthreads();
  if (t < 64)
    atomicAdd(&s1[t], s1s[0][t] + s1s[1][t] + s1s[2][t] + s1s[3][t]);
}

// ---------------------------------------------------------------------------
// finalize2v: per col c of layer 2, q = w^T M1 w; derive BN2 scale/shiftf.
// ---------------------------------------------------------------------------
__global__ __launch_bounds__(256) void finalize2v_kernel(
    const float* __restrict__ M1, const float* __restrict__ s1,
    const float* __restrict__ W2, const float* __restrict__ b2,
    const float* __restrict__ gamma2, const float* __restrict__ beta2,
    float* __restrict__ scale2, float* __restrict__ shift2f, float fN) {
  __shared__ float sM[64 * 65];
  __shared__ float ss[64];
  int t = threadIdx.x;
  for (int i = t; i < 4096; i += 256) sM[(i >> 6) * 65 + (i & 63)] = M1[i];
  if (t < 64) ss[t] = s1[t];
  __syncthreads();
  int lane = t & 63;
  int col = blockIdx.x * 4 + (t >> 6);
  float wi = W2[(size_t)col * 64 + lane];
  float p = 0.f;
#pragma unroll
  for (int j = 0; j < 64; ++j) p = fmaf(sM[lane * 65 + j], __shfl(wi, j), p);
  float qi = wi * p;
  float swi = ss[lane] * wi;
#pragma unroll
  for (int off = 1; off < 64; off <<= 1) {
    qi += __shfl_xor(qi, off);
    swi += __shfl_xor(swi, off);
  }
  if (lane == 0) {
    float b = b2[col];
    float sy = swi + fN * b;
    float sqs = qi + 2.f * b * swi + fN * b * b;
    float mu = sy / fN;
    float var = sqs / fN - mu * mu;
    float sc = gamma2[col] * rsqrtf(var + 1e-5f);
    scale2[col] = sc;
    shift2f[col] = (beta2[col] - mu * sc) + sc * b;
  }
}

// ---------------------------------------------------------------------------
// Fused kernel, register-resident W3, pad-stride LDS, af double-buffer.
// MODE 1: stats only.  MODE 3: stats + store y3 (bf16).  MODE 2: out path.
// ---------------------------------------------------------------------------
#define G3_MFMA(AF, K)                                        \
  __builtin_amdgcn_s_setprio(1);                              \
  _Pragma("unroll") for (int m = 0; m < 4; ++m) {             \
    acc[m][0] = MFMA_BF16(AF[m], b3r[K][0], acc[m][0], 0, 0, 0); \
    acc[m][1] = MFMA_BF16(AF[m], b3r[K][1], acc[m][1], 0, 0, 0); \
  }                                                           \
  __builtin_amdgcn_s_setprio(0);

template <int MODE>
__global__ __launch_bounds__(512, 2) void fused_kernel(
    const float* __restrict__ x2, const float* __restrict__ fold1,
    const __bf16* __restrict__ W2bf, const float* __restrict__ scale2,
    const float* __restrict__ shift2f, const __bf16* __restrict__ W3bf,
    const float* __restrict__ b3, const float* __restrict__ scale3,
    const float* __restrict__ shift3f, const float* __restrict__ W4,
    const float* __restrict__ b4, float* __restrict__ gsum3,
    float* __restrict__ gsq3, float* __restrict__ out,
    __bf16* __restrict__ y3o) {
  __shared__ __bf16 h1[64 * 72];      // 9 KB, row stride 72 (144B)
  __shared__ __bf16 h2[64 * 520];     // 65 KB, row stride 520 (1040B)
  __shared__ __bf16 sW2[512 * 72];    // 72 KB, [channel][k] stride 72
  __shared__ float sF[256];
  __shared__ float sSc2[512], sSh2[512];
  __shared__ float outaccW[8][64][2];  // 4 KB (MODE 2)

  const int t = threadIdx.x;
  const int lane = t & 63, wave = t >> 6;
  const int lrow = lane & 15, lgrp = lane >> 4;
  const int colHalf = blockIdx.x & 1;
  const int rowBlk = blockIdx.x >> 1;
  const int wCol3 = colHalf * 256 + wave * 32;  // GEMM3 col base (this wave)
  const int wCol2 = wave * 64;                  // GEMM2 channel base

  // ---- one-time LDS staging ----
  if (t < 256) sF[t] = fold1[t];
  sSc2[t & 511] = scale2[t & 511];
  sSh2[t & 511] = shift2f[t & 511];
#pragma unroll
  for (int i = 0; i < 8; ++i) {
    int seg = i * 512 + t;
    int ch = seg >> 3;
    int c0 = (seg & 7) * 8;
    bf16x8 v = *(const bf16x8*)&W2bf[ch * 64 + c0];
    *(bf16x8*)&sW2[ch * 72 + c0] = v;
  }

  // ---- one-time: W3 fragments -> registers ----
  bf16x8 b3r[16][2];
#pragma unroll
  for (int k = 0; k < 16; ++k)
#pragma unroll
    for (int n = 0; n < 2; ++n)
      b3r[k][n] = *(const bf16x8*)&W3bf[(size_t)(wCol3 + n * 16 + lrow) * 512 +
                                        k * 32 + lgrp * 8];

  const int c3a = wCol3 + lrow, c3b = wCol3 + 16 + lrow;
  float b3a = 0.f, b3b = 0.f;
  float sc3a = 0.f, sc3b = 0.f, sh3a = 0.f, sh3b = 0.f;
  float w40a = 0.f, w40b = 0.f, w41a = 0.f, w41b = 0.f, B40 = 0.f, B41 = 0.f;
  if (MODE != 2) {
    b3a = b3[c3a];
    b3b = b3[c3b];
  } else {
    sc3a = scale3[c3a];
    sc3b = scale3[c3b];
    sh3a = shift3f[c3a];
    sh3b = shift3f[c3b];
    w40a = W4[c3a];
    w40b = W4[c3b];
    w41a = W4[512 + c3a];
    w41b = W4[512 + c3b];
    B40 = b4[0];
    B41 = b4[1];
  }
  float csA = 0.f, cqA = 0.f, csB = 0.f, cqB = 0.f;

  // x2 prefetch for g=0 (thread's h1-stage row is t>>3)
  const int hr = t >> 3, hc0 = (t & 7) * 8;
  const float* xbase = x2 + ((size_t)rowBlk * 1024 + hr) * 3;
  float xa = xbase[0], xb = xbase[1], xc = xbase[2];

  for (int g = 0; g < 16; ++g) {
    const int rBase = (rowBlk * 16 + g) * 64;

    // ---- stage h1 from prefetched x2 ----
    {
      bf16x8 hv;
#pragma unroll
      for (int j = 0; j < 8; ++j) {
        int c = hc0 + j;
        float h = fmaf(sF[c], xa,
                       fmaf(sF[64 + c], xb, fmaf(sF[128 + c], xc, sF[192 + c])));
        hv[j] = (__bf16)fmaxf(h, 0.f);
      }
      *(bf16x8*)&h1[hr * 72 + hc0] = hv;
    }
    __syncthreads();  // B1: h1 ready; prev GEMM3 done -> h2 writable

    // ---- GEMM2 (swapped operands): h2[:, wCol2..+64] ----
    {
      f32x4 a2[4][4] = {};  // [n][m]
#pragma unroll
      for (int kk = 0; kk < 2; ++kk) {
        bf16x8 af[4];
#pragma unroll
        for (int m = 0; m < 4; ++m)
          af[m] = *(const bf16x8*)&h1[(m * 16 + lrow) * 72 + kk * 32 + lgrp * 8];
#pragma unroll
        for (int n = 0; n < 4; ++n) {
          bf16x8 bw = *(const bf16x8*)&sW2[(wCol2 + n * 16 + lrow) * 72 +
                                           kk * 32 + lgrp * 8];
#pragma unroll
          for (int m = 0; m < 4; ++m)
            a2[n][m] = MFMA_BF16(bw, af[m], a2[n][m], 0, 0, 0);
        }
      }
#pragma unroll
      for (int n = 0; n < 4; ++n) {
        int ch0 = wCol2 + n * 16 + lgrp * 4;
        float s0 = sSc2[ch0], s1v = sSc2[ch0 + 1], s2v = sSc2[ch0 + 2],
              s3v = sSc2[ch0 + 3];
        float z0 = sSh2[ch0], z1 = sSh2[ch0 + 1], z2 = sSh2[ch0 + 2],
              z3 = sSh2[ch0 + 3];
#pragma unroll
        for (int m = 0; m < 4; ++m) {
          int row = m * 16 + lrow;
          bf16x4 hv;
          hv[0] = (__bf16)fmaxf(fmaf(s0, a2[n][m][0], z0), 0.f);
          hv[1] = (__bf16)fmaxf(fmaf(s1v, a2[n][m][1], z1), 0.f);
          hv[2] = (__bf16)fmaxf(fmaf(s2v, a2[n][m][2], z2), 0.f);
          hv[3] = (__bf16)fmaxf(fmaf(s3v, a2[n][m][3], z3), 0.f);
          *(bf16x4*)&h2[row * 520 + ch0] = hv;
        }
      }
    }
    __syncthreads();  // B2: h2 ready

    // ---- x2 prefetch for next rg (hides under GEMM3) ----
    if (g < 15) {
      const float* xn = xbase + (size_t)(g + 1) * 192;
      xa = xn[0];
      xb = xn[1];
      xc = xn[2];
    }

    // ---- GEMM3: af double-buffered, register-B MFMA ----
    f32x4 acc[4][2] = {};  // [m][n]
    bf16x8 afA[4], afB[4];
#pragma unroll
    for (int m = 0; m < 4; ++m)
      afA[m] = *(const bf16x8*)&h2[(m * 16 + lrow) * 520 + lgrp * 8];
#pragma unroll
    for (int k = 0; k < 16; k += 2) {
      // even step: compute afA, prefetch afB (k+1)
#pragma unroll
      for (int m = 0; m < 4; ++m)
        afB[m] = *(const bf16x8*)&h2[(m * 16 + lrow) * 520 + (k + 1) * 32 +
                                     lgrp * 8];
      G3_MFMA(afA, k)
      // odd step: compute afB, prefetch afA (k+2)
      if (k < 14) {
#pragma unroll
        for (int m = 0; m < 4; ++m)
          afA[m] = *(const bf16x8*)&h2[(m * 16 + lrow) * 520 + (k + 2) * 32 +
                                       lgrp * 8];
      }
      G3_MFMA(afB, k + 1)
    }

    if (MODE != 2) {
#pragma unroll
      for (int m = 0; m < 4; ++m)
#pragma unroll
        for (int rr = 0; rr < 4; ++rr) {
          float ya = acc[m][0][rr] + b3a;
          float yb = acc[m][1][rr] + b3b;
          csA += ya;
          cqA = fmaf(ya, ya, cqA);
          csB += yb;
          cqB = fmaf(yb, yb, cqB);
          if (MODE == 3) {
            size_t row = (size_t)(rBase + m * 16 + lgrp * 4 + rr);
            y3o[row * 512 + c3a] = (__bf16)ya;
            y3o[row * 512 + c3b] = (__bf16)yb;
          }
        }
    } else {
#pragma unroll
      for (int m = 0; m < 4; ++m)
#pragma unroll
        for (int rr = 0; rr < 4; ++rr) {
          float ha = fmaxf(fmaf(sc3a, acc[m][0][rr], sh3a), 0.f);
          float hb = fmaxf(fmaf(sc3b, acc[m][1][rr], sh3b), 0.f);
          float dd0 = fmaf(ha, w40a, hb * w40b);
          float dd1 = fmaf(ha, w41a, hb * w41b);
          dd0 += __shfl_xor(dd0, 1);
          dd1 += __shfl_xor(dd1, 1);
          dd0 += __shfl_xor(dd0, 2);
          dd1 += __shfl_xor(dd1, 2);
          dd0 += __shfl_xor(dd0, 4);
          dd1 += __shfl_xor(dd1, 4);
          dd0 += __shfl_xor(dd0, 8);
          dd1 += __shfl_xor(dd1, 8);
          if (lrow == 0) {
            int row = m * 16 + lgrp * 4 + rr;
            outaccW[wave][row][0] = dd0;
            outaccW[wave][row][1] = dd1;
          }
        }
      __syncthreads();  // B_epi: outaccW slots complete
      if (t < 128) {
        int row = t >> 1, o = t & 1;
        float s = 0.f;
#pragma unroll
        for (int w = 0; w < 8; ++w) s += outaccW[w][row][o];
        if (colHalf == 0) s += (o == 0) ? B40 : B41;
        atomicAdd(&out[(size_t)(rBase + row) * 2 + o], s);
      }
    }
  }

  if (MODE != 2) {
    csA += __shfl_xor(csA, 16);
    cqA += __shfl_xor(cqA, 16);
    csB += __shfl_xor(csB, 16);
    cqB += __shfl_xor(cqB, 16);
    csA += __shfl_xor(csA, 32);
    cqA += __shfl_xor(cqA, 32);
    csB += __shfl_xor(csB, 32);
    cqB += __shfl_xor(cqB, 32);
    if (lgrp == 0) {
      atomicAdd(&gsum3[c3a], csA);
      atomicAdd(&gsq3[c3a], cqA);
      atomicAdd(&gsum3[c3b], csB);
      atomicAdd(&gsq3[c3b], cqB);
    }
  }
}

// ---------------------------------------------------------------------------
// stream_out: out = relu(sc3*y3 + sh3p) @ W4^T + b4, y3 bf16 from HBM.
// ---------------------------------------------------------------------------
__global__ __launch_bounds__(256) void stream_out_kernel(
    const __bf16* __restrict__ y3, const float* __restrict__ scale3,
    const float* __restrict__ shift3p, const float* __restrict__ W4,
    const float* __restrict__ b4, float* __restrict__ out, int N) {
  __shared__ float sSc[512], sSh[512], sW0[512], sW1[512];
  int t = threadIdx.x;
  for (int i = t; i < 512; i += 256) {
    sSc[i] = scale3[i];
    sSh[i] = shift3p[i];
    sW0[i] = W4[i];
    sW1[i] = W4[512 + i];
  }
  __syncthreads();
  int lane = t & 63, wv = t >> 6;
  int c0 = lane * 8;
  float fsc[8], fsh[8], fw0[8], fw1[8];
#pragma unroll
  for (int j = 0; j < 8; ++j) {
    fsc[j] = sSc[c0 + j];
    fsh[j] = sSh[c0 + j];
    fw0[j] = sW0[c0 + j];
    fw1[j] = sW1[c0 + j];
  }
  float B0 = b4[0], B1 = b4[1];
  for (size_t row = (size_t)blockIdx.x * 4 + wv; row < (size_t)N;
       row += (size_t)gridDim.x * 4) {
    bf16x8 v = *(const bf16x8*)(y3 + row * 512 + c0);
    float d0 = 0.f, d1 = 0.f;
#pragma unroll
    for (int j = 0; j < 8; ++j) {
      float h = fmaxf(fmaf(fsc[j], (float)v[j], fsh[j]), 0.f);
      d0 = fmaf(h, fw0[j], d0);
      d1 = fmaf(h, fw1[j], d1);
    }
#pragma unroll
    for (int off = 1; off < 64; off <<= 1) {
      d0 += __shfl_xor(d0, off);
      d1 += __shfl_xor(d1, off);
    }
    if (lane == 0) {
      out[row * 2 + 0] = d0 + B0;
      out[row * 2 + 1] = d1 + B1;
    }
  }
}

// ---------------------------------------------------------------------------
extern "C" void kernel_launch(void* const* d_in, const int* in_sizes, int n_in,
                              void* d_out, int out_size, void* d_ws,
                              size_t ws_size, hipStream_t stream) {
  const float* x2 = (const float*)d_in[1];
  const float* W1 = (const float*)d_in[2];
  const float* b1 = (const float*)d_in[3];
  const float* W2 = (const float*)d_in[4];
  const float* b2 = (const float*)d_in[5];
  const float* W3 = (const float*)d_in[6];
  const float* b3 = (const float*)d_in[7];
  const float* W4 = (const float*)d_in[8];
  const float* b4 = (const float*)d_in[9];
  const float* gamma1 = (const float*)d_in[10];
  const float* beta1 = (const float*)d_in[11];
  const float* gamma2 = (const float*)d_in[12];
  const float* beta2 = (const float*)d_in[13];
  const float* gamma3 = (const float*)d_in[14];
  const float* beta3 = (const float*)d_in[15];
  float* out = (float*)d_out;

  const int N = in_sizes[1] / 3;  // 262144
  const float invN = 1.0f / (float)N;

  // --- small scratch layout (< 1 MiB) ---
  float* f0 = (float*)d_ws;
  float* gsum1 = f0;           // 64
  float* gsq1 = f0 + 64;       // 64
  float* M1 = f0 + 128;        // 4096
  float* s1 = f0 + 4224;       // 64
  float* gsum3 = f0 + 4288;    // 512
  float* gsq3 = f0 + 4800;     // 512  (zeroed region ends at 5312)
  float* fold1 = f0 + 5312;    // 256
  float* scale2 = f0 + 5568;   // 512
  float* shift2f = f0 + 6080;  // 512
  float* scale3 = f0 + 6592;   // 512
  float* shift3f = f0 + 7104;  // 512
  float* shift3p = f0 + 7616;  // 512
  __bf16* W2bf = (__bf16*)(f0 + 8128);  // 32768 elems
  __bf16* W3bf = W2bf + 32768;          // 262144 elems; ends ~622 KB

  // --- y3 store path gate (known to fail when ws < 269 MB; kept as fallback)
  const size_t y3off = (size_t)1 << 20;
  const size_t need = y3off + (size_t)N * 512 * 2;
  const bool storePath = (ws_size >= need);
  __bf16* y3bf = (__bf16*)((char*)d_ws + y3off);

  prep_kernel<<<1024, 256, 0, stream>>>(W2, W3, W2bf, W3bf, f0);
  stats1_kernel<<<N / 128, 256, 0, stream>>>(x2, W1, b1, gsum1, gsq1);
  finalize1_kernel<<<1, 64, 0, stream>>>(gsum1, gsq1, gamma1, beta1, W1, b1,
                                         fold1, invN);
  m1_kernel<<<N / 256, 256, 0, stream>>>(x2, fold1, M1, s1);
  finalize2v_kernel<<<128, 256, 0, stream>>>(M1, s1, W2, b2, gamma2, beta2,
                                             scale2, shift2f, (float)N);
  if (storePath) {
    fused_kernel<3><<<512, 512, 0, stream>>>(
        x2, fold1, W2bf, scale2, shift2f, W3bf, b3, scale3, shift3f, W4, b4,
        gsum3, gsq3, out, y3bf);
    finalize3_kernel<<<1, 512, 0, stream>>>(gsum3, gsq3, gamma3, beta3, b3,
                                            scale3, shift3f, shift3p, invN);
    stream_out_kernel<<<2048, 256, 0, stream>>>(y3bf, scale3, shift3p, W4, b4,
                                                out, N);
  } else {
    fused_kernel<1><<<512, 512, 0, stream>>>(
        x2, fold1, W2bf, scale2, shift2f, W3bf, b3, scale3, shift3f, W4, b4,
        gsum3, gsq3, out, nullptr);
    finalize3_kernel<<<1, 512, 0, stream>>>(gsum3, gsq3, gamma3, beta3, b3,
                                            scale3, shift3f, shift3p, invN);
    hipMemsetAsync(out, 0, (size_t)N * 2 * sizeof(float), stream);
    fused_kernel<2><<<512, 512, 0, stream>>>(
        x2, fold1, W2bf, scale2, shift2f, W3bf, b3, scale3, shift3f, W4, b4,
        gsum3, gsq3, out, nullptr);
  }
}

// Round 8
// 545.687 us; speedup vs baseline: 2.7789x; 1.0037x over previous
//
#include <hip/hip_runtime.h>

typedef __bf16 bf16x4 __attribute__((ext_vector_type(4)));
typedef __bf16 bf16x8 __attribute__((ext_vector_type(8)));
typedef float f32x4 __attribute__((ext_vector_type(4)));

#define MFMA_BF16 __builtin_amdgcn_mfma_f32_16x16x32_bf16

// ---------------------------------------------------------------------------
// prep: zero accumulators (5312 f32), cast W2/W3 to bf16
// ---------------------------------------------------------------------------
__global__ __launch_bounds__(256) void prep_kernel(
    const float* __restrict__ W2, const float* __restrict__ W3,
    __bf16* __restrict__ W2bf, __bf16* __restrict__ W3bf,
    float* __restrict__ stats) {
  int i = blockIdx.x * 256 + threadIdx.x;
  if (i < 32768) W2bf[i] = (__bf16)W2[i];
  if (i < 262144) W3bf[i] = (__bf16)W3[i];
  if (i < 5312) stats[i] = 0.f;
}

// ---------------------------------------------------------------------------
// stats1: column stats of y1 = x2 @ W1^T + b1 (no store)
// ---------------------------------------------------------------------------
__global__ __launch_bounds__(256) void stats1_kernel(
    const float* __restrict__ x, const float* __restrict__ W1,
    const float* __restrict__ b1, float* __restrict__ gsum,
    float* __restrict__ gsq) {
  int t = threadIdx.x;
  int c = t & 63;
  int rw = t >> 6;
  float w0 = W1[c * 3 + 0], w1 = W1[c * 3 + 1], w2 = W1[c * 3 + 2];
  float b = b1[c];
  int base = blockIdx.x * 128;
  float sum = 0.f, sq = 0.f;
#pragma unroll 4
  for (int i = 0; i < 32; ++i) {
    int row = base + i * 4 + rw;
    const float* xp = x + (size_t)row * 3;
    float y = fmaf(xp[0], w0, fmaf(xp[1], w1, fmaf(xp[2], w2, b)));
    sum += y;
    sq += y * y;
  }
  __shared__ float ssum[256], ssq[256];
  ssum[t] = sum;
  ssq[t] = sq;
  __syncthreads();
  if (t < 64) {
    float s = ssum[t] + ssum[t + 64] + ssum[t + 128] + ssum[t + 192];
    float q = ssq[t] + ssq[t + 64] + ssq[t + 128] + ssq[t + 192];
    atomicAdd(&gsum[t], s);
    atomicAdd(&gsq[t], q);
  }
}

// ---------------------------------------------------------------------------
// finalize1: fold BN1 scale/shift with W1,b1 into 4 coeffs per column
// ---------------------------------------------------------------------------
__global__ void finalize1_kernel(const float* __restrict__ gsum,
                                 const float* __restrict__ gsq,
                                 const float* __restrict__ gamma,
                                 const float* __restrict__ beta,
                                 const float* __restrict__ W1,
                                 const float* __restrict__ b1,
                                 float* __restrict__ fold1, float invN) {
  int c = threadIdx.x;  // 64
  float mu = gsum[c] * invN;
  float var = gsq[c] * invN - mu * mu;
  float sc = gamma[c] * rsqrtf(var + 1e-5f);
  float sh = beta[c] - mu * sc;
  fold1[c] = sc * W1[c * 3 + 0];
  fold1[64 + c] = sc * W1[c * 3 + 1];
  fold1[128 + c] = sc * W1[c * 3 + 2];
  fold1[192 + c] = sc * b1[c] + sh;
}

// finalize BN3: scale, shiftf (bias-folded, for acc path), shiftp (plain)
__global__ void finalize3_kernel(const float* __restrict__ gsum,
                                 const float* __restrict__ gsq,
                                 const float* __restrict__ gamma,
                                 const float* __restrict__ beta,
                                 const float* __restrict__ b,
                                 float* __restrict__ scale,
                                 float* __restrict__ shiftf,
                                 float* __restrict__ shiftp, float invN) {
  int c = blockIdx.x * blockDim.x + threadIdx.x;
  if (c >= 512) return;
  float mu = gsum[c] * invN;
  float var = gsq[c] * invN - mu * mu;
  float sc = gamma[c] * rsqrtf(var + 1e-5f);
  float sh = beta[c] - mu * sc;
  scale[c] = sc;
  shiftf[c] = sc * b[c] + sh;
  shiftp[c] = sh;
}

// ---------------------------------------------------------------------------
// m1: M1 = sum_r h1_r h1_r^T (64x64), s1 = sum_r h1_r.
// ---------------------------------------------------------------------------
__global__ __launch_bounds__(256, 4) void m1_kernel(
    const float* __restrict__ x2, const float* __restrict__ fold1,
    float* __restrict__ M1, float* __restrict__ s1) {
  __shared__ float sF[256];
  __shared__ float xs[768];
  __shared__ __bf16 h1T[64 * 264];  // [col][row], row-pad 264
  __shared__ float s1s[4][64];

  const int t = threadIdx.x;
  const int lane = t & 63, wave = t >> 6;
  const int lrow = lane & 15, lgrp = lane >> 4;

  sF[t] = fold1[t];
  if (t < 192)
    ((float4*)xs)[t] = ((const float4*)(x2 + (size_t)blockIdx.x * 768))[t];
  __syncthreads();

  const int c0 = (t & 3) * 16;
  const int r0 = t >> 2;
  float sAcc[16] = {};
#pragma unroll
  for (int s = 0; s < 4; ++s) {
    int r = r0 + s * 64;
    float X0 = xs[r * 3], X1 = xs[r * 3 + 1], X2 = xs[r * 3 + 2];
#pragma unroll
    for (int j = 0; j < 16; ++j) {
      int c = c0 + j;
      float h = fmaxf(
          fmaf(sF[c], X0, fmaf(sF[64 + c], X1, fmaf(sF[128 + c], X2, sF[192 + c]))),
          0.f);
      sAcc[j] += h;
      h1T[c * 264 + r] = (__bf16)h;
    }
  }
  __syncthreads();

  f32x4 acc[4] = {};
#pragma unroll
  for (int kk = 0; kk < 256; kk += 32) {
    bf16x8 af = *(const bf16x8*)&h1T[(wave * 16 + lrow) * 264 + kk + lgrp * 8];
#pragma unroll
    for (int n = 0; n < 4; ++n) {
      bf16x8 bfr = *(const bf16x8*)&h1T[(n * 16 + lrow) * 264 + kk + lgrp * 8];
      acc[n] = MFMA_BF16(af, bfr, acc[n], 0, 0, 0);
    }
  }
#pragma unroll
  for (int n = 0; n < 4; ++n)
#pragma unroll
    for (int rr = 0; rr < 4; ++rr)
      atomicAdd(&M1[(wave * 16 + lgrp * 4 + rr) * 64 + n * 16 + lrow],
                acc[n][rr]);

#pragma unroll
  for (int j = 0; j < 16; ++j) {
    float v = sAcc[j];
    v += __shfl_xor(v, 4);
    v += __shfl_xor(v, 8);
    v += __shfl_xor(v, 16);
    v += __shfl_xor(v, 32);
    if (lane < 4) s1s[wave][(lane & 3) * 16 + j] = v;
  }
  __syncthreads();
  if (t < 64)
    atomicAdd(&s1[t], s1s[0][t] + s1s[1][t] + s1s[2][t] + s1s[3][t]);
}

// ---------------------------------------------------------------------------
// finalize2v: per col c of layer 2, q = w^T M1 w; derive BN2 scale/shiftf.
// ---------------------------------------------------------------------------
__global__ __launch_bounds__(256) void finalize2v_kernel(
    const float* __restrict__ M1, const float* __restrict__ s1,
    const float* __restrict__ W2, const float* __restrict__ b2,
    const float* __restrict__ gamma2, const float* __restrict__ beta2,
    float* __restrict__ scale2, float* __restrict__ shift2f, float fN) {
  __shared__ float sM[64 * 65];
  __shared__ float ss[64];
  int t = threadIdx.x;
  for (int i = t; i < 4096; i += 256) sM[(i >> 6) * 65 + (i & 63)] = M1[i];
  if (t < 64) ss[t] = s1[t];
  __syncthreads();
  int lane = t & 63;
  int col = blockIdx.x * 4 + (t >> 6);
  float wi = W2[(size_t)col * 64 + lane];
  float p = 0.f;
#pragma unroll
  for (int j = 0; j < 64; ++j) p = fmaf(sM[lane * 65 + j], __shfl(wi, j), p);
  float qi = wi * p;
  float swi = ss[lane] * wi;
#pragma unroll
  for (int off = 1; off < 64; off <<= 1) {
    qi += __shfl_xor(qi, off);
    swi += __shfl_xor(swi, off);
  }
  if (lane == 0) {
    float b = b2[col];
    float sy = swi + fN * b;
    float sqs = qi + 2.f * b * swi + fN * b * b;
    float mu = sy / fN;
    float var = sqs / fN - mu * mu;
    float sc = gamma2[col] * rsqrtf(var + 1e-5f);
    scale2[col] = sc;
    shift2f[col] = (beta2[col] - mu * sc) + sc * b;
  }
}

// ---------------------------------------------------------------------------
// Fused kernel: register-resident W2 and W3, 4-deep GEMM3 pipeline.
// MODE 3: stats + store y3 bf16 for rowBlk < rStoreBlks.
// MODE 2: BN3+ReLU+@W4 -> out (atomicAdd across colHalf), rowBlk offset.
// ---------------------------------------------------------------------------
#define G3_LD(BUF, K)                                                        \
  _Pragma("unroll") for (int m = 0; m < 4; ++m) BUF[m] =                     \
      *(const bf16x8*)&h2[(m * 16 + lrow) * 520 + (K) * 32 + lgrp * 8];

#define G3_MM(BUF, K)                                                        \
  __builtin_amdgcn_s_setprio(1);                                             \
  _Pragma("unroll") for (int m = 0; m < 4; ++m) {                            \
    acc[m][0] = MFMA_BF16(BUF[m], b3r[K][0], acc[m][0], 0, 0, 0);            \
    acc[m][1] = MFMA_BF16(BUF[m], b3r[K][1], acc[m][1], 0, 0, 0);            \
  }                                                                          \
  __builtin_amdgcn_s_setprio(0);

template <int MODE>
__global__ __launch_bounds__(512, 2) void fused_kernel(
    const float* __restrict__ x2, const float* __restrict__ fold1,
    const __bf16* __restrict__ W2bf, const float* __restrict__ scale2,
    const float* __restrict__ shift2f, const __bf16* __restrict__ W3bf,
    const float* __restrict__ b3, const float* __restrict__ scale3,
    const float* __restrict__ shift3f, const float* __restrict__ W4,
    const float* __restrict__ b4, float* __restrict__ gsum3,
    float* __restrict__ gsq3, float* __restrict__ out,
    __bf16* __restrict__ y3o, int rStoreBlks, int rowBlkOff) {
  __shared__ __bf16 h1[64 * 72];      // 9 KB, row stride 72
  __shared__ __bf16 h2[64 * 520];     // 65 KB, row stride 520
  __shared__ float sF[256];
  __shared__ float sSc2[512], sSh2[512];
  __shared__ float outaccW[8][64][2];  // 4 KB (MODE 2)

  const int t = threadIdx.x;
  const int lane = t & 63, wave = t >> 6;
  const int lrow = lane & 15, lgrp = lane >> 4;
  const int colHalf = blockIdx.x & 1;
  const int rowBlk = rowBlkOff + (int)(blockIdx.x >> 1);
  const int wCol3 = colHalf * 256 + wave * 32;  // GEMM3 col base (this wave)
  const int wCol2 = wave * 64;                  // GEMM2 channel base
  const bool doStore = (MODE == 3) && (rowBlk < rStoreBlks);

  // ---- one-time LDS staging ----
  if (t < 256) sF[t] = fold1[t];
  sSc2[t & 511] = scale2[t & 511];
  sSh2[t & 511] = shift2f[t & 511];

  // ---- one-time: W2, W3 fragments -> registers ----
  bf16x8 b2r[2][4];
#pragma unroll
  for (int kk = 0; kk < 2; ++kk)
#pragma unroll
    for (int n = 0; n < 4; ++n)
      b2r[kk][n] = *(const bf16x8*)&W2bf[(wCol2 + n * 16 + lrow) * 64 +
                                         kk * 32 + lgrp * 8];
  bf16x8 b3r[16][2];
#pragma unroll
  for (int k = 0; k < 16; ++k)
#pragma unroll
    for (int n = 0; n < 2; ++n)
      b3r[k][n] = *(const bf16x8*)&W3bf[(size_t)(wCol3 + n * 16 + lrow) * 512 +
                                        k * 32 + lgrp * 8];

  const int c3a = wCol3 + lrow, c3b = wCol3 + 16 + lrow;
  float b3a = 0.f, b3b = 0.f;
  float sc3a = 0.f, sc3b = 0.f, sh3a = 0.f, sh3b = 0.f;
  float w40a = 0.f, w40b = 0.f, w41a = 0.f, w41b = 0.f, B40 = 0.f, B41 = 0.f;
  if (MODE != 2) {
    b3a = b3[c3a];
    b3b = b3[c3b];
  } else {
    sc3a = scale3[c3a];
    sc3b = scale3[c3b];
    sh3a = shift3f[c3a];
    sh3b = shift3f[c3b];
    w40a = W4[c3a];
    w40b = W4[c3b];
    w41a = W4[512 + c3a];
    w41b = W4[512 + c3b];
    B40 = b4[0];
    B41 = b4[1];
  }
  float csA = 0.f, cqA = 0.f, csB = 0.f, cqB = 0.f;

  // x2 prefetch for g=0 (thread's h1-stage row is t>>3)
  const int hr = t >> 3, hc0 = (t & 7) * 8;
  const float* xbase = x2 + ((size_t)rowBlk * 1024 + hr) * 3;
  float xa = xbase[0], xb = xbase[1], xc = xbase[2];

  __syncthreads();  // sF/sSc2/sSh2 visible to all waves

  for (int g = 0; g < 16; ++g) {
    const int rBase = (rowBlk * 16 + g) * 64;

    // ---- stage h1 from prefetched x2 ----
    {
      bf16x8 hv;
#pragma unroll
      for (int j = 0; j < 8; ++j) {
        int c = hc0 + j;
        float h = fmaf(sF[c], xa,
                       fmaf(sF[64 + c], xb, fmaf(sF[128 + c], xc, sF[192 + c])));
        hv[j] = (__bf16)fmaxf(h, 0.f);
      }
      *(bf16x8*)&h1[hr * 72 + hc0] = hv;
    }
    __syncthreads();  // B1: h1 ready; prev GEMM3 done -> h2 writable

    // ---- GEMM2 (swapped operands, reg-B): h2[:, wCol2..+64] ----
    {
      bf16x8 af2[2][4];
#pragma unroll
      for (int kk = 0; kk < 2; ++kk)
#pragma unroll
        for (int m = 0; m < 4; ++m)
          af2[kk][m] =
              *(const bf16x8*)&h1[(m * 16 + lrow) * 72 + kk * 32 + lgrp * 8];
#pragma unroll
      for (int nh = 0; nh < 2; ++nh) {
        f32x4 a2[2][4] = {};  // [n2][m]
#pragma unroll
        for (int kk = 0; kk < 2; ++kk)
#pragma unroll
          for (int n2 = 0; n2 < 2; ++n2) {
            int n = nh * 2 + n2;
#pragma unroll
            for (int m = 0; m < 4; ++m)
              a2[n2][m] = MFMA_BF16(b2r[kk][n], af2[kk][m], a2[n2][m], 0, 0, 0);
          }
#pragma unroll
        for (int n2 = 0; n2 < 2; ++n2) {
          int ch0 = wCol2 + (nh * 2 + n2) * 16 + lgrp * 4;
          float s0 = sSc2[ch0], s1v = sSc2[ch0 + 1], s2v = sSc2[ch0 + 2],
                s3v = sSc2[ch0 + 3];
          float z0 = sSh2[ch0], z1 = sSh2[ch0 + 1], z2 = sSh2[ch0 + 2],
                z3 = sSh2[ch0 + 3];
#pragma unroll
          for (int m = 0; m < 4; ++m) {
            int row = m * 16 + lrow;
            bf16x4 hv;
            hv[0] = (__bf16)fmaxf(fmaf(s0, a2[n2][m][0], z0), 0.f);
            hv[1] = (__bf16)fmaxf(fmaf(s1v, a2[n2][m][1], z1), 0.f);
            hv[2] = (__bf16)fmaxf(fmaf(s2v, a2[n2][m][2], z2), 0.f);
            hv[3] = (__bf16)fmaxf(fmaf(s3v, a2[n2][m][3], z3), 0.f);
            *(bf16x4*)&h2[row * 520 + ch0] = hv;
          }
        }
      }
    }
    __syncthreads();  // B2: h2 ready

    // ---- x2 prefetch for next rg (hides under GEMM3) ----
    if (g < 15) {
      const float* xn = xbase + (size_t)(g + 1) * 192;
      xa = xn[0];
      xb = xn[1];
      xc = xn[2];
    }

    // ---- GEMM3: 4-deep af pipeline, register-B MFMA ----
    f32x4 acc[4][2] = {};  // [m][n]
    bf16x8 afA[4], afB[4], afC[4], afD[4];
    G3_LD(afA, 0)
    G3_LD(afB, 1)
    G3_LD(afC, 2)
#pragma unroll
    for (int k = 0; k < 16; k += 4) {
      G3_LD(afD, k + 3)
      G3_MM(afA, k)
      if (k < 12) { G3_LD(afA, k + 4) }
      G3_MM(afB, k + 1)
      if (k < 12) { G3_LD(afB, k + 5) }
      G3_MM(afC, k + 2)
      if (k < 12) { G3_LD(afC, k + 6) }
      G3_MM(afD, k + 3)
    }

    if (MODE != 2) {
#pragma unroll
      for (int m = 0; m < 4; ++m)
#pragma unroll
        for (int rr = 0; rr < 4; ++rr) {
          float ya = acc[m][0][rr] + b3a;
          float yb = acc[m][1][rr] + b3b;
          csA += ya;
          cqA = fmaf(ya, ya, cqA);
          csB += yb;
          cqB = fmaf(yb, yb, cqB);
          if (doStore) {
            size_t row = (size_t)(rBase + m * 16 + lgrp * 4 + rr);
            y3o[row * 512 + c3a] = (__bf16)ya;
            y3o[row * 512 + c3b] = (__bf16)yb;
          }
        }
    } else {
#pragma unroll
      for (int m = 0; m < 4; ++m)
#pragma unroll
        for (int rr = 0; rr < 4; ++rr) {
          float ha = fmaxf(fmaf(sc3a, acc[m][0][rr], sh3a), 0.f);
          float hb = fmaxf(fmaf(sc3b, acc[m][1][rr], sh3b), 0.f);
          float dd0 = fmaf(ha, w40a, hb * w40b);
          float dd1 = fmaf(ha, w41a, hb * w41b);
          dd0 += __shfl_xor(dd0, 1);
          dd1 += __shfl_xor(dd1, 1);
          dd0 += __shfl_xor(dd0, 2);
          dd1 += __shfl_xor(dd1, 2);
          dd0 += __shfl_xor(dd0, 4);
          dd1 += __shfl_xor(dd1, 4);
          dd0 += __shfl_xor(dd0, 8);
          dd1 += __shfl_xor(dd1, 8);
          if (lrow == 0) {
            int row = m * 16 + lgrp * 4 + rr;
            outaccW[wave][row][0] = dd0;
            outaccW[wave][row][1] = dd1;
          }
        }
      __syncthreads();  // B_epi: outaccW complete
      if (t < 128) {
        int row = t >> 1, o = t & 1;
        float s = 0.f;
#pragma unroll
        for (int w = 0; w < 8; ++w) s += outaccW[w][row][o];
        if (colHalf == 0) s += (o == 0) ? B40 : B41;
        atomicAdd(&out[(size_t)(rBase + row) * 2 + o], s);
      }
    }
  }

  if (MODE != 2) {
    csA += __shfl_xor(csA, 16);
    cqA += __shfl_xor(cqA, 16);
    csB += __shfl_xor(csB, 16);
    cqB += __shfl_xor(cqB, 16);
    csA += __shfl_xor(csA, 32);
    cqA += __shfl_xor(cqA, 32);
    csB += __shfl_xor(csB, 32);
    cqB += __shfl_xor(cqB, 32);
    if (lgrp == 0) {
      atomicAdd(&gsum3[c3a], csA);
      atomicAdd(&gsq3[c3a], cqA);
      atomicAdd(&gsum3[c3b], csB);
      atomicAdd(&gsq3[c3b], cqB);
    }
  }
}

// ---------------------------------------------------------------------------
// stream_out: out = relu(sc3*y3 + sh3p) @ W4^T + b4, y3 bf16 from HBM.
// ---------------------------------------------------------------------------
__global__ __launch_bounds__(256) void stream_out_kernel(
    const __bf16* __restrict__ y3, const float* __restrict__ scale3,
    const float* __restrict__ shift3p, const float* __restrict__ W4,
    const float* __restrict__ b4, float* __restrict__ out, int N) {
  __shared__ float sSc[512], sSh[512], sW0[512], sW1[512];
  int t = threadIdx.x;
  for (int i = t; i < 512; i += 256) {
    sSc[i] = scale3[i];
    sSh[i] = shift3p[i];
    sW0[i] = W4[i];
    sW1[i] = W4[512 + i];
  }
  __syncthreads();
  int lane = t & 63, wv = t >> 6;
  int c0 = lane * 8;
  float fsc[8], fsh[8], fw0[8], fw1[8];
#pragma unroll
  for (int j = 0; j < 8; ++j) {
    fsc[j] = sSc[c0 + j];
    fsh[j] = sSh[c0 + j];
    fw0[j] = sW0[c0 + j];
    fw1[j] = sW1[c0 + j];
  }
  float B0 = b4[0], B1 = b4[1];
  for (size_t row = (size_t)blockIdx.x * 4 + wv; row < (size_t)N;
       row += (size_t)gridDim.x * 4) {
    bf16x8 v = *(const bf16x8*)(y3 + row * 512 + c0);
    float d0 = 0.f, d1 = 0.f;
#pragma unroll
    for (int j = 0; j < 8; ++j) {
      float h = fmaxf(fmaf(fsc[j], (float)v[j], fsh[j]), 0.f);
      d0 = fmaf(h, fw0[j], d0);
      d1 = fmaf(h, fw1[j], d1);
    }
#pragma unroll
    for (int off = 1; off < 64; off <<= 1) {
      d0 += __shfl_xor(d0, off);
      d1 += __shfl_xor(d1, off);
    }
    if (lane == 0) {
      out[row * 2 + 0] = d0 + B0;
      out[row * 2 + 1] = d1 + B1;
    }
  }
}

// ---------------------------------------------------------------------------
extern "C" void kernel_launch(void* const* d_in, const int* in_sizes, int n_in,
                              void* d_out, int out_size, void* d_ws,
                              size_t ws_size, hipStream_t stream) {
  const float* x2 = (const float*)d_in[1];
  const float* W1 = (const float*)d_in[2];
  const float* b1 = (const float*)d_in[3];
  const float* W2 = (const float*)d_in[4];
  const float* b2 = (const float*)d_in[5];
  const float* W3 = (const float*)d_in[6];
  const float* b3 = (const float*)d_in[7];
  const float* W4 = (const float*)d_in[8];
  const float* b4 = (const float*)d_in[9];
  const float* gamma1 = (const float*)d_in[10];
  const float* beta1 = (const float*)d_in[11];
  const float* gamma2 = (const float*)d_in[12];
  const float* beta2 = (const float*)d_in[13];
  const float* gamma3 = (const float*)d_in[14];
  const float* beta3 = (const float*)d_in[15];
  float* out = (float*)d_out;

  const int N = in_sizes[1] / 3;  // 262144
  const float invN = 1.0f / (float)N;

  // --- small scratch layout (< 1 MiB) ---
  float* f0 = (float*)d_ws;
  float* gsum1 = f0;           // 64
  float* gsq1 = f0 + 64;       // 64
  float* M1 = f0 + 128;        // 4096
  float* s1 = f0 + 4224;       // 64
  float* gsum3 = f0 + 4288;    // 512
  float* gsq3 = f0 + 4800;     // 512  (zeroed region ends at 5312)
  float* fold1 = f0 + 5312;    // 256
  float* scale2 = f0 + 5568;   // 512
  float* shift2f = f0 + 6080;  // 512
  float* scale3 = f0 + 6592;   // 512
  float* shift3f = f0 + 7104;  // 512
  float* shift3p = f0 + 7616;  // 512
  __bf16* W2bf = (__bf16*)(f0 + 8128);  // 32768 elems
  __bf16* W3bf = W2bf + 32768;          // 262144 elems; ends ~622 KB

  // --- adaptive y3 cache: store as many 1024-row blocks as fit ---
  const size_t y3off = (size_t)1 << 20;
  size_t availRows = (ws_size > y3off) ? (ws_size - y3off) / 1024 : 0;
  int rStoreBlks = (int)((availRows / 1024 < (size_t)(N / 1024))
                             ? availRows / 1024
                             : (size_t)(N / 1024));
  const int rStore = rStoreBlks * 1024;
  __bf16* y3bf = (__bf16*)((char*)d_ws + y3off);

  prep_kernel<<<1024, 256, 0, stream>>>(W2, W3, W2bf, W3bf, f0);
  stats1_kernel<<<N / 128, 256, 0, stream>>>(x2, W1, b1, gsum1, gsq1);
  finalize1_kernel<<<1, 64, 0, stream>>>(gsum1, gsq1, gamma1, beta1, W1, b1,
                                         fold1, invN);
  m1_kernel<<<N / 256, 256, 0, stream>>>(x2, fold1, M1, s1);
  finalize2v_kernel<<<128, 256, 0, stream>>>(M1, s1, W2, b2, gamma2, beta2,
                                             scale2, shift2f, (float)N);

  // pass 1: stats (+ y3 store where it fits)
  fused_kernel<3><<<(N / 1024) * 2, 512, 0, stream>>>(
      x2, fold1, W2bf, scale2, shift2f, W3bf, b3, scale3, shift3f, W4, b4,
      gsum3, gsq3, out, y3bf, rStoreBlks, 0);
  finalize3_kernel<<<1, 512, 0, stream>>>(gsum3, gsq3, gamma3, beta3, b3,
                                          scale3, shift3f, shift3p, invN);

  // pass 2a: stream stored rows
  if (rStore > 0)
    stream_out_kernel<<<2048, 256, 0, stream>>>(y3bf, scale3, shift3p, W4, b4,
                                                out, rStore);
  // pass 2b: recompute remainder
  if (rStore < N) {
    hipMemsetAsync(out + (size_t)rStore * 2, 0,
                   (size_t)(N - rStore) * 2 * sizeof(float), stream);
    fused_kernel<2><<<((N - rStore) / 1024) * 2, 512, 0, stream>>>(
        x2, fold1, W2bf, scale2, shift2f, W3bf, b3, scale3, shift3f, W4, b4,
        gsum3, gsq3, out, y3bf, 0, rStoreBlks);
  }
}

// Round 9
// 420.579 us; speedup vs baseline: 3.6056x; 1.2975x over previous
//
#include <hip/hip_runtime.h>

typedef __bf16 bf16x4 __attribute__((ext_vector_type(4)));
typedef __bf16 bf16x8 __attribute__((ext_vector_type(8)));
typedef float f32x4 __attribute__((ext_vector_type(4)));

#define MFMA_BF16 __builtin_amdgcn_mfma_f32_16x16x32_bf16

// ---------------------------------------------------------------------------
// prep: zero accumulators (5312 f32), cast W2/W3 to bf16
// ---------------------------------------------------------------------------
__global__ __launch_bounds__(256) void prep_kernel(
    const float* __restrict__ W2, const float* __restrict__ W3,
    __bf16* __restrict__ W2bf, __bf16* __restrict__ W3bf,
    float* __restrict__ stats) {
  int i = blockIdx.x * 256 + threadIdx.x;
  if (i < 32768) W2bf[i] = (__bf16)W2[i];
  if (i < 262144) W3bf[i] = (__bf16)W3[i];
  if (i < 5312) stats[i] = 0.f;
}

// ---------------------------------------------------------------------------
// stats1: column stats of y1 = x2 @ W1^T + b1 (no store)
// ---------------------------------------------------------------------------
__global__ __launch_bounds__(256) void stats1_kernel(
    const float* __restrict__ x, const float* __restrict__ W1,
    const float* __restrict__ b1, float* __restrict__ gsum,
    float* __restrict__ gsq) {
  int t = threadIdx.x;
  int c = t & 63;
  int rw = t >> 6;
  float w0 = W1[c * 3 + 0], w1 = W1[c * 3 + 1], w2 = W1[c * 3 + 2];
  float b = b1[c];
  int base = blockIdx.x * 128;
  float sum = 0.f, sq = 0.f;
#pragma unroll 4
  for (int i = 0; i < 32; ++i) {
    int row = base + i * 4 + rw;
    const float* xp = x + (size_t)row * 3;
    float y = fmaf(xp[0], w0, fmaf(xp[1], w1, fmaf(xp[2], w2, b)));
    sum += y;
    sq += y * y;
  }
  __shared__ float ssum[256], ssq[256];
  ssum[t] = sum;
  ssq[t] = sq;
  __syncthreads();
  if (t < 64) {
    float s = ssum[t] + ssum[t + 64] + ssum[t + 128] + ssum[t + 192];
    float q = ssq[t] + ssq[t + 64] + ssq[t + 128] + ssq[t + 192];
    atomicAdd(&gsum[t], s);
    atomicAdd(&gsq[t], q);
  }
}

// ---------------------------------------------------------------------------
// finalize1: fold BN1 scale/shift with W1,b1 into 4 coeffs per column
// ---------------------------------------------------------------------------
__global__ void finalize1_kernel(const float* __restrict__ gsum,
                                 const float* __restrict__ gsq,
                                 const float* __restrict__ gamma,
                                 const float* __restrict__ beta,
                                 const float* __restrict__ W1,
                                 const float* __restrict__ b1,
                                 float* __restrict__ fold1, float invN) {
  int c = threadIdx.x;  // 64
  float mu = gsum[c] * invN;
  float var = gsq[c] * invN - mu * mu;
  float sc = gamma[c] * rsqrtf(var + 1e-5f);
  float sh = beta[c] - mu * sc;
  fold1[c] = sc * W1[c * 3 + 0];
  fold1[64 + c] = sc * W1[c * 3 + 1];
  fold1[128 + c] = sc * W1[c * 3 + 2];
  fold1[192 + c] = sc * b1[c] + sh;
}

// finalize BN3: scale, shiftf (bias-folded, for acc path), shiftp (plain)
__global__ void finalize3_kernel(const float* __restrict__ gsum,
                                 const float* __restrict__ gsq,
                                 const float* __restrict__ gamma,
                                 const float* __restrict__ beta,
                                 const float* __restrict__ b,
                                 float* __restrict__ scale,
                                 float* __restrict__ shiftf,
                                 float* __restrict__ shiftp, float invN) {
  int c = blockIdx.x * blockDim.x + threadIdx.x;
  if (c >= 512) return;
  float mu = gsum[c] * invN;
  float var = gsq[c] * invN - mu * mu;
  float sc = gamma[c] * rsqrtf(var + 1e-5f);
  float sh = beta[c] - mu * sc;
  scale[c] = sc;
  shiftf[c] = sc * b[c] + sh;
  shiftp[c] = sh;
}

// ---------------------------------------------------------------------------
// m1: M1 = sum_r h1_r h1_r^T (64x64), s1 = sum_r h1_r.
// ---------------------------------------------------------------------------
__global__ __launch_bounds__(256, 4) void m1_kernel(
    const float* __restrict__ x2, const float* __restrict__ fold1,
    float* __restrict__ M1, float* __restrict__ s1) {
  __shared__ float sF[256];
  __shared__ float xs[768];
  __shared__ __bf16 h1T[64 * 264];  // [col][row], row-pad 264
  __shared__ float s1s[4][64];

  const int t = threadIdx.x;
  const int lane = t & 63, wave = t >> 6;
  const int lrow = lane & 15, lgrp = lane >> 4;

  sF[t] = fold1[t];
  if (t < 192)
    ((float4*)xs)[t] = ((const float4*)(x2 + (size_t)blockIdx.x * 768))[t];
  __syncthreads();

  const int c0 = (t & 3) * 16;
  const int r0 = t >> 2;
  float sAcc[16] = {};
#pragma unroll
  for (int s = 0; s < 4; ++s) {
    int r = r0 + s * 64;
    float X0 = xs[r * 3], X1 = xs[r * 3 + 1], X2 = xs[r * 3 + 2];
#pragma unroll
    for (int j = 0; j < 16; ++j) {
      int c = c0 + j;
      float h = fmaxf(
          fmaf(sF[c], X0, fmaf(sF[64 + c], X1, fmaf(sF[128 + c], X2, sF[192 + c]))),
          0.f);
      sAcc[j] += h;
      h1T[c * 264 + r] = (__bf16)h;
    }
  }
  __syncthreads();

  f32x4 acc[4] = {};
#pragma unroll
  for (int kk = 0; kk < 256; kk += 32) {
    bf16x8 af = *(const bf16x8*)&h1T[(wave * 16 + lrow) * 264 + kk + lgrp * 8];
#pragma unroll
    for (int n = 0; n < 4; ++n) {
      bf16x8 bfr = *(const bf16x8*)&h1T[(n * 16 + lrow) * 264 + kk + lgrp * 8];
      acc[n] = MFMA_BF16(af, bfr, acc[n], 0, 0, 0);
    }
  }
#pragma unroll
  for (int n = 0; n < 4; ++n)
#pragma unroll
    for (int rr = 0; rr < 4; ++rr)
      atomicAdd(&M1[(wave * 16 + lgrp * 4 + rr) * 64 + n * 16 + lrow],
                acc[n][rr]);

#pragma unroll
  for (int j = 0; j < 16; ++j) {
    float v = sAcc[j];
    v += __shfl_xor(v, 4);
    v += __shfl_xor(v, 8);
    v += __shfl_xor(v, 16);
    v += __shfl_xor(v, 32);
    if (lane < 4) s1s[wave][(lane & 3) * 16 + j] = v;
  }
  __syncthreads();
  if (t < 64)
    atomicAdd(&s1[t], s1s[0][t] + s1s[1][t] + s1s[2][t] + s1s[3][t]);
}

// ---------------------------------------------------------------------------
// finalize2v: per col c of layer 2, q = w^T M1 w; derive BN2 scale/shiftf.
// ---------------------------------------------------------------------------
__global__ __launch_bounds__(256) void finalize2v_kernel(
    const float* __restrict__ M1, const float* __restrict__ s1,
    const float* __restrict__ W2, const float* __restrict__ b2,
    const float* __restrict__ gamma2, const float* __restrict__ beta2,
    float* __restrict__ scale2, float* __restrict__ shift2f, float fN) {
  __shared__ float sM[64 * 65];
  __shared__ float ss[64];
  int t = threadIdx.x;
  for (int i = t; i < 4096; i += 256) sM[(i >> 6) * 65 + (i & 63)] = M1[i];
  if (t < 64) ss[t] = s1[t];
  __syncthreads();
  int lane = t & 63;
  int col = blockIdx.x * 4 + (t >> 6);
  float wi = W2[(size_t)col * 64 + lane];
  float p = 0.f;
#pragma unroll
  for (int j = 0; j < 64; ++j) p = fmaf(sM[lane * 65 + j], __shfl(wi, j), p);
  float qi = wi * p;
  float swi = ss[lane] * wi;
#pragma unroll
  for (int off = 1; off < 64; off <<= 1) {
    qi += __shfl_xor(qi, off);
    swi += __shfl_xor(swi, off);
  }
  if (lane == 0) {
    float b = b2[col];
    float sy = swi + fN * b;
    float sqs = qi + 2.f * b * swi + fN * b * b;
    float mu = sy / fN;
    float var = sqs / fN - mu * mu;
    float sc = gamma2[col] * rsqrtf(var + 1e-5f);
    scale2[col] = sc;
    shift2f[col] = (beta2[col] - mu * sc) + sc * b;
  }
}

// ---------------------------------------------------------------------------
// Fused kernel: register-resident W2/W3, 4-deep GEMM3 pipeline, h1-overlap.
// Block handles gCount row-groups starting at rg = gBase + (blockIdx>>1)*gCount.
// MODE 3: stats + store y3 bf16 where rg < rStoreRgs.
// MODE 2 (gCount==1 only): BN3+ReLU+@W4 -> out (atomicAdd across colHalf).
// ---------------------------------------------------------------------------
#define G3_LD(BUF, K)                                                        \
  _Pragma("unroll") for (int m = 0; m < 4; ++m) BUF[m] =                     \
      *(const bf16x8*)&h2[(m * 16 + lrow) * 520 + (K) * 32 + lgrp * 8];

#define G3_MM(BUF, K)                                                        \
  __builtin_amdgcn_s_setprio(1);                                             \
  _Pragma("unroll") for (int m = 0; m < 4; ++m) {                            \
    acc[m][0] = MFMA_BF16(BUF[m], b3r[K][0], acc[m][0], 0, 0, 0);            \
    acc[m][1] = MFMA_BF16(BUF[m], b3r[K][1], acc[m][1], 0, 0, 0);            \
  }                                                                          \
  __builtin_amdgcn_s_setprio(0);

template <int MODE>
__global__ __launch_bounds__(512, 2) void fused_kernel(
    const float* __restrict__ x2, const float* __restrict__ fold1,
    const __bf16* __restrict__ W2bf, const float* __restrict__ scale2,
    const float* __restrict__ shift2f, const __bf16* __restrict__ W3bf,
    const float* __restrict__ b3, const float* __restrict__ scale3,
    const float* __restrict__ shift3f, const float* __restrict__ W4,
    const float* __restrict__ b4, float* __restrict__ gsum3,
    float* __restrict__ gsq3, float* __restrict__ out,
    __bf16* __restrict__ y3o, int gBase, int gCount, int rStoreRgs) {
  __shared__ __bf16 h1[64 * 72];      // 9 KB, row stride 72
  __shared__ __bf16 h2[64 * 520];     // 65 KB, row stride 520
  __shared__ float sF[256];
  __shared__ float sSc2[512], sSh2[512];
  __shared__ float outaccW[8][64][2];  // 4 KB (MODE 2)

  const int t = threadIdx.x;
  const int lane = t & 63, wave = t >> 6;
  const int lrow = lane & 15, lgrp = lane >> 4;
  const int colHalf = blockIdx.x & 1;
  const int rgFirst = gBase + (int)(blockIdx.x >> 1) * gCount;
  const int wCol3 = colHalf * 256 + wave * 32;  // GEMM3 col base (this wave)
  const int wCol2 = wave * 64;                  // GEMM2 channel base
  const bool doStore = (MODE == 3) && (rgFirst < rStoreRgs);

  // ---- one-time LDS staging ----
  if (t < 256) sF[t] = fold1[t];
  sSc2[t & 511] = scale2[t & 511];
  sSh2[t & 511] = shift2f[t & 511];

  // ---- one-time: W2, W3 fragments -> registers ----
  bf16x8 b2r[2][4];
#pragma unroll
  for (int kk = 0; kk < 2; ++kk)
#pragma unroll
    for (int n = 0; n < 4; ++n)
      b2r[kk][n] = *(const bf16x8*)&W2bf[(wCol2 + n * 16 + lrow) * 64 +
                                         kk * 32 + lgrp * 8];
  bf16x8 b3r[16][2];
#pragma unroll
  for (int k = 0; k < 16; ++k)
#pragma unroll
    for (int n = 0; n < 2; ++n)
      b3r[k][n] = *(const bf16x8*)&W3bf[(size_t)(wCol3 + n * 16 + lrow) * 512 +
                                        k * 32 + lgrp * 8];

  const int c3a = wCol3 + lrow, c3b = wCol3 + 16 + lrow;
  float b3a = 0.f, b3b = 0.f;
  float sc3a = 0.f, sc3b = 0.f, sh3a = 0.f, sh3b = 0.f;
  float w40a = 0.f, w40b = 0.f, w41a = 0.f, w41b = 0.f, B40 = 0.f, B41 = 0.f;
  if (MODE != 2) {
    b3a = b3[c3a];
    b3b = b3[c3b];
  } else {
    sc3a = scale3[c3a];
    sc3b = scale3[c3b];
    sh3a = shift3f[c3a];
    sh3b = shift3f[c3b];
    w40a = W4[c3a];
    w40b = W4[c3b];
    w41a = W4[512 + c3a];
    w41b = W4[512 + c3b];
    B40 = b4[0];
    B41 = b4[1];
  }
  float csA = 0.f, cqA = 0.f, csB = 0.f, cqB = 0.f;

  // x2 load for g=0 (thread's h1-stage row is t>>3)
  const int hr = t >> 3, hc0 = (t & 7) * 8;
  const float* xbase = x2 + ((size_t)rgFirst * 64 + hr) * 3;
  float xa = xbase[0], xb = xbase[1], xc = xbase[2];

  __syncthreads();  // sF/sSc2/sSh2 visible

  // ---- prologue: stage h1(0) ----
  {
    bf16x8 hv;
#pragma unroll
    for (int j = 0; j < 8; ++j) {
      int c = hc0 + j;
      float h = fmaf(sF[c], xa,
                     fmaf(sF[64 + c], xb, fmaf(sF[128 + c], xc, sF[192 + c])));
      hv[j] = (__bf16)fmaxf(h, 0.f);
    }
    *(bf16x8*)&h1[hr * 72 + hc0] = hv;
  }
  __syncthreads();  // h1(0) ready

  for (int g = 0; g < gCount; ++g) {
    const int rBase = (rgFirst + g) * 64;

    // issue x loads for g+1 (consumed after B2; latency hidden by GEMM2)
    if (g + 1 < gCount) {
      const float* xn = xbase + (size_t)(g + 1) * 192;
      xa = xn[0];
      xb = xn[1];
      xc = xn[2];
    }

    // ---- GEMM2 (swapped operands, reg-B): h2[:, wCol2..+64] ----
    {
      bf16x8 af2[2][4];
#pragma unroll
      for (int kk = 0; kk < 2; ++kk)
#pragma unroll
        for (int m = 0; m < 4; ++m)
          af2[kk][m] =
              *(const bf16x8*)&h1[(m * 16 + lrow) * 72 + kk * 32 + lgrp * 8];
#pragma unroll
      for (int nh = 0; nh < 2; ++nh) {
        f32x4 a2[2][4] = {};  // [n2][m]
#pragma unroll
        for (int kk = 0; kk < 2; ++kk)
#pragma unroll
          for (int n2 = 0; n2 < 2; ++n2) {
            int n = nh * 2 + n2;
#pragma unroll
            for (int m = 0; m < 4; ++m)
              a2[n2][m] = MFMA_BF16(b2r[kk][n], af2[kk][m], a2[n2][m], 0, 0, 0);
          }
#pragma unroll
        for (int n2 = 0; n2 < 2; ++n2) {
          int ch0 = wCol2 + (nh * 2 + n2) * 16 + lgrp * 4;
          float s0 = sSc2[ch0], s1v = sSc2[ch0 + 1], s2v = sSc2[ch0 + 2],
                s3v = sSc2[ch0 + 3];
          float z0 = sSh2[ch0], z1 = sSh2[ch0 + 1], z2 = sSh2[ch0 + 2],
                z3 = sSh2[ch0 + 3];
#pragma unroll
          for (int m = 0; m < 4; ++m) {
            int row = m * 16 + lrow;
            bf16x4 hv;
            hv[0] = (__bf16)fmaxf(fmaf(s0, a2[n2][m][0], z0), 0.f);
            hv[1] = (__bf16)fmaxf(fmaf(s1v, a2[n2][m][1], z1), 0.f);
            hv[2] = (__bf16)fmaxf(fmaf(s2v, a2[n2][m][2], z2), 0.f);
            hv[3] = (__bf16)fmaxf(fmaf(s3v, a2[n2][m][3], z3), 0.f);
            *(bf16x4*)&h2[row * 520 + ch0] = hv;
          }
        }
      }
    }
    __syncthreads();  // B2: h2 ready; h1(g) reads done

    // ---- stage h1(g+1) (overlaps GEMM3 issue) ----
    if (g + 1 < gCount) {
      bf16x8 hv;
#pragma unroll
      for (int j = 0; j < 8; ++j) {
        int c = hc0 + j;
        float h = fmaf(sF[c], xa,
                       fmaf(sF[64 + c], xb, fmaf(sF[128 + c], xc, sF[192 + c])));
        hv[j] = (__bf16)fmaxf(h, 0.f);
      }
      *(bf16x8*)&h1[hr * 72 + hc0] = hv;
    }

    // ---- GEMM3: 4-deep af pipeline, register-B MFMA ----
    f32x4 acc[4][2] = {};  // [m][n]
    bf16x8 afA[4], afB[4], afC[4], afD[4];
    G3_LD(afA, 0)
    G3_LD(afB, 1)
    G3_LD(afC, 2)
#pragma unroll
    for (int k = 0; k < 16; k += 4) {
      G3_LD(afD, k + 3)
      G3_MM(afA, k)
      if (k < 12) { G3_LD(afA, k + 4) }
      G3_MM(afB, k + 1)
      if (k < 12) { G3_LD(afB, k + 5) }
      G3_MM(afC, k + 2)
      if (k < 12) { G3_LD(afC, k + 6) }
      G3_MM(afD, k + 3)
    }

    if (MODE != 2) {
#pragma unroll
      for (int m = 0; m < 4; ++m)
#pragma unroll
        for (int rr = 0; rr < 4; ++rr) {
          float ya = acc[m][0][rr] + b3a;
          float yb = acc[m][1][rr] + b3b;
          csA += ya;
          cqA = fmaf(ya, ya, cqA);
          csB += yb;
          cqB = fmaf(yb, yb, cqB);
          if (doStore) {
            size_t row = (size_t)(rBase + m * 16 + lgrp * 4 + rr);
            y3o[row * 512 + c3a] = (__bf16)ya;
            y3o[row * 512 + c3b] = (__bf16)yb;
          }
        }
    } else {
#pragma unroll
      for (int m = 0; m < 4; ++m)
#pragma unroll
        for (int rr = 0; rr < 4; ++rr) {
          float ha = fmaxf(fmaf(sc3a, acc[m][0][rr], sh3a), 0.f);
          float hb = fmaxf(fmaf(sc3b, acc[m][1][rr], sh3b), 0.f);
          float dd0 = fmaf(ha, w40a, hb * w40b);
          float dd1 = fmaf(ha, w41a, hb * w41b);
          dd0 += __shfl_xor(dd0, 1);
          dd1 += __shfl_xor(dd1, 1);
          dd0 += __shfl_xor(dd0, 2);
          dd1 += __shfl_xor(dd1, 2);
          dd0 += __shfl_xor(dd0, 4);
          dd1 += __shfl_xor(dd1, 4);
          dd0 += __shfl_xor(dd0, 8);
          dd1 += __shfl_xor(dd1, 8);
          if (lrow == 0) {
            int row = m * 16 + lgrp * 4 + rr;
            outaccW[wave][row][0] = dd0;
            outaccW[wave][row][1] = dd1;
          }
        }
    }
    __syncthreads();  // GEMM3 reads done (h2 free); h1(g+1)/outaccW visible
  }

  if (MODE != 2) {
    csA += __shfl_xor(csA, 16);
    cqA += __shfl_xor(cqA, 16);
    csB += __shfl_xor(csB, 16);
    cqB += __shfl_xor(cqB, 16);
    csA += __shfl_xor(csA, 32);
    cqA += __shfl_xor(cqA, 32);
    csB += __shfl_xor(csB, 32);
    cqB += __shfl_xor(cqB, 32);
    if (lgrp == 0) {
      atomicAdd(&gsum3[c3a], csA);
      atomicAdd(&gsq3[c3a], cqA);
      atomicAdd(&gsum3[c3b], csB);
      atomicAdd(&gsq3[c3b], cqB);
    }
  } else {
    // gCount == 1: single rg, reduce outaccW after loop barrier
    if (t < 128) {
      int row = t >> 1, o = t & 1;
      float s = 0.f;
#pragma unroll
      for (int w = 0; w < 8; ++w) s += outaccW[w][row][o];
      if (colHalf == 0) s += (o == 0) ? B40 : B41;
      atomicAdd(&out[(size_t)(rgFirst * 64 + row) * 2 + o], s);
    }
  }
}

// ---------------------------------------------------------------------------
// stream_out: out = relu(sc3*y3 + sh3p) @ W4^T + b4, y3 bf16 from HBM.
// ---------------------------------------------------------------------------
__global__ __launch_bounds__(256) void stream_out_kernel(
    const __bf16* __restrict__ y3, const float* __restrict__ scale3,
    const float* __restrict__ shift3p, const float* __restrict__ W4,
    const float* __restrict__ b4, float* __restrict__ out, int N) {
  __shared__ float sSc[512], sSh[512], sW0[512], sW1[512];
  int t = threadIdx.x;
  for (int i = t; i < 512; i += 256) {
    sSc[i] = scale3[i];
    sSh[i] = shift3p[i];
    sW0[i] = W4[i];
    sW1[i] = W4[512 + i];
  }
  __syncthreads();
  int lane = t & 63, wv = t >> 6;
  int c0 = lane * 8;
  float fsc[8], fsh[8], fw0[8], fw1[8];
#pragma unroll
  for (int j = 0; j < 8; ++j) {
    fsc[j] = sSc[c0 + j];
    fsh[j] = sSh[c0 + j];
    fw0[j] = sW0[c0 + j];
    fw1[j] = sW1[c0 + j];
  }
  float B0 = b4[0], B1 = b4[1];
  for (size_t row = (size_t)blockIdx.x * 4 + wv; row < (size_t)N;
       row += (size_t)gridDim.x * 4) {
    bf16x8 v = *(const bf16x8*)(y3 + row * 512 + c0);
    float d0 = 0.f, d1 = 0.f;
#pragma unroll
    for (int j = 0; j < 8; ++j) {
      float h = fmaxf(fmaf(fsc[j], (float)v[j], fsh[j]), 0.f);
      d0 = fmaf(h, fw0[j], d0);
      d1 = fmaf(h, fw1[j], d1);
    }
#pragma unroll
    for (int off = 1; off < 64; off <<= 1) {
      d0 += __shfl_xor(d0, off);
      d1 += __shfl_xor(d1, off);
    }
    if (lane == 0) {
      out[row * 2 + 0] = d0 + B0;
      out[row * 2 + 1] = d1 + B1;
    }
  }
}

// ---------------------------------------------------------------------------
extern "C" void kernel_launch(void* const* d_in, const int* in_sizes, int n_in,
                              void* d_out, int out_size, void* d_ws,
                              size_t ws_size, hipStream_t stream) {
  const float* x2 = (const float*)d_in[1];
  const float* W1 = (const float*)d_in[2];
  const float* b1 = (const float*)d_in[3];
  const float* W2 = (const float*)d_in[4];
  const float* b2 = (const float*)d_in[5];
  const float* W3 = (const float*)d_in[6];
  const float* b3 = (const float*)d_in[7];
  const float* W4 = (const float*)d_in[8];
  const float* b4 = (const float*)d_in[9];
  const float* gamma1 = (const float*)d_in[10];
  const float* beta1 = (const float*)d_in[11];
  const float* gamma2 = (const float*)d_in[12];
  const float* beta2 = (const float*)d_in[13];
  const float* gamma3 = (const float*)d_in[14];
  const float* beta3 = (const float*)d_in[15];
  float* out = (float*)d_out;

  const int N = in_sizes[1] / 3;  // 262144
  const float invN = 1.0f / (float)N;

  // --- small scratch layout (< 1 MiB) ---
  float* f0 = (float*)d_ws;
  float* gsum1 = f0;           // 64
  float* gsq1 = f0 + 64;       // 64
  float* M1 = f0 + 128;        // 4096
  float* s1 = f0 + 4224;       // 64
  float* gsum3 = f0 + 4288;    // 512
  float* gsq3 = f0 + 4800;     // 512  (zeroed region ends at 5312)
  float* fold1 = f0 + 5312;    // 256
  float* scale2 = f0 + 5568;   // 512
  float* shift2f = f0 + 6080;  // 512
  float* scale3 = f0 + 6592;   // 512
  float* shift3f = f0 + 7104;  // 512
  float* shift3p = f0 + 7616;  // 512
  __bf16* W2bf = (__bf16*)(f0 + 8128);  // 32768 elems
  __bf16* W3bf = W2bf + 32768;          // 262144 elems; ends ~622 KB

  // --- adaptive y3 cache: store as many 1024-row blocks as fit ---
  const size_t y3off = (size_t)1 << 20;
  size_t availRows = (ws_size > y3off) ? (ws_size - y3off) / 1024 : 0;
  int rStoreBlks = (int)((availRows / 1024 < (size_t)(N / 1024))
                             ? availRows / 1024
                             : (size_t)(N / 1024));
  const int rStore = rStoreBlks * 1024;
  __bf16* y3bf = (__bf16*)((char*)d_ws + y3off);

  prep_kernel<<<1024, 256, 0, stream>>>(W2, W3, W2bf, W3bf, f0);
  stats1_kernel<<<N / 128, 256, 0, stream>>>(x2, W1, b1, gsum1, gsq1);
  finalize1_kernel<<<1, 64, 0, stream>>>(gsum1, gsq1, gamma1, beta1, W1, b1,
                                         fold1, invN);
  m1_kernel<<<N / 256, 256, 0, stream>>>(x2, fold1, M1, s1);
  finalize2v_kernel<<<128, 256, 0, stream>>>(M1, s1, W2, b2, gamma2, beta2,
                                             scale2, shift2f, (float)N);

  // pass 1: stats (+ y3 store where it fits), 16 row-groups per block
  fused_kernel<3><<<(N / 1024) * 2, 512, 0, stream>>>(
      x2, fold1, W2bf, scale2, shift2f, W3bf, b3, scale3, shift3f, W4, b4,
      gsum3, gsq3, out, y3bf, 0, 16, rStoreBlks * 16);
  finalize3_kernel<<<1, 512, 0, stream>>>(gsum3, gsq3, gamma3, beta3, b3,
                                          scale3, shift3f, shift3p, invN);

  // pass 2a: stream stored rows
  if (rStore > 0)
    stream_out_kernel<<<2048, 256, 0, stream>>>(y3bf, scale3, shift3p, W4, b4,
                                                out, rStore);
  // pass 2b: recompute remainder, ONE row-group per block (spread over CUs)
  if (rStore < N) {
    hipMemsetAsync(out + (size_t)rStore * 2, 0,
                   (size_t)(N - rStore) * 2 * sizeof(float), stream);
    fused_kernel<2><<<((N - rStore) / 64) * 2, 512, 0, stream>>>(
        x2, fold1, W2bf, scale2, shift2f, W3bf, b3, scale3, shift3f, W4, b4,
        gsum3, gsq3, out, y3bf, rStore / 64, 1, 0);
  }
}

// Round 10
// 389.807 us; speedup vs baseline: 3.8902x; 1.0789x over previous
//
#include <hip/hip_runtime.h>

typedef __bf16 bf16x4 __attribute__((ext_vector_type(4)));
typedef __bf16 bf16x8 __attribute__((ext_vector_type(8)));
typedef float f32x4 __attribute__((ext_vector_type(4)));

#define MFMA_BF16 __builtin_amdgcn_mfma_f32_16x16x32_bf16

// ---------------------------------------------------------------------------
// prep: zero accumulators (5312 f32), cast W2/W3 to bf16
// ---------------------------------------------------------------------------
__global__ __launch_bounds__(256) void prep_kernel(
    const float* __restrict__ W2, const float* __restrict__ W3,
    __bf16* __restrict__ W2bf, __bf16* __restrict__ W3bf,
    float* __restrict__ stats) {
  int i = blockIdx.x * 256 + threadIdx.x;
  if (i < 32768) W2bf[i] = (__bf16)W2[i];
  if (i < 262144) W3bf[i] = (__bf16)W3[i];
  if (i < 5312) stats[i] = 0.f;
}

// ---------------------------------------------------------------------------
// stats1: column stats of y1 = x2 @ W1^T + b1 (no store)
// ---------------------------------------------------------------------------
__global__ __launch_bounds__(256) void stats1_kernel(
    const float* __restrict__ x, const float* __restrict__ W1,
    const float* __restrict__ b1, float* __restrict__ gsum,
    float* __restrict__ gsq) {
  int t = threadIdx.x;
  int c = t & 63;
  int rw = t >> 6;
  float w0 = W1[c * 3 + 0], w1 = W1[c * 3 + 1], w2 = W1[c * 3 + 2];
  float b = b1[c];
  int base = blockIdx.x * 128;
  float sum = 0.f, sq = 0.f;
#pragma unroll 4
  for (int i = 0; i < 32; ++i) {
    int row = base + i * 4 + rw;
    const float* xp = x + (size_t)row * 3;
    float y = fmaf(xp[0], w0, fmaf(xp[1], w1, fmaf(xp[2], w2, b)));
    sum += y;
    sq += y * y;
  }
  __shared__ float ssum[256], ssq[256];
  ssum[t] = sum;
  ssq[t] = sq;
  __syncthreads();
  if (t < 64) {
    float s = ssum[t] + ssum[t + 64] + ssum[t + 128] + ssum[t + 192];
    float q = ssq[t] + ssq[t + 64] + ssq[t + 128] + ssq[t + 192];
    atomicAdd(&gsum[t], s);
    atomicAdd(&gsq[t], q);
  }
}

// ---------------------------------------------------------------------------
// finalize1: fold BN1 scale/shift with W1,b1 into 4 coeffs per column
// ---------------------------------------------------------------------------
__global__ void finalize1_kernel(const float* __restrict__ gsum,
                                 const float* __restrict__ gsq,
                                 const float* __restrict__ gamma,
                                 const float* __restrict__ beta,
                                 const float* __restrict__ W1,
                                 const float* __restrict__ b1,
                                 float* __restrict__ fold1, float invN) {
  int c = threadIdx.x;  // 64
  float mu = gsum[c] * invN;
  float var = gsq[c] * invN - mu * mu;
  float sc = gamma[c] * rsqrtf(var + 1e-5f);
  float sh = beta[c] - mu * sc;
  fold1[c] = sc * W1[c * 3 + 0];
  fold1[64 + c] = sc * W1[c * 3 + 1];
  fold1[128 + c] = sc * W1[c * 3 + 2];
  fold1[192 + c] = sc * b1[c] + sh;
}

// finalize BN3: scale, shiftf (bias-folded, for acc path), shiftp (plain)
__global__ void finalize3_kernel(const float* __restrict__ gsum,
                                 const float* __restrict__ gsq,
                                 const float* __restrict__ gamma,
                                 const float* __restrict__ beta,
                                 const float* __restrict__ b,
                                 float* __restrict__ scale,
                                 float* __restrict__ shiftf,
                                 float* __restrict__ shiftp, float invN) {
  int c = blockIdx.x * blockDim.x + threadIdx.x;
  if (c >= 512) return;
  float mu = gsum[c] * invN;
  float var = gsq[c] * invN - mu * mu;
  float sc = gamma[c] * rsqrtf(var + 1e-5f);
  float sh = beta[c] - mu * sc;
  scale[c] = sc;
  shiftf[c] = sc * b[c] + sh;
  shiftp[c] = sh;
}

// ---------------------------------------------------------------------------
// m1: M1 = sum_r h1_r h1_r^T (64x64), s1 = sum_r h1_r.
// ---------------------------------------------------------------------------
__global__ __launch_bounds__(256, 4) void m1_kernel(
    const float* __restrict__ x2, const float* __restrict__ fold1,
    float* __restrict__ M1, float* __restrict__ s1) {
  __shared__ float sF[256];
  __shared__ float xs[768];
  __shared__ __bf16 h1T[64 * 264];  // [col][row], row-pad 264
  __shared__ float s1s[4][64];

  const int t = threadIdx.x;
  const int lane = t & 63, wave = t >> 6;
  const int lrow = lane & 15, lgrp = lane >> 4;

  sF[t] = fold1[t];
  if (t < 192)
    ((float4*)xs)[t] = ((const float4*)(x2 + (size_t)blockIdx.x * 768))[t];
  __syncthreads();

  const int c0 = (t & 3) * 16;
  const int r0 = t >> 2;
  float sAcc[16] = {};
#pragma unroll
  for (int s = 0; s < 4; ++s) {
    int r = r0 + s * 64;
    float X0 = xs[r * 3], X1 = xs[r * 3 + 1], X2 = xs[r * 3 + 2];
#pragma unroll
    for (int j = 0; j < 16; ++j) {
      int c = c0 + j;
      float h = fmaxf(
          fmaf(sF[c], X0, fmaf(sF[64 + c], X1, fmaf(sF[128 + c], X2, sF[192 + c]))),
          0.f);
      sAcc[j] += h;
      h1T[c * 264 + r] = (__bf16)h;
    }
  }
  __syncthreads();

  f32x4 acc[4] = {};
#pragma unroll
  for (int kk = 0; kk < 256; kk += 32) {
    bf16x8 af = *(const bf16x8*)&h1T[(wave * 16 + lrow) * 264 + kk + lgrp * 8];
#pragma unroll
    for (int n = 0; n < 4; ++n) {
      bf16x8 bfr = *(const bf16x8*)&h1T[(n * 16 + lrow) * 264 + kk + lgrp * 8];
      acc[n] = MFMA_BF16(af, bfr, acc[n], 0, 0, 0);
    }
  }
#pragma unroll
  for (int n = 0; n < 4; ++n)
#pragma unroll
    for (int rr = 0; rr < 4; ++rr)
      atomicAdd(&M1[(wave * 16 + lgrp * 4 + rr) * 64 + n * 16 + lrow],
                acc[n][rr]);

#pragma unroll
  for (int j = 0; j < 16; ++j) {
    float v = sAcc[j];
    v += __shfl_xor(v, 4);
    v += __shfl_xor(v, 8);
    v += __shfl_xor(v, 16);
    v += __shfl_xor(v, 32);
    if (lane < 4) s1s[wave][(lane & 3) * 16 + j] = v;
  }
  __syncthreads();
  if (t < 64)
    atomicAdd(&s1[t], s1s[0][t] + s1s[1][t] + s1s[2][t] + s1s[3][t]);
}

// ---------------------------------------------------------------------------
// finalize2v: per col c of layer 2, q = w^T M1 w; derive BN2 scale/shiftf.
// ---------------------------------------------------------------------------
__global__ __launch_bounds__(256) void finalize2v_kernel(
    const float* __restrict__ M1, const float* __restrict__ s1,
    const float* __restrict__ W2, const float* __restrict__ b2,
    const float* __restrict__ gamma2, const float* __restrict__ beta2,
    float* __restrict__ scale2, float* __restrict__ shift2f, float fN) {
  __shared__ float sM[64 * 65];
  __shared__ float ss[64];
  int t = threadIdx.x;
  for (int i = t; i < 4096; i += 256) sM[(i >> 6) * 65 + (i & 63)] = M1[i];
  if (t < 64) ss[t] = s1[t];
  __syncthreads();
  int lane = t & 63;
  int col = blockIdx.x * 4 + (t >> 6);
  float wi = W2[(size_t)col * 64 + lane];
  float p = 0.f;
#pragma unroll
  for (int j = 0; j < 64; ++j) p = fmaf(sM[lane * 65 + j], __shfl(wi, j), p);
  float qi = wi * p;
  float swi = ss[lane] * wi;
#pragma unroll
  for (int off = 1; off < 64; off <<= 1) {
    qi += __shfl_xor(qi, off);
    swi += __shfl_xor(swi, off);
  }
  if (lane == 0) {
    float b = b2[col];
    float sy = swi + fN * b;
    float sqs = qi + 2.f * b * swi + fN * b * b;
    float mu = sy / fN;
    float var = sqs / fN - mu * mu;
    float sc = gamma2[col] * rsqrtf(var + 1e-5f);
    scale2[col] = sc;
    shift2f[col] = (beta2[col] - mu * sc) + sc * b;
  }
}

// ---------------------------------------------------------------------------
// Fused kernel: register-resident W2/W3, ONE barrier per row-group.
// Double-buffered h1/h2: per iteration g the three independent tasks
//   GEMM2(g+1)->h2[(g+1)&1]  ||  stage h1(g+2)->h1[g&1]  ||  GEMM3(g)<-h2[g&1]
// overlap between consecutive barriers.
// MODE 3: stats + store y3 bf16 where rg < rStoreRgs.
// MODE 2 (gCount==1): BN3+ReLU+@W4 -> out (atomicAdd across colHalf).
// ---------------------------------------------------------------------------
#define G3_LD(BUF, K)                                                        \
  _Pragma("unroll") for (int m = 0; m < 4; ++m) BUF[m] =                     \
      *(const bf16x8*)&h2r[(m * 16 + lrow) * 520 + (K) * 32 + lgrp * 8];

#define G3_MM(BUF, K)                                                        \
  __builtin_amdgcn_s_setprio(1);                                             \
  _Pragma("unroll") for (int m = 0; m < 4; ++m) {                            \
    acc[m][0] = MFMA_BF16(BUF[m], b3r[K][0], acc[m][0], 0, 0, 0);            \
    acc[m][1] = MFMA_BF16(BUF[m], b3r[K][1], acc[m][1], 0, 0, 0);            \
  }                                                                          \
  __builtin_amdgcn_s_setprio(0);

template <int MODE>
__global__ __launch_bounds__(512, 2) void fused_kernel(
    const float* __restrict__ x2, const float* __restrict__ fold1,
    const __bf16* __restrict__ W2bf, const float* __restrict__ scale2,
    const float* __restrict__ shift2f, const __bf16* __restrict__ W3bf,
    const float* __restrict__ b3, const float* __restrict__ scale3,
    const float* __restrict__ shift3f, const float* __restrict__ W4,
    const float* __restrict__ b4, float* __restrict__ gsum3,
    float* __restrict__ gsq3, float* __restrict__ out,
    __bf16* __restrict__ y3o, int gBase, int gCount, int rStoreRgs) {
  __shared__ __bf16 h1buf[2][64 * 72];   // 2 x 9 KB
  __shared__ __bf16 h2buf[2][64 * 520];  // 2 x 65 KB
  __shared__ float sF[256];
  __shared__ float sSc2[512], sSh2[512];
  __shared__ float outaccW[8][64][2];    // 4 KB (MODE 2)

  const int t = threadIdx.x;
  const int lane = t & 63, wave = t >> 6;
  const int lrow = lane & 15, lgrp = lane >> 4;
  const int colHalf = blockIdx.x & 1;
  const int rgFirst = gBase + (int)(blockIdx.x >> 1) * gCount;
  const int wCol3 = colHalf * 256 + wave * 32;
  const int wCol2 = wave * 64;
  const bool doStore = (MODE == 3) && (rgFirst < rStoreRgs);

  // ---- one-time LDS staging ----
  if (t < 256) sF[t] = fold1[t];
  sSc2[t] = scale2[t & 511];  // t < 512
  sSh2[t] = shift2f[t & 511];

  // ---- one-time: W2, W3 fragments -> registers ----
  bf16x8 b2r[2][4];
#pragma unroll
  for (int kk = 0; kk < 2; ++kk)
#pragma unroll
    for (int n = 0; n < 4; ++n)
      b2r[kk][n] = *(const bf16x8*)&W2bf[(wCol2 + n * 16 + lrow) * 64 +
                                         kk * 32 + lgrp * 8];
  bf16x8 b3r[16][2];
#pragma unroll
  for (int k = 0; k < 16; ++k)
#pragma unroll
    for (int n = 0; n < 2; ++n)
      b3r[k][n] = *(const bf16x8*)&W3bf[(size_t)(wCol3 + n * 16 + lrow) * 512 +
                                        k * 32 + lgrp * 8];

  const int c3a = wCol3 + lrow, c3b = wCol3 + 16 + lrow;
  float b3a = 0.f, b3b = 0.f;
  float sc3a = 0.f, sc3b = 0.f, sh3a = 0.f, sh3b = 0.f;
  float w40a = 0.f, w40b = 0.f, w41a = 0.f, w41b = 0.f, B40 = 0.f, B41 = 0.f;
  if (MODE != 2) {
    b3a = b3[c3a];
    b3b = b3[c3b];
  } else {
    sc3a = scale3[c3a];
    sc3b = scale3[c3b];
    sh3a = shift3f[c3a];
    sh3b = shift3f[c3b];
    w40a = W4[c3a];
    w40b = W4[c3b];
    w41a = W4[512 + c3a];
    w41b = W4[512 + c3b];
    B40 = b4[0];
    B41 = b4[1];
  }
  float csA = 0.f, cqA = 0.f, csB = 0.f, cqB = 0.f;

  const int hr = t >> 3, hc0 = (t & 7) * 8;
  const float* xbase = x2 + ((size_t)rgFirst * 64 + hr) * 3;
  float xa, xb, xc;

  // stage h1 from (xa,xb,xc) into h1p
  auto stageH1 = [&](__bf16* h1p) {
    bf16x8 hv;
#pragma unroll
    for (int j = 0; j < 8; ++j) {
      int c = hc0 + j;
      float h = fmaf(sF[c], xa,
                     fmaf(sF[64 + c], xb, fmaf(sF[128 + c], xc, sF[192 + c])));
      hv[j] = (__bf16)fmaxf(h, 0.f);
    }
    *(bf16x8*)&h1p[hr * 72 + hc0] = hv;
  };

  // GEMM2: y2 = h1 @ W2^T (swapped operands), BN2+ReLU, write h2
  auto gemm2 = [&](const __bf16* h1p, __bf16* h2p) {
#pragma unroll
    for (int nh = 0; nh < 2; ++nh) {
      f32x4 a2[2][4] = {};  // [n2][m]
#pragma unroll
      for (int kk = 0; kk < 2; ++kk) {
        bf16x8 af0 = *(const bf16x8*)&h1p[(0 * 16 + lrow) * 72 + kk * 32 + lgrp * 8];
        bf16x8 af1 = *(const bf16x8*)&h1p[(1 * 16 + lrow) * 72 + kk * 32 + lgrp * 8];
        bf16x8 af2 = *(const bf16x8*)&h1p[(2 * 16 + lrow) * 72 + kk * 32 + lgrp * 8];
        bf16x8 af3 = *(const bf16x8*)&h1p[(3 * 16 + lrow) * 72 + kk * 32 + lgrp * 8];
#pragma unroll
        for (int n2 = 0; n2 < 2; ++n2) {
          int n = nh * 2 + n2;
          a2[n2][0] = MFMA_BF16(b2r[kk][n], af0, a2[n2][0], 0, 0, 0);
          a2[n2][1] = MFMA_BF16(b2r[kk][n], af1, a2[n2][1], 0, 0, 0);
          a2[n2][2] = MFMA_BF16(b2r[kk][n], af2, a2[n2][2], 0, 0, 0);
          a2[n2][3] = MFMA_BF16(b2r[kk][n], af3, a2[n2][3], 0, 0, 0);
        }
      }
#pragma unroll
      for (int n2 = 0; n2 < 2; ++n2) {
        int ch0 = wCol2 + (nh * 2 + n2) * 16 + lgrp * 4;
        float s0 = sSc2[ch0], s1v = sSc2[ch0 + 1], s2v = sSc2[ch0 + 2],
              s3v = sSc2[ch0 + 3];
        float z0 = sSh2[ch0], z1 = sSh2[ch0 + 1], z2 = sSh2[ch0 + 2],
              z3 = sSh2[ch0 + 3];
#pragma unroll
        for (int m = 0; m < 4; ++m) {
          int row = m * 16 + lrow;
          bf16x4 hv;
          hv[0] = (__bf16)fmaxf(fmaf(s0, a2[n2][m][0], z0), 0.f);
          hv[1] = (__bf16)fmaxf(fmaf(s1v, a2[n2][m][1], z1), 0.f);
          hv[2] = (__bf16)fmaxf(fmaf(s2v, a2[n2][m][2], z2), 0.f);
          hv[3] = (__bf16)fmaxf(fmaf(s3v, a2[n2][m][3], z3), 0.f);
          *(bf16x4*)&h2p[row * 520 + ch0] = hv;
        }
      }
    }
  };

  __syncthreads();  // sF/sSc2/sSh2 visible

  // ---- prologue ----
  xa = xbase[0];
  xb = xbase[1];
  xc = xbase[2];
  stageH1(h1buf[0]);
  __syncthreads();  // h1(0) ready
  gemm2(h1buf[0], h2buf[0]);
  if (gCount > 1) {
    const float* xn = xbase + 192;
    xa = xn[0];
    xb = xn[1];
    xc = xn[2];
    stageH1(h1buf[1]);
  }
  __syncthreads();  // h2(0) + h1(1) ready

  for (int g = 0; g < gCount; ++g) {
    const int rBase = (rgFirst + g) * 64;
    const __bf16* h2r = h2buf[g & 1];

    // issue x loads for h1(g+2) early
    if (g + 2 < gCount) {
      const float* xn = xbase + (size_t)(g + 2) * 192;
      xa = xn[0];
      xb = xn[1];
      xc = xn[2];
    }

    // GEMM2(g+1) -> h2[(g+1)&1]
    if (g + 1 < gCount) gemm2(h1buf[(g + 1) & 1], h2buf[(g + 1) & 1]);

    // stage h1(g+2) -> h1[g&1]
    if (g + 2 < gCount) stageH1(h1buf[g & 1]);

    // ---- GEMM3(g): 2-deep af pipeline, register-B MFMA ----
    f32x4 acc[4][2] = {};  // [m][n]
    bf16x8 afA[4], afB[4];
    G3_LD(afA, 0)
#pragma unroll
    for (int k = 0; k < 16; k += 2) {
      G3_LD(afB, k + 1)
      G3_MM(afA, k)
      if (k < 14) { G3_LD(afA, k + 2) }
      G3_MM(afB, k + 1)
    }

    if (MODE != 2) {
#pragma unroll
      for (int m = 0; m < 4; ++m)
#pragma unroll
        for (int rr = 0; rr < 4; ++rr) {
          float ya = acc[m][0][rr] + b3a;
          float yb = acc[m][1][rr] + b3b;
          csA += ya;
          cqA = fmaf(ya, ya, cqA);
          csB += yb;
          cqB = fmaf(yb, yb, cqB);
          if (doStore) {
            size_t row = (size_t)(rBase + m * 16 + lgrp * 4 + rr);
            y3o[row * 512 + c3a] = (__bf16)ya;
            y3o[row * 512 + c3b] = (__bf16)yb;
          }
        }
    } else {
#pragma unroll
      for (int m = 0; m < 4; ++m)
#pragma unroll
        for (int rr = 0; rr < 4; ++rr) {
          float ha = fmaxf(fmaf(sc3a, acc[m][0][rr], sh3a), 0.f);
          float hb = fmaxf(fmaf(sc3b, acc[m][1][rr], sh3b), 0.f);
          float dd0 = fmaf(ha, w40a, hb * w40b);
          float dd1 = fmaf(ha, w41a, hb * w41b);
          dd0 += __shfl_xor(dd0, 1);
          dd1 += __shfl_xor(dd1, 1);
          dd0 += __shfl_xor(dd0, 2);
          dd1 += __shfl_xor(dd1, 2);
          dd0 += __shfl_xor(dd0, 4);
          dd1 += __shfl_xor(dd1, 4);
          dd0 += __shfl_xor(dd0, 8);
          dd1 += __shfl_xor(dd1, 8);
          if (lrow == 0) {
            int row = m * 16 + lgrp * 4 + rr;
            outaccW[wave][row][0] = dd0;
            outaccW[wave][row][1] = dd1;
          }
        }
    }
    __syncthreads();  // single per-rg barrier: all buffers rotate safely
  }

  if (MODE != 2) {
    csA += __shfl_xor(csA, 16);
    cqA += __shfl_xor(cqA, 16);
    csB += __shfl_xor(csB, 16);
    cqB += __shfl_xor(cqB, 16);
    csA += __shfl_xor(csA, 32);
    cqA += __shfl_xor(cqA, 32);
    csB += __shfl_xor(csB, 32);
    cqB += __shfl_xor(cqB, 32);
    if (lgrp == 0) {
      atomicAdd(&gsum3[c3a], csA);
      atomicAdd(&gsq3[c3a], cqA);
      atomicAdd(&gsum3[c3b], csB);
      atomicAdd(&gsq3[c3b], cqB);
    }
  } else {
    // gCount == 1: reduce outaccW after the loop barrier
    if (t < 128) {
      int row = t >> 1, o = t & 1;
      float s = 0.f;
#pragma unroll
      for (int w = 0; w < 8; ++w) s += outaccW[w][row][o];
      if (colHalf == 0) s += (o == 0) ? B40 : B41;
      atomicAdd(&out[(size_t)(rgFirst * 64 + row) * 2 + o], s);
    }
  }
}

// ---------------------------------------------------------------------------
// stream_out: out = relu(sc3*y3 + sh3p) @ W4^T + b4, y3 bf16 from HBM.
// ---------------------------------------------------------------------------
__global__ __launch_bounds__(256) void stream_out_kernel(
    const __bf16* __restrict__ y3, const float* __restrict__ scale3,
    const float* __restrict__ shift3p, const float* __restrict__ W4,
    const float* __restrict__ b4, float* __restrict__ out, int N) {
  __shared__ float sSc[512], sSh[512], sW0[512], sW1[512];
  int t = threadIdx.x;
  for (int i = t; i < 512; i += 256) {
    sSc[i] = scale3[i];
    sSh[i] = shift3p[i];
    sW0[i] = W4[i];
    sW1[i] = W4[512 + i];
  }
  __syncthreads();
  int lane = t & 63, wv = t >> 6;
  int c0 = lane * 8;
  float fsc[8], fsh[8], fw0[8], fw1[8];
#pragma unroll
  for (int j = 0; j < 8; ++j) {
    fsc[j] = sSc[c0 + j];
    fsh[j] = sSh[c0 + j];
    fw0[j] = sW0[c0 + j];
    fw1[j] = sW1[c0 + j];
  }
  float B0 = b4[0], B1 = b4[1];
  for (size_t row = (size_t)blockIdx.x * 4 + wv; row < (size_t)N;
       row += (size_t)gridDim.x * 4) {
    bf16x8 v = *(const bf16x8*)(y3 + row * 512 + c0);
    float d0 = 0.f, d1 = 0.f;
#pragma unroll
    for (int j = 0; j < 8; ++j) {
      float h = fmaxf(fmaf(fsc[j], (float)v[j], fsh[j]), 0.f);
      d0 = fmaf(h, fw0[j], d0);
      d1 = fmaf(h, fw1[j], d1);
    }
#pragma unroll
    for (int off = 1; off < 64; off <<= 1) {
      d0 += __shfl_xor(d0, off);
      d1 += __shfl_xor(d1, off);
    }
    if (lane == 0) {
      out[row * 2 + 0] = d0 + B0;
      out[row * 2 + 1] = d1 + B1;
    }
  }
}

// ---------------------------------------------------------------------------
extern "C" void kernel_launch(void* const* d_in, const int* in_sizes, int n_in,
                              void* d_out, int out_size, void* d_ws,
                              size_t ws_size, hipStream_t stream) {
  const float* x2 = (const float*)d_in[1];
  const float* W1 = (const float*)d_in[2];
  const float* b1 = (const float*)d_in[3];
  const float* W2 = (const float*)d_in[4];
  const float* b2 = (const float*)d_in[5];
  const float* W3 = (const float*)d_in[6];
  const float* b3 = (const float*)d_in[7];
  const float* W4 = (const float*)d_in[8];
  const float* b4 = (const float*)d_in[9];
  const float* gamma1 = (const float*)d_in[10];
  const float* beta1 = (const float*)d_in[11];
  const float* gamma2 = (const float*)d_in[12];
  const float* beta2 = (const float*)d_in[13];
  const float* gamma3 = (const float*)d_in[14];
  const float* beta3 = (const float*)d_in[15];
  float* out = (float*)d_out;

  const int N = in_sizes[1] / 3;  // 262144
  const float invN = 1.0f / (float)N;

  // --- small scratch layout (< 1 MiB) ---
  float* f0 = (float*)d_ws;
  float* gsum1 = f0;           // 64
  float* gsq1 = f0 + 64;       // 64
  float* M1 = f0 + 128;        // 4096
  float* s1 = f0 + 4224;       // 64
  float* gsum3 = f0 + 4288;    // 512
  float* gsq3 = f0 + 4800;     // 512  (zeroed region ends at 5312)
  float* fold1 = f0 + 5312;    // 256
  float* scale2 = f0 + 5568;   // 512
  float* shift2f = f0 + 6080;  // 512
  float* scale3 = f0 + 6592;   // 512
  float* shift3f = f0 + 7104;  // 512
  float* shift3p = f0 + 7616;  // 512
  __bf16* W2bf = (__bf16*)(f0 + 8128);  // 32768 elems
  __bf16* W3bf = W2bf + 32768;          // 262144 elems; ends ~622 KB

  // --- adaptive y3 cache: store as many 1024-row blocks as fit ---
  const size_t y3off = (size_t)1 << 20;
  size_t availRows = (ws_size > y3off) ? (ws_size - y3off) / 1024 : 0;
  int rStoreBlks = (int)((availRows / 1024 < (size_t)(N / 1024))
                             ? availRows / 1024
                             : (size_t)(N / 1024));
  const int rStore = rStoreBlks * 1024;
  __bf16* y3bf = (__bf16*)((char*)d_ws + y3off);

  prep_kernel<<<1024, 256, 0, stream>>>(W2, W3, W2bf, W3bf, f0);
  stats1_kernel<<<N / 128, 256, 0, stream>>>(x2, W1, b1, gsum1, gsq1);
  finalize1_kernel<<<1, 64, 0, stream>>>(gsum1, gsq1, gamma1, beta1, W1, b1,
                                         fold1, invN);
  m1_kernel<<<N / 256, 256, 0, stream>>>(x2, fold1, M1, s1);
  finalize2v_kernel<<<128, 256, 0, stream>>>(M1, s1, W2, b2, gamma2, beta2,
                                             scale2, shift2f, (float)N);

  // pass 1: stats (+ y3 store where it fits), 16 row-groups per block
  fused_kernel<3><<<(N / 1024) * 2, 512, 0, stream>>>(
      x2, fold1, W2bf, scale2, shift2f, W3bf, b3, scale3, shift3f, W4, b4,
      gsum3, gsq3, out, y3bf, 0, 16, rStoreBlks * 16);
  finalize3_kernel<<<1, 512, 0, stream>>>(gsum3, gsq3, gamma3, beta3, b3,
                                          scale3, shift3f, shift3p, invN);

  // pass 2a: stream stored rows
  if (rStore > 0)
    stream_out_kernel<<<2048, 256, 0, stream>>>(y3bf, scale3, shift3p, W4, b4,
                                                out, rStore);
  // pass 2b: recompute remainder, ONE row-group per block (spread over CUs)
  if (rStore < N) {
    hipMemsetAsync(out + (size_t)rStore * 2, 0,
                   (size_t)(N - rStore) * 2 * sizeof(float), stream);
    fused_kernel<2><<<((N - rStore) / 64) * 2, 512, 0, stream>>>(
        x2, fold1, W2bf, scale2, shift2f, W3bf, b3, scale3, shift3f, W4, b4,
        gsum3, gsq3, out, y3bf, rStore / 64, 1, 0);
  }
}

// Round 11
// 384.108 us; speedup vs baseline: 3.9479x; 1.0148x over previous
//
#include <hip/hip_runtime.h>

typedef __bf16 bf16x4 __attribute__((ext_vector_type(4)));
typedef __bf16 bf16x8 __attribute__((ext_vector_type(8)));
typedef float f32x4 __attribute__((ext_vector_type(4)));

#define MFMA_BF16 __builtin_amdgcn_mfma_f32_16x16x32_bf16

// ---------------------------------------------------------------------------
// prep_stats1: blocks [0,2048) = column stats of y1 = x2@W1^T+b1 (atomics,
// pre-zeroed); blocks [2048,2064) convert W2->bf16; [2064,2192) W3->bf16.
// ---------------------------------------------------------------------------
__global__ __launch_bounds__(256) void prep_stats1_kernel(
    const float* __restrict__ x, const float* __restrict__ W1,
    const float* __restrict__ b1, const float* __restrict__ W2,
    const float* __restrict__ W3, __bf16* __restrict__ W2bf,
    __bf16* __restrict__ W3bf, float* __restrict__ gsum,
    float* __restrict__ gsq) {
  const int b = blockIdx.x;
  const int t = threadIdx.x;
  if (b >= 2048) {
    const float* src;
    __bf16* dst;
    int idx;
    if (b < 2064) {
      idx = (b - 2048) * 2048 + t * 8;
      src = W2;
      dst = W2bf;
    } else {
      idx = (b - 2064) * 2048 + t * 8;
      src = W3;
      dst = W3bf;
    }
    float4 f0 = *(const float4*)(src + idx);
    float4 f1 = *(const float4*)(src + idx + 4);
    bf16x8 o;
    o[0] = (__bf16)f0.x;
    o[1] = (__bf16)f0.y;
    o[2] = (__bf16)f0.z;
    o[3] = (__bf16)f0.w;
    o[4] = (__bf16)f1.x;
    o[5] = (__bf16)f1.y;
    o[6] = (__bf16)f1.z;
    o[7] = (__bf16)f1.w;
    *(bf16x8*)(dst + idx) = o;
    return;
  }
  int c = t & 63;
  int rw = t >> 6;
  float w0 = W1[c * 3 + 0], w1 = W1[c * 3 + 1], w2 = W1[c * 3 + 2];
  float bb = b1[c];
  int base = b * 128;
  float sum = 0.f, sq = 0.f;
#pragma unroll 4
  for (int i = 0; i < 32; ++i) {
    int row = base + i * 4 + rw;
    const float* xp = x + (size_t)row * 3;
    float y = fmaf(xp[0], w0, fmaf(xp[1], w1, fmaf(xp[2], w2, bb)));
    sum += y;
    sq += y * y;
  }
  __shared__ float ssum[256], ssq[256];
  ssum[t] = sum;
  ssq[t] = sq;
  __syncthreads();
  if (t < 64) {
    float s = ssum[t] + ssum[t + 64] + ssum[t + 128] + ssum[t + 192];
    float q = ssq[t] + ssq[t + 64] + ssq[t + 128] + ssq[t + 192];
    atomicAdd(&gsum[t], s);
    atomicAdd(&gsq[t], q);
  }
}

// ---------------------------------------------------------------------------
// m1: M1 = sum_r h1_r h1_r^T (64x64), s1 = sum_r h1_r. fold1 computed inline.
// ---------------------------------------------------------------------------
__global__ __launch_bounds__(256, 4) void m1_kernel(
    const float* __restrict__ x2, const float* __restrict__ gsum1,
    const float* __restrict__ gsq1, const float* __restrict__ gamma1,
    const float* __restrict__ beta1, const float* __restrict__ W1,
    const float* __restrict__ b1, float* __restrict__ M1,
    float* __restrict__ s1, float invN) {
  __shared__ float sF[256];
  __shared__ float xs[768];
  __shared__ __bf16 h1T[64 * 264];  // [col][row], row-pad 264
  __shared__ float s1s[4][64];

  const int t = threadIdx.x;
  const int lane = t & 63, wave = t >> 6;
  const int lrow = lane & 15, lgrp = lane >> 4;

  if (t < 64) {
    float mu = gsum1[t] * invN;
    float var = gsq1[t] * invN - mu * mu;
    float sc = gamma1[t] * rsqrtf(var + 1e-5f);
    float sh = beta1[t] - mu * sc;
    sF[t] = sc * W1[t * 3];
    sF[64 + t] = sc * W1[t * 3 + 1];
    sF[128 + t] = sc * W1[t * 3 + 2];
    sF[192 + t] = sc * b1[t] + sh;
  }
  if (t < 192)
    ((float4*)xs)[t] = ((const float4*)(x2 + (size_t)blockIdx.x * 768))[t];
  __syncthreads();

  const int c0 = (t & 3) * 16;
  const int r0 = t >> 2;
  float sAcc[16] = {};
#pragma unroll
  for (int s = 0; s < 4; ++s) {
    int r = r0 + s * 64;
    float X0 = xs[r * 3], X1 = xs[r * 3 + 1], X2 = xs[r * 3 + 2];
#pragma unroll
    for (int j = 0; j < 16; ++j) {
      int c = c0 + j;
      float h = fmaxf(
          fmaf(sF[c], X0, fmaf(sF[64 + c], X1, fmaf(sF[128 + c], X2, sF[192 + c]))),
          0.f);
      sAcc[j] += h;
      h1T[c * 264 + r] = (__bf16)h;
    }
  }
  __syncthreads();

  f32x4 acc[4] = {};
#pragma unroll
  for (int kk = 0; kk < 256; kk += 32) {
    bf16x8 af = *(const bf16x8*)&h1T[(wave * 16 + lrow) * 264 + kk + lgrp * 8];
#pragma unroll
    for (int n = 0; n < 4; ++n) {
      bf16x8 bfr = *(const bf16x8*)&h1T[(n * 16 + lrow) * 264 + kk + lgrp * 8];
      acc[n] = MFMA_BF16(af, bfr, acc[n], 0, 0, 0);
    }
  }
#pragma unroll
  for (int n = 0; n < 4; ++n)
#pragma unroll
    for (int rr = 0; rr < 4; ++rr)
      atomicAdd(&M1[(wave * 16 + lgrp * 4 + rr) * 64 + n * 16 + lrow],
                acc[n][rr]);

#pragma unroll
  for (int j = 0; j < 16; ++j) {
    float v = sAcc[j];
    v += __shfl_xor(v, 4);
    v += __shfl_xor(v, 8);
    v += __shfl_xor(v, 16);
    v += __shfl_xor(v, 32);
    if (lane < 4) s1s[wave][(lane & 3) * 16 + j] = v;
  }
  __syncthreads();
  if (t < 64)
    atomicAdd(&s1[t], s1s[0][t] + s1s[1][t] + s1s[2][t] + s1s[3][t]);
}

// ---------------------------------------------------------------------------
// finalize2v: per col c of layer 2, q = w^T M1 w; derive BN2 scale/shiftf.
// ---------------------------------------------------------------------------
__global__ __launch_bounds__(256) void finalize2v_kernel(
    const float* __restrict__ M1, const float* __restrict__ s1,
    const float* __restrict__ W2, const float* __restrict__ b2,
    const float* __restrict__ gamma2, const float* __restrict__ beta2,
    float* __restrict__ scale2, float* __restrict__ shift2f, float fN) {
  __shared__ float sM[64 * 65];
  __shared__ float ss[64];
  int t = threadIdx.x;
  for (int i = t; i < 4096; i += 256) sM[(i >> 6) * 65 + (i & 63)] = M1[i];
  if (t < 64) ss[t] = s1[t];
  __syncthreads();
  int lane = t & 63;
  int col = blockIdx.x * 4 + (t >> 6);
  float wi = W2[(size_t)col * 64 + lane];
  float p = 0.f;
#pragma unroll
  for (int j = 0; j < 64; ++j) p = fmaf(sM[lane * 65 + j], __shfl(wi, j), p);
  float qi = wi * p;
  float swi = ss[lane] * wi;
#pragma unroll
  for (int off = 1; off < 64; off <<= 1) {
    qi += __shfl_xor(qi, off);
    swi += __shfl_xor(swi, off);
  }
  if (lane == 0) {
    float b = b2[col];
    float sy = swi + fN * b;
    float sqs = qi + 2.f * b * swi + fN * b * b;
    float mu = sy / fN;
    float var = sqs / fN - mu * mu;
    float sc = gamma2[col] * rsqrtf(var + 1e-5f);
    scale2[col] = sc;
    shift2f[col] = (beta2[col] - mu * sc) + sc * b;
  }
}

// ---------------------------------------------------------------------------
// Fused kernel: register-resident W2/W3, ONE barrier per row-group,
// double-buffered h1/h2. fold1 (sF) computed inline from stats1.
// MODE 3: stats + store y3 bf16 where rg < rStoreRgs.
// MODE 2 (gCount==1): BN3 (inline from stats3) + ReLU + @W4 -> out.
// ---------------------------------------------------------------------------
#define G3_LD(BUF, K)                                                        \
  _Pragma("unroll") for (int m = 0; m < 4; ++m) BUF[m] =                     \
      *(const bf16x8*)&h2r[(m * 16 + lrow) * 520 + (K) * 32 + lgrp * 8];

#define G3_MM(BUF, K)                                                        \
  __builtin_amdgcn_s_setprio(1);                                             \
  _Pragma("unroll") for (int m = 0; m < 4; ++m) {                            \
    acc[m][0] = MFMA_BF16(BUF[m], b3r[K][0], acc[m][0], 0, 0, 0);            \
    acc[m][1] = MFMA_BF16(BUF[m], b3r[K][1], acc[m][1], 0, 0, 0);            \
  }                                                                          \
  __builtin_amdgcn_s_setprio(0);

template <int MODE>
__global__ __launch_bounds__(512, 2) void fused_kernel(
    const float* __restrict__ x2, const float* __restrict__ gsum1,
    const float* __restrict__ gsq1, const float* __restrict__ gamma1,
    const float* __restrict__ beta1, const float* __restrict__ W1,
    const float* __restrict__ b1, const __bf16* __restrict__ W2bf,
    const float* __restrict__ scale2, const float* __restrict__ shift2f,
    const __bf16* __restrict__ W3bf, const float* __restrict__ b3,
    const float* __restrict__ gamma3, const float* __restrict__ beta3,
    const float* __restrict__ W4, const float* __restrict__ b4,
    float* __restrict__ gsum3, float* __restrict__ gsq3,
    float* __restrict__ out, __bf16* __restrict__ y3o, int gBase, int gCount,
    int rStoreRgs, float invN) {
  __shared__ __bf16 h1buf[2][64 * 72];   // 2 x 9 KB
  __shared__ __bf16 h2buf[2][64 * 520];  // 2 x 65 KB
  __shared__ float sF[256];
  __shared__ float sSc2[512], sSh2[512];
  __shared__ float outaccW[8][64][2];    // 4 KB (MODE 2)

  const int t = threadIdx.x;
  const int lane = t & 63, wave = t >> 6;
  const int lrow = lane & 15, lgrp = lane >> 4;
  const int colHalf = blockIdx.x & 1;
  const int rgFirst = gBase + (int)(blockIdx.x >> 1) * gCount;
  const int wCol3 = colHalf * 256 + wave * 32;
  const int wCol2 = wave * 64;
  const bool doStore = (MODE == 3) && (rgFirst < rStoreRgs);

  // ---- one-time LDS staging (sF inline from stats1) ----
  if (t < 64) {
    float mu = gsum1[t] * invN;
    float var = gsq1[t] * invN - mu * mu;
    float sc = gamma1[t] * rsqrtf(var + 1e-5f);
    float sh = beta1[t] - mu * sc;
    sF[t] = sc * W1[t * 3];
    sF[64 + t] = sc * W1[t * 3 + 1];
    sF[128 + t] = sc * W1[t * 3 + 2];
    sF[192 + t] = sc * b1[t] + sh;
  }
  sSc2[t] = scale2[t & 511];
  sSh2[t] = shift2f[t & 511];

  // ---- one-time: W2, W3 fragments -> registers ----
  bf16x8 b2r[2][4];
#pragma unroll
  for (int kk = 0; kk < 2; ++kk)
#pragma unroll
    for (int n = 0; n < 4; ++n)
      b2r[kk][n] = *(const bf16x8*)&W2bf[(wCol2 + n * 16 + lrow) * 64 +
                                         kk * 32 + lgrp * 8];
  bf16x8 b3r[16][2];
#pragma unroll
  for (int k = 0; k < 16; ++k)
#pragma unroll
    for (int n = 0; n < 2; ++n)
      b3r[k][n] = *(const bf16x8*)&W3bf[(size_t)(wCol3 + n * 16 + lrow) * 512 +
                                        k * 32 + lgrp * 8];

  const int c3a = wCol3 + lrow, c3b = wCol3 + 16 + lrow;
  float b3a = 0.f, b3b = 0.f;
  float sc3a = 0.f, sc3b = 0.f, sh3a = 0.f, sh3b = 0.f;
  float w40a = 0.f, w40b = 0.f, w41a = 0.f, w41b = 0.f, B40 = 0.f, B41 = 0.f;
  if (MODE != 2) {
    b3a = b3[c3a];
    b3b = b3[c3b];
  } else {
    // inline finalize3 (bias-folded shift, since acc lacks b3)
    float mu = gsum3[c3a] * invN;
    float var = gsq3[c3a] * invN - mu * mu;
    sc3a = gamma3[c3a] * rsqrtf(var + 1e-5f);
    sh3a = sc3a * b3[c3a] + (beta3[c3a] - mu * sc3a);
    mu = gsum3[c3b] * invN;
    var = gsq3[c3b] * invN - mu * mu;
    sc3b = gamma3[c3b] * rsqrtf(var + 1e-5f);
    sh3b = sc3b * b3[c3b] + (beta3[c3b] - mu * sc3b);
    w40a = W4[c3a];
    w40b = W4[c3b];
    w41a = W4[512 + c3a];
    w41b = W4[512 + c3b];
    B40 = b4[0];
    B41 = b4[1];
  }
  float csA = 0.f, cqA = 0.f, csB = 0.f, cqB = 0.f;

  const int hr = t >> 3, hc0 = (t & 7) * 8;
  const float* xbase = x2 + ((size_t)rgFirst * 64 + hr) * 3;
  float xa, xb, xc;

  auto stageH1 = [&](__bf16* h1p) {
    bf16x8 hv;
#pragma unroll
    for (int j = 0; j < 8; ++j) {
      int c = hc0 + j;
      float h = fmaf(sF[c], xa,
                     fmaf(sF[64 + c], xb, fmaf(sF[128 + c], xc, sF[192 + c])));
      hv[j] = (__bf16)fmaxf(h, 0.f);
    }
    *(bf16x8*)&h1p[hr * 72 + hc0] = hv;
  };

  auto gemm2 = [&](const __bf16* h1p, __bf16* h2p) {
#pragma unroll
    for (int nh = 0; nh < 2; ++nh) {
      f32x4 a2[2][4] = {};  // [n2][m]
#pragma unroll
      for (int kk = 0; kk < 2; ++kk) {
        bf16x8 af0 = *(const bf16x8*)&h1p[(0 * 16 + lrow) * 72 + kk * 32 + lgrp * 8];
        bf16x8 af1 = *(const bf16x8*)&h1p[(1 * 16 + lrow) * 72 + kk * 32 + lgrp * 8];
        bf16x8 af2 = *(const bf16x8*)&h1p[(2 * 16 + lrow) * 72 + kk * 32 + lgrp * 8];
        bf16x8 af3 = *(const bf16x8*)&h1p[(3 * 16 + lrow) * 72 + kk * 32 + lgrp * 8];
#pragma unroll
        for (int n2 = 0; n2 < 2; ++n2) {
          int n = nh * 2 + n2;
          a2[n2][0] = MFMA_BF16(b2r[kk][n], af0, a2[n2][0], 0, 0, 0);
          a2[n2][1] = MFMA_BF16(b2r[kk][n], af1, a2[n2][1], 0, 0, 0);
          a2[n2][2] = MFMA_BF16(b2r[kk][n], af2, a2[n2][2], 0, 0, 0);
          a2[n2][3] = MFMA_BF16(b2r[kk][n], af3, a2[n2][3], 0, 0, 0);
        }
      }
#pragma unroll
      for (int n2 = 0; n2 < 2; ++n2) {
        int ch0 = wCol2 + (nh * 2 + n2) * 16 + lgrp * 4;
        float s0 = sSc2[ch0], s1v = sSc2[ch0 + 1], s2v = sSc2[ch0 + 2],
              s3v = sSc2[ch0 + 3];
        float z0 = sSh2[ch0], z1 = sSh2[ch0 + 1], z2 = sSh2[ch0 + 2],
              z3 = sSh2[ch0 + 3];
#pragma unroll
        for (int m = 0; m < 4; ++m) {
          int row = m * 16 + lrow;
          bf16x4 hv;
          hv[0] = (__bf16)fmaxf(fmaf(s0, a2[n2][m][0], z0), 0.f);
          hv[1] = (__bf16)fmaxf(fmaf(s1v, a2[n2][m][1], z1), 0.f);
          hv[2] = (__bf16)fmaxf(fmaf(s2v, a2[n2][m][2], z2), 0.f);
          hv[3] = (__bf16)fmaxf(fmaf(s3v, a2[n2][m][3], z3), 0.f);
          *(bf16x4*)&h2p[row * 520 + ch0] = hv;
        }
      }
    }
  };

  __syncthreads();  // sF/sSc2/sSh2 visible

  // ---- prologue ----
  xa = xbase[0];
  xb = xbase[1];
  xc = xbase[2];
  stageH1(h1buf[0]);
  __syncthreads();  // h1(0) ready
  gemm2(h1buf[0], h2buf[0]);
  if (gCount > 1) {
    const float* xn = xbase + 192;
    xa = xn[0];
    xb = xn[1];
    xc = xn[2];
    stageH1(h1buf[1]);
  }
  __syncthreads();  // h2(0) + h1(1) ready

  for (int g = 0; g < gCount; ++g) {
    const int rBase = (rgFirst + g) * 64;
    const __bf16* h2r = h2buf[g & 1];

    if (g + 2 < gCount) {
      const float* xn = xbase + (size_t)(g + 2) * 192;
      xa = xn[0];
      xb = xn[1];
      xc = xn[2];
    }

    if (g + 1 < gCount) gemm2(h1buf[(g + 1) & 1], h2buf[(g + 1) & 1]);
    if (g + 2 < gCount) stageH1(h1buf[g & 1]);

    // ---- GEMM3(g): 2-deep af pipeline, register-B MFMA ----
    f32x4 acc[4][2] = {};  // [m][n]
    bf16x8 afA[4], afB[4];
    G3_LD(afA, 0)
#pragma unroll
    for (int k = 0; k < 16; k += 2) {
      G3_LD(afB, k + 1)
      G3_MM(afA, k)
      if (k < 14) { G3_LD(afA, k + 2) }
      G3_MM(afB, k + 1)
    }

    if (MODE != 2) {
#pragma unroll
      for (int m = 0; m < 4; ++m)
#pragma unroll
        for (int rr = 0; rr < 4; ++rr) {
          float ya = acc[m][0][rr] + b3a;
          float yb = acc[m][1][rr] + b3b;
          csA += ya;
          cqA = fmaf(ya, ya, cqA);
          csB += yb;
          cqB = fmaf(yb, yb, cqB);
          if (doStore) {
            size_t row = (size_t)(rBase + m * 16 + lgrp * 4 + rr);
            y3o[row * 512 + c3a] = (__bf16)ya;
            y3o[row * 512 + c3b] = (__bf16)yb;
          }
        }
    } else {
#pragma unroll
      for (int m = 0; m < 4; ++m)
#pragma unroll
        for (int rr = 0; rr < 4; ++rr) {
          float ha = fmaxf(fmaf(sc3a, acc[m][0][rr], sh3a), 0.f);
          float hb = fmaxf(fmaf(sc3b, acc[m][1][rr], sh3b), 0.f);
          float dd0 = fmaf(ha, w40a, hb * w40b);
          float dd1 = fmaf(ha, w41a, hb * w41b);
          dd0 += __shfl_xor(dd0, 1);
          dd1 += __shfl_xor(dd1, 1);
          dd0 += __shfl_xor(dd0, 2);
          dd1 += __shfl_xor(dd1, 2);
          dd0 += __shfl_xor(dd0, 4);
          dd1 += __shfl_xor(dd1, 4);
          dd0 += __shfl_xor(dd0, 8);
          dd1 += __shfl_xor(dd1, 8);
          if (lrow == 0) {
            int row = m * 16 + lgrp * 4 + rr;
            outaccW[wave][row][0] = dd0;
            outaccW[wave][row][1] = dd1;
          }
        }
    }
    __syncthreads();  // single per-rg barrier
  }

  if (MODE != 2) {
    csA += __shfl_xor(csA, 16);
    cqA += __shfl_xor(cqA, 16);
    csB += __shfl_xor(csB, 16);
    cqB += __shfl_xor(cqB, 16);
    csA += __shfl_xor(csA, 32);
    cqA += __shfl_xor(cqA, 32);
    csB += __shfl_xor(csB, 32);
    cqB += __shfl_xor(cqB, 32);
    if (lgrp == 0) {
      atomicAdd(&gsum3[c3a], csA);
      atomicAdd(&gsq3[c3a], cqA);
      atomicAdd(&gsum3[c3b], csB);
      atomicAdd(&gsq3[c3b], cqB);
    }
  } else {
    if (t < 128) {
      int row = t >> 1, o = t & 1;
      float s = 0.f;
#pragma unroll
      for (int w = 0; w < 8; ++w) s += outaccW[w][row][o];
      if (colHalf == 0) s += (o == 0) ? B40 : B41;
      atomicAdd(&out[(size_t)(rgFirst * 64 + row) * 2 + o], s);
    }
  }
}

// ---------------------------------------------------------------------------
// stream_out: out = relu(sc3*y3 + sh3) @ W4^T + b4. BN3 finalize inline.
// 2 rows per wave per iter; 5-shuffle/row pack reduction; 16B store by lanes 0-3.
// ---------------------------------------------------------------------------
__global__ __launch_bounds__(256) void stream_out_kernel(
    const __bf16* __restrict__ y3, const float* __restrict__ gsum3,
    const float* __restrict__ gsq3, const float* __restrict__ gamma3,
    const float* __restrict__ beta3, const float* __restrict__ W4,
    const float* __restrict__ b4, float* __restrict__ out, int N, float invN) {
  __shared__ float sSc[512], sSh[512], sW0[512], sW1[512];
  int t = threadIdx.x;
  for (int i = t; i < 512; i += 256) {
    float mu = gsum3[i] * invN;
    float var = gsq3[i] * invN - mu * mu;
    float sc = gamma3[i] * rsqrtf(var + 1e-5f);
    sSc[i] = sc;
    sSh[i] = beta3[i] - mu * sc;  // y3 already includes b3
    sW0[i] = W4[i];
    sW1[i] = W4[512 + i];
  }
  __syncthreads();
  int lane = t & 63, wv = t >> 6;
  int c0 = lane * 8;
  float fsc[8], fsh[8], fw0[8], fw1[8];
#pragma unroll
  for (int j = 0; j < 8; ++j) {
    fsc[j] = sSc[c0 + j];
    fsh[j] = sSh[c0 + j];
    fw0[j] = sW0[c0 + j];
    fw1[j] = sW1[c0 + j];
  }
  float B0 = b4[0], B1 = b4[1];
  for (size_t row = (size_t)blockIdx.x * 8 + wv * 2; row < (size_t)N;
       row += (size_t)gridDim.x * 8) {
    bf16x8 v0 = *(const bf16x8*)(y3 + row * 512 + c0);
    bf16x8 v1 = *(const bf16x8*)(y3 + (row + 1) * 512 + c0);
    float d0a = 0.f, d1a = 0.f, d0b = 0.f, d1b = 0.f;
#pragma unroll
    for (int j = 0; j < 8; ++j) {
      float ha = fmaxf(fmaf(fsc[j], (float)v0[j], fsh[j]), 0.f);
      float hb = fmaxf(fmaf(fsc[j], (float)v1[j], fsh[j]), 0.f);
      d0a = fmaf(ha, fw0[j], d0a);
      d1a = fmaf(ha, fw1[j], d1a);
      d0b = fmaf(hb, fw0[j], d0b);
      d1b = fmaf(hb, fw1[j], d1b);
    }
    // pack reduce: 10 shuffles for 4 sums (2 rows)
    float t0 = d0a + __shfl_xor(d0a, 1);
    float t1 = d1a + __shfl_xor(d1a, 1);
    float t2 = d0b + __shfl_xor(d0b, 1);
    float t3 = d1b + __shfl_xor(d1b, 1);
    float u0 = (lane & 1) ? t1 : t0;
    float u1 = (lane & 1) ? t3 : t2;
    u0 += __shfl_xor(u0, 2);
    u1 += __shfl_xor(u1, 2);
    float w = (lane & 2) ? u1 : u0;
    w += __shfl_xor(w, 4);
    w += __shfl_xor(w, 8);
    w += __shfl_xor(w, 16);
    w += __shfl_xor(w, 32);
    if (lane < 4) out[row * 2 + lane] = w + ((lane & 1) ? B1 : B0);
  }
}

// ---------------------------------------------------------------------------
extern "C" void kernel_launch(void* const* d_in, const int* in_sizes, int n_in,
                              void* d_out, int out_size, void* d_ws,
                              size_t ws_size, hipStream_t stream) {
  const float* x2 = (const float*)d_in[1];
  const float* W1 = (const float*)d_in[2];
  const float* b1 = (const float*)d_in[3];
  const float* W2 = (const float*)d_in[4];
  const float* b2 = (const float*)d_in[5];
  const float* W3 = (const float*)d_in[6];
  const float* b3 = (const float*)d_in[7];
  const float* W4 = (const float*)d_in[8];
  const float* b4 = (const float*)d_in[9];
  const float* gamma1 = (const float*)d_in[10];
  const float* beta1 = (const float*)d_in[11];
  const float* gamma2 = (const float*)d_in[12];
  const float* beta2 = (const float*)d_in[13];
  const float* gamma3 = (const float*)d_in[14];
  const float* beta3 = (const float*)d_in[15];
  float* out = (float*)d_out;

  const int N = in_sizes[1] / 3;  // 262144
  const float invN = 1.0f / (float)N;

  // --- small scratch layout ---
  float* f0 = (float*)d_ws;
  float* gsum1 = f0;           // 64
  float* gsq1 = f0 + 64;       // 64
  float* M1 = f0 + 128;        // 4096
  float* s1 = f0 + 4224;       // 64
  float* gsum3 = f0 + 4288;    // 512
  float* gsq3 = f0 + 4800;     // 512  (zeroed region: 5312 floats)
  float* scale2 = f0 + 5312;   // 512
  float* shift2f = f0 + 5824;  // 512
  __bf16* W2bf = (__bf16*)(f0 + 6336);  // 32768 elems
  __bf16* W3bf = W2bf + 32768;          // 262144 elems

  // --- adaptive y3 cache ---
  const size_t y3off = (size_t)1 << 20;
  size_t availRows = (ws_size > y3off) ? (ws_size - y3off) / 1024 : 0;
  int rStoreBlks = (int)((availRows / 1024 < (size_t)(N / 1024))
                             ? availRows / 1024
                             : (size_t)(N / 1024));
  const int rStore = rStoreBlks * 1024;
  __bf16* y3bf = (__bf16*)((char*)d_ws + y3off);

  hipMemsetAsync(f0, 0, 5312 * sizeof(float), stream);
  prep_stats1_kernel<<<2192, 256, 0, stream>>>(x2, W1, b1, W2, W3, W2bf, W3bf,
                                               gsum1, gsq1);
  m1_kernel<<<N / 256, 256, 0, stream>>>(x2, gsum1, gsq1, gamma1, beta1, W1,
                                         b1, M1, s1, invN);
  finalize2v_kernel<<<128, 256, 0, stream>>>(M1, s1, W2, b2, gamma2, beta2,
                                             scale2, shift2f, (float)N);

  // pass 1: stats (+ y3 store where it fits), 16 row-groups per block
  fused_kernel<3><<<(N / 1024) * 2, 512, 0, stream>>>(
      x2, gsum1, gsq1, gamma1, beta1, W1, b1, W2bf, scale2, shift2f, W3bf, b3,
      gamma3, beta3, W4, b4, gsum3, gsq3, out, y3bf, 0, 16, rStoreBlks * 16,
      invN);

  // pass 2a: stream stored rows (BN3 finalize inline)
  if (rStore > 0)
    stream_out_kernel<<<2048, 256, 0, stream>>>(y3bf, gsum3, gsq3, gamma3,
                                                beta3, W4, b4, out, rStore,
                                                invN);
  // pass 2b: recompute remainder, ONE row-group per block
  if (rStore < N) {
    hipMemsetAsync(out + (size_t)rStore * 2, 0,
                   (size_t)(N - rStore) * 2 * sizeof(float), stream);
    fused_kernel<2><<<((N - rStore) / 64) * 2, 512, 0, stream>>>(
        x2, gsum1, gsq1, gamma1, beta1, W1, b1, W2bf, scale2, shift2f, W3bf,
        b3, gamma3, beta3, W4, b4, gsum3, gsq3, out, y3bf, rStore / 64, 1, 0,
        invN);
  }
}